// Round 2
// baseline (4622.623 us; speedup 1.0000x reference)
//
#include <hip/hip_runtime.h>
#include <hip/hip_bf16.h>
#include <cmath>

// ---------------------------------------------------------------------------
// MuleHunterGNN: SAGE -> GAT -> SAGE -> skip -> MLP classifier
// fp32 compute, bf16 for bulky read-only intermediates (xh, identity).
// Workspace-adaptive: GAT heads processed in groups of G (4/2/1) by ws_size.
// ---------------------------------------------------------------------------

__device__ __forceinline__ float bf2f(unsigned short u) {
  return __uint_as_float((unsigned)u << 16);
}
__device__ __forceinline__ unsigned short f2bf(float f) {
  __hip_bfloat16 h = __float2bfloat16(f);
  return *reinterpret_cast<unsigned short*>(&h);
}
__device__ __forceinline__ unsigned encf(float f) {
  unsigned u = __float_as_uint(f);
  return (u & 0x80000000u) ? ~u : (u | 0x80000000u);
}
__device__ __forceinline__ float decf(unsigned t) {
  unsigned u = (t & 0x80000000u) ? (t ^ 0x80000000u) : ~t;
  return __uint_as_float(u);
}

// ---- degree ------------------------------------------------------------
__global__ void k_deg(const int* __restrict__ dst, float* __restrict__ deg, int E) {
  int e = blockIdx.x * blockDim.x + threadIdx.x;
  if (e < E) atomicAdd(&deg[dst[e]], 1.0f);
}

__global__ void k_initmax(unsigned* __restrict__ p, int n) {
  int i = blockIdx.x * blockDim.x + threadIdx.x;
  if (i < n) p[i] = 0x007FFFFFu;  // encf(-inf)
}

// ---- scatter-add of 128-wide fp32 rows: agg[dst] += x[src] --------------
__global__ void k_scatter128(const float* __restrict__ x, const int* __restrict__ src,
                             const int* __restrict__ dst, float* __restrict__ agg, int E) {
  long tid = (long)blockIdx.x * blockDim.x + threadIdx.x;
  int e = (int)(tid >> 5);
  if (e >= E) return;
  int j = ((int)tid & 31) << 2;
  int s = src[e], d = dst[e];
  float4 v = *reinterpret_cast<const float4*>(x + (size_t)s * 128 + j);
  float* p = agg + (size_t)d * 128 + j;
  atomicAdd(p + 0, v.x); atomicAdd(p + 1, v.y);
  atomicAdd(p + 2, v.z); atomicAdd(p + 3, v.w);
}

// ---- fused GEMM: C = (A1/deg) @ W1 [+ A2 @ W2] + bias; optional bf16 out --
// A: [N, M] row-major fp32, W row-major with leading dim ldW, C: [N, Kout].
// 256 threads -> 32 rows x 128 cols tile.
template <bool OBF16>
__global__ __launch_bounds__(256) void k_gemm(
    const float* __restrict__ A1, const float* __restrict__ W1, int ldW1,
    const float* __restrict__ deg,
    const float* __restrict__ A2, const float* __restrict__ W2, int ldW2,
    const float* __restrict__ bias, void* __restrict__ Cout,
    int Nrows, int M, int Kout, int relu) {
  __shared__ alignas(16) float sA[32][128];
  __shared__ alignas(16) float sW[128][128];
  const int tid = threadIdx.x;
  const int tx = tid & 31;   // 4-col group
  const int ty = tid >> 5;   // 4-row group
  const int row0 = blockIdx.x * 32;
  const int col0 = blockIdx.y * 128;
  const int KT = min(128, Kout - col0);

  float acc[4][4] = {};

  const float* As[2] = {A1, A2};
  const float* Ws[2] = {W1, W2};
  const int lds[2] = {ldW1, ldW2};
  for (int pass = 0; pass < 2; ++pass) {
    const float* A = As[pass];
    const float* W = Ws[pass];
    const int ldW = lds[pass];
    if (!A) break;
    for (int i = tid; i < 32 * M; i += 256) {
      int r = i / M, k = i - r * M;
      int gr = row0 + r;
      float v = 0.f;
      if (gr < Nrows) {
        v = A[(size_t)gr * M + k];
        if (pass == 0 && deg) v /= fmaxf(deg[gr], 1.0f);
      }
      sA[r][k] = v;
    }
    for (int i = tid; i < (M << 7); i += 256) {
      int k = i >> 7, c = i & 127;
      sW[k][c] = (c < KT) ? W[(size_t)k * ldW + col0 + c] : 0.f;
    }
    __syncthreads();
    #pragma unroll 4
    for (int k = 0; k < M; ++k) {
      float4 w = *reinterpret_cast<const float4*>(&sW[k][tx << 2]);
      #pragma unroll
      for (int i = 0; i < 4; ++i) {
        float a = sA[(ty << 2) + i][k];
        acc[i][0] = fmaf(a, w.x, acc[i][0]);
        acc[i][1] = fmaf(a, w.y, acc[i][1]);
        acc[i][2] = fmaf(a, w.z, acc[i][2]);
        acc[i][3] = fmaf(a, w.w, acc[i][3]);
      }
    }
    __syncthreads();
  }

  if ((tx << 2) >= KT) return;
  float4 bv = make_float4(0.f, 0.f, 0.f, 0.f);
  if (bias) bv = *reinterpret_cast<const float4*>(bias + col0 + (tx << 2));
  #pragma unroll
  for (int i = 0; i < 4; ++i) {
    int gr = row0 + (ty << 2) + i;
    if (gr >= Nrows) continue;
    float o0 = acc[i][0] + bv.x, o1 = acc[i][1] + bv.y;
    float o2 = acc[i][2] + bv.z, o3 = acc[i][3] + bv.w;
    if (relu) {
      o0 = fmaxf(o0, 0.f); o1 = fmaxf(o1, 0.f);
      o2 = fmaxf(o2, 0.f); o3 = fmaxf(o3, 0.f);
    }
    if (OBF16) {
      ushort4 u;
      u.x = f2bf(o0); u.y = f2bf(o1); u.z = f2bf(o2); u.w = f2bf(o3);
      *reinterpret_cast<ushort4*>((unsigned short*)Cout + (size_t)gr * Kout + col0 + (tx << 2)) = u;
    } else {
      float4 o; o.x = o0; o.y = o1; o.z = o2; o.w = o3;
      *reinterpret_cast<float4*>((float*)Cout + (size_t)gr * Kout + col0 + (tx << 2)) = o;
    }
  }
}

// ---- per-column sum / sumsq (K in {64,128}) ------------------------------
__global__ void k_stats(const float* __restrict__ X, float* __restrict__ stats,
                        int Nrows, int K) {
  int c = threadIdx.x & (K - 1);
  int rl = threadIdx.x / K;
  int rpb = 256 / K;
  float s = 0.f, s2 = 0.f;
  for (long r = (long)blockIdx.x * rpb + rl; r < Nrows; r += (long)gridDim.x * rpb) {
    float v = X[r * K + c];
    s += v;
    s2 = fmaf(v, v, s2);
  }
  __shared__ float b1s[256], b2s[256];
  b1s[threadIdx.x] = s; b2s[threadIdx.x] = s2;
  __syncthreads();
  if (rl == 0) {
    for (int t = 1; t < rpb; ++t) { s += b1s[t * K + c]; s2 += b2s[t * K + c]; }
    atomicAdd(&stats[c], s);
    atomicAdd(&stats[128 + c], s2);
  }
}

// ---- BN + ReLU (+ optional residual added after relu), in place ---------
__global__ void k_bn(float* __restrict__ X, const float* __restrict__ stats,
                     const float* __restrict__ g, const float* __restrict__ b,
                     const void* __restrict__ addAfter, int addBf16,
                     int Nrows, int K) {
  long i = (long)blockIdx.x * blockDim.x + threadIdx.x;
  if (i >= (long)Nrows * K) return;
  int c = (int)(i & (K - 1));
  float invN = 1.0f / (float)Nrows;
  float m = stats[c] * invN;
  float v = stats[128 + c] * invN - m * m;
  float y = g[c] * (X[i] - m) * rsqrtf(v + 1e-5f) + b[c];
  y = fmaxf(y, 0.f);
  if (addAfter) {
    float add = addBf16 ? bf2f(((const unsigned short*)addAfter)[i])
                        : ((const float*)addAfter)[i];
    y += add;
  }
  X[i] = y;
}

// ---- fold attention vectors: attw[k][j] (j<4: Ws head j, j>=4: Wd head j-4)
__global__ void k_foldatt(const float* __restrict__ Wg, const float* __restrict__ atts,
                          const float* __restrict__ attd, float* __restrict__ attw) {
  int t = blockIdx.x * blockDim.x + threadIdx.x;
  if (t >= 1024) return;
  int k = t >> 3, j = t & 7, h = j & 3;
  const float* av = (j < 4 ? atts : attd) + h * 128;
  const float* wg = Wg + (size_t)k * 512 + h * 128;
  float s = 0.f;
  for (int c = 0; c < 128; ++c) s = fmaf(wg[c], av[c], s);
  attw[t] = s;
}

// ---- a_s/a_d per node: one wave each, grid-stride ------------------------
__global__ void k_attdots(const float* __restrict__ h1, const float* __restrict__ attw,
                          float* __restrict__ asad, int Nrows) {
  int lane = threadIdx.x & 63;
  float c0[8], c1[8];
  #pragma unroll
  for (int j = 0; j < 8; ++j) {
    c0[j] = attw[(2 * lane) * 8 + j];
    c1[j] = attw[(2 * lane + 1) * 8 + j];
  }
  long wid = ((long)blockIdx.x * blockDim.x + threadIdx.x) >> 6;
  long nw = ((long)gridDim.x * blockDim.x) >> 6;
  for (long n = wid; n < Nrows; n += nw) {
    float2 v = *reinterpret_cast<const float2*>(h1 + (n << 7) + (lane << 1));
    float a[8];
    #pragma unroll
    for (int j = 0; j < 8; ++j) a[j] = v.x * c0[j] + v.y * c1[j];
    #pragma unroll
    for (int off = 1; off < 64; off <<= 1) {
      #pragma unroll
      for (int j = 0; j < 8; ++j) a[j] += __shfl_xor(a[j], off);
    }
    if (lane == 0) {
      *reinterpret_cast<float4*>(asad + n * 8)     = make_float4(a[0], a[1], a[2], a[3]);
      *reinterpret_cast<float4*>(asad + n * 8 + 4) = make_float4(a[4], a[5], a[6], a[7]);
    }
  }
}

// ---- edge pass 1: e = lrelu(a_s[src]+a_d[dst]); segment max over dst ------
__global__ void k_edge1(const int* __restrict__ src, const int* __restrict__ dst,
                        const float* __restrict__ asad,
                        float* __restrict__ eouts, unsigned* __restrict__ emax, int E) {
  int e = blockIdx.x * blockDim.x + threadIdx.x;
  if (e >= E) return;
  int s = src[e], d = dst[e];
  float4 a = *reinterpret_cast<const float4*>(asad + (size_t)s * 8);
  float4 b = *reinterpret_cast<const float4*>(asad + (size_t)d * 8 + 4);
  float4 ev;
  ev.x = a.x + b.x; ev.y = a.y + b.y; ev.z = a.z + b.z; ev.w = a.w + b.w;
  ev.x = ev.x >= 0.f ? ev.x : 0.2f * ev.x;
  ev.y = ev.y >= 0.f ? ev.y : 0.2f * ev.y;
  ev.z = ev.z >= 0.f ? ev.z : 0.2f * ev.z;
  ev.w = ev.w >= 0.f ? ev.w : 0.2f * ev.w;
  *reinterpret_cast<float4*>(eouts + (size_t)e * 4) = ev;
  unsigned* em = emax + (size_t)d * 4;
  atomicMax(em + 0, encf(ev.x)); atomicMax(em + 1, encf(ev.y));
  atomicMax(em + 2, encf(ev.z)); atomicMax(em + 3, encf(ev.w));
}

// ---- edge pass 2: ee = exp(e - emax[dst]); denom[dst] += ee ---------------
__global__ void k_edge2(const int* __restrict__ dst, float* __restrict__ ee,
                        const unsigned* __restrict__ emax, float* __restrict__ denom, int E) {
  int e = blockIdx.x * blockDim.x + threadIdx.x;
  if (e >= E) return;
  int d = dst[e];
  float4 ev = *reinterpret_cast<const float4*>(ee + (size_t)e * 4);
  const unsigned* em = emax + (size_t)d * 4;
  float4 x;
  x.x = expf(ev.x - decf(em[0]));
  x.y = expf(ev.y - decf(em[1]));
  x.z = expf(ev.z - decf(em[2]));
  x.w = expf(ev.w - decf(em[3]));
  *reinterpret_cast<float4*>(ee + (size_t)e * 4) = x;
  float* dn = denom + (size_t)d * 4;
  atomicAdd(dn + 0, x.x); atomicAdd(dn + 1, x.y);
  atomicAdd(dn + 2, x.z); atomicAdd(dn + 3, x.w);
}

// ---- edge pass 3 (per head group): h2[dst] += 0.25*sum_g alpha_g*xh[src,g,:]
__global__ void k_gatscG(const __hip_bfloat16* __restrict__ xh, const int* __restrict__ src,
                         const int* __restrict__ dst, const float* __restrict__ ee,
                         const float* __restrict__ denom, float* __restrict__ out,
                         int E, int G, int h0) {
  long tid = (long)blockIdx.x * blockDim.x + threadIdx.x;
  int e = (int)(tid >> 5);
  if (e >= E) return;
  int j = ((int)tid & 31) << 2;
  int s = src[e], d = dst[e];
  float o0 = 0.f, o1 = 0.f, o2 = 0.f, o3 = 0.f;
  for (int g = 0; g < G; ++g) {
    float a = 0.25f * ee[(size_t)e * 4 + h0 + g]
                    / fmaxf(denom[(size_t)d * 4 + h0 + g], 1e-16f);
    const unsigned short* xr =
        (const unsigned short*)xh + ((size_t)s * G + g) * 128 + j;
    ushort4 u = *reinterpret_cast<const ushort4*>(xr);
    o0 = fmaf(a, bf2f(u.x), o0);
    o1 = fmaf(a, bf2f(u.y), o1);
    o2 = fmaf(a, bf2f(u.z), o2);
    o3 = fmaf(a, bf2f(u.w), o3);
  }
  float* p = out + (size_t)d * 128 + j;
  atomicAdd(p + 0, o0); atomicAdd(p + 1, o1);
  atomicAdd(p + 2, o2); atomicAdd(p + 3, o3);
}

// ---- final: logits = z2 @ Wc3 + bc3; log_softmax --------------------------
__global__ void k_final(const float* __restrict__ z2, const float* __restrict__ W,
                        const float* __restrict__ b, float* __restrict__ out, int Nrows) {
  int n = blockIdx.x * blockDim.x + threadIdx.x;
  if (n >= Nrows) return;
  float l0 = b[0], l1 = b[1];
  const float* z = z2 + (size_t)n * 32;
  #pragma unroll
  for (int k = 0; k < 32; ++k) {
    float v = z[k];
    l0 = fmaf(v, W[2 * k], l0);
    l1 = fmaf(v, W[2 * k + 1], l1);
  }
  float m = fmaxf(l0, l1);
  float lse = m + logf(expf(l0 - m) + expf(l1 - m));
  out[2 * n] = l0 - lse;
  out[2 * n + 1] = l1 - lse;
}

// ---------------------------------------------------------------------------
extern "C" void kernel_launch(void* const* d_in, const int* in_sizes, int n_in,
                              void* d_out, int out_size, void* d_ws, size_t ws_size,
                              hipStream_t stream) {
  const float* x    = (const float*)d_in[0];
  const int*   ei   = (const int*)  d_in[1];
  const float* Wl1  = (const float*)d_in[2];
  const float* Wr1  = (const float*)d_in[3];
  const float* b1   = (const float*)d_in[4];
  const float* g1   = (const float*)d_in[5];
  const float* be1  = (const float*)d_in[6];
  const float* Wg   = (const float*)d_in[7];
  const float* atts = (const float*)d_in[8];
  const float* attd = (const float*)d_in[9];
  // d_in[10] = bg: constant column offset, cancels exactly in the following BN.
  const float* g2   = (const float*)d_in[11];
  const float* be2  = (const float*)d_in[12];
  const float* Wl3  = (const float*)d_in[13];
  const float* Wr3  = (const float*)d_in[14];
  const float* b3   = (const float*)d_in[15];
  const float* g3   = (const float*)d_in[16];
  const float* be3  = (const float*)d_in[17];
  const float* Wsk  = (const float*)d_in[18];
  const float* bsk  = (const float*)d_in[19];
  const float* Wc1  = (const float*)d_in[20];
  const float* bc1  = (const float*)d_in[21];
  const float* gc   = (const float*)d_in[22];
  const float* bec  = (const float*)d_in[23];
  const float* Wc2  = (const float*)d_in[24];
  const float* bc2  = (const float*)d_in[25];
  const float* Wc3  = (const float*)d_in[26];
  const float* bc3  = (const float*)d_in[27];
  (void)n_in; (void)out_size;

  const int N = in_sizes[0] / 128;
  const int E = in_sizes[1] / 2;
  const int* src = ei;
  const int* dst = ei + E;

  // ---- workspace carve-out (fp32 words), 16B-aligned regions --------------
  auto al4 = [](size_t w) { return (w + 3) & ~(size_t)3; };
  float* ws = (float*)d_ws;
  size_t o = 0;
  float* deg    = ws + o; o += al4((size_t)N);
  unsigned short* idbf = (unsigned short*)(ws + o); o += al4((size_t)N * 32);  // [N,64] bf16
  float* stats  = ws + o; o += 1024;
  float* attw   = ws + o; o += 1024;
  float* asad   = ws + o; o += al4((size_t)N * 8);
  unsigned* emaxb = (unsigned*)(ws + o); o += al4((size_t)N * 4);
  float* denom  = ws + o; o += al4((size_t)N * 4);
  float* ee     = ws + o; o += al4((size_t)E * 4);
  float* bufA   = ws + o; o += (size_t)N * 128;   // agg1 / agg3 / z1
  float* hB     = ws + o; o += (size_t)N * 128;   // h1 / h3+z2
  float* h2     = ws + o; o += (size_t)N * 128;
  unsigned short* xh = (unsigned short*)(ws + o); // [N, G*128] bf16

  long avail = (long)(ws_size / 4) - (long)o;
  int G = 4;
  while (G > 1 && (long)N * 64 * G > avail) G >>= 1;

  float* st1 = stats, *st2 = stats + 256, *st3 = stats + 512, *st4 = stats + 768;
  float* h3 = hB;
  float* z1 = bufA;
  float* z2 = hB + (size_t)N * 64;

  dim3 blk(256);
  int gE     = (E + 255) / 256;
  int gN32   = (N + 31) / 32;
  int gESC   = (int)(((long)E * 32 + 255) / 256);
  int gBN128 = (int)(((long)N * 128 + 255) / 256);
  int gBN64  = (int)(((long)N * 64 + 255) / 256);

  hipMemsetAsync(deg, 0, (size_t)N * 4, stream);
  hipMemsetAsync(stats, 0, 1024 * 4, stream);
  hipMemsetAsync(bufA, 0, (size_t)N * 128 * 4, stream);

  // ---- SAGE1 ----
  k_deg<<<gE, blk, 0, stream>>>(dst, deg, E);
  k_scatter128<<<gESC, blk, 0, stream>>>(x, src, dst, bufA, E);
  k_gemm<true><<<dim3(gN32, 1), blk, 0, stream>>>(
      x, Wsk, 64, nullptr, nullptr, nullptr, 0, bsk, idbf, N, 128, 64, 0);
  k_gemm<false><<<dim3(gN32, 1), blk, 0, stream>>>(
      bufA, Wl1, 128, deg, x, Wr1, 128, b1, hB, N, 128, 128, 0);
  k_stats<<<256, blk, 0, stream>>>(hB, st1, N, 128);
  k_bn<<<gBN128, blk, 0, stream>>>(hB, st1, g1, be1, nullptr, 0, N, 128);

  // ---- GAT ----
  k_foldatt<<<4, blk, 0, stream>>>(Wg, atts, attd, attw);
  k_attdots<<<2048, blk, 0, stream>>>(hB, attw, asad, N);
  k_initmax<<<(N * 4 + 255) / 256, blk, 0, stream>>>(emaxb, N * 4);
  hipMemsetAsync(denom, 0, (size_t)N * 4 * 4, stream);
  k_edge1<<<gE, blk, 0, stream>>>(src, dst, asad, ee, emaxb, E);
  k_edge2<<<gE, blk, 0, stream>>>(dst, ee, emaxb, denom, E);
  hipMemsetAsync(h2, 0, (size_t)N * 128 * 4, stream);
  for (int h0 = 0; h0 < 4; h0 += G) {
    k_gemm<true><<<dim3(gN32, G), blk, 0, stream>>>(
        hB, Wg + h0 * 128, 512, nullptr, nullptr, nullptr, 0, nullptr,
        xh, N, 128, G * 128, 0);
    k_gatscG<<<gESC, blk, 0, stream>>>((__hip_bfloat16*)xh, src, dst, ee, denom, h2, E, G, h0);
  }
  k_stats<<<256, blk, 0, stream>>>(h2, st2, N, 128);
  k_bn<<<gBN128, blk, 0, stream>>>(h2, st2, g2, be2, nullptr, 0, N, 128);

  // ---- SAGE3 ----
  hipMemsetAsync(bufA, 0, (size_t)N * 128 * 4, stream);
  k_scatter128<<<gESC, blk, 0, stream>>>(h2, src, dst, bufA, E);
  k_gemm<false><<<dim3(gN32, 1), blk, 0, stream>>>(
      bufA, Wl3, 64, deg, h2, Wr3, 64, b3, h3, N, 128, 64, 0);
  k_stats<<<256, blk, 0, stream>>>(h3, st3, N, 64);
  k_bn<<<gBN64, blk, 0, stream>>>(h3, st3, g3, be3, idbf, 1, N, 64);  // +identity

  // ---- classifier ----
  k_gemm<false><<<dim3(gN32, 1), blk, 0, stream>>>(
      h3, Wc1, 64, nullptr, nullptr, nullptr, 0, bc1, z1, N, 64, 64, 0);
  k_stats<<<256, blk, 0, stream>>>(z1, st4, N, 64);
  k_bn<<<gBN64, blk, 0, stream>>>(z1, st4, gc, bec, nullptr, 0, N, 64);
  k_gemm<false><<<dim3(gN32, 1), blk, 0, stream>>>(
      z1, Wc2, 32, nullptr, nullptr, nullptr, 0, bc2, z2, N, 64, 32, 1);
  k_final<<<(N + 255) / 256, blk, 0, stream>>>(z2, Wc3, bc3, (float*)d_out, N);
}

// Round 3
// 2355.686 us; speedup vs baseline: 1.9623x; 1.9623x over previous
//
#include <hip/hip_runtime.h>
#include <hip/hip_bf16.h>
#include <cmath>

// ---------------------------------------------------------------------------
// MuleHunterGNN: SAGE -> GAT -> SAGE -> skip -> MLP classifier
// CSR-gather aggregation (no scatter atomics), fp32 compute,
// bf16 for bulky read-only intermediates (xh, identity).
// ---------------------------------------------------------------------------

__device__ __forceinline__ float bf2f(unsigned short u) {
  return __uint_as_float((unsigned)u << 16);
}
__device__ __forceinline__ unsigned short f2bf(float f) {
  __hip_bfloat16 h = __float2bfloat16(f);
  return *reinterpret_cast<unsigned short*>(&h);
}

// ---- CSR build -----------------------------------------------------------
__global__ void k_hist(const int* __restrict__ dst, int* __restrict__ cnt, int E) {
  int e = blockIdx.x * blockDim.x + threadIdx.x;
  if (e < E) atomicAdd(&cnt[dst[e]], 1);
}

// single-block exclusive scan: indptr[0]=0, indptr[i+1]=sum(cnt[0..i])
__global__ __launch_bounds__(1024) void k_scan(const int* __restrict__ cnt,
                                               int* __restrict__ indptr, int N) {
  __shared__ int wsum[16];
  __shared__ int carry;
  int lane = threadIdx.x & 63, w = threadIdx.x >> 6;
  if (threadIdx.x == 0) { carry = 0; indptr[0] = 0; }
  __syncthreads();
  for (int base = 0; base < N; base += 1024) {
    int i = base + threadIdx.x;
    int v = (i < N) ? cnt[i] : 0;
    #pragma unroll
    for (int off = 1; off < 64; off <<= 1) {
      int t = __shfl_up(v, off);
      if (lane >= off) v += t;
    }
    if (lane == 63) wsum[w] = v;
    __syncthreads();
    int add = carry;
    for (int j = 0; j < w; ++j) add += wsum[j];
    if (i < N) indptr[i + 1] = v + add;
    __syncthreads();
    if (threadIdx.x == 0) {
      int s = 0;
      for (int j = 0; j < 16; ++j) s += wsum[j];
      carry += s;
    }
    __syncthreads();
  }
}

__global__ void k_fill(const int* __restrict__ src, const int* __restrict__ dst,
                       int* __restrict__ cursor, int* __restrict__ csr_src, int E) {
  int e = blockIdx.x * blockDim.x + threadIdx.x;
  if (e >= E) return;
  int pos = atomicAdd(&cursor[dst[e]], 1);
  csr_src[pos] = src[e];
}

// ---- gather mean of 128-wide rows: out[d] = mean_{e in N(d)} X[src_e] -----
__global__ __launch_bounds__(256) void k_gmean(const float* __restrict__ X,
                                               const int* __restrict__ indptr,
                                               const int* __restrict__ csr,
                                               float* __restrict__ out, int N) {
  long wid = ((long)blockIdx.x * blockDim.x + threadIdx.x) >> 6;
  if (wid >= N) return;
  int lane = threadIdx.x & 63;
  int b = indptr[wid], en = indptr[wid + 1];
  float2 acc = make_float2(0.f, 0.f);
  for (int i = b; i < en; ++i) {
    int s = csr[i];
    float2 v = *reinterpret_cast<const float2*>(X + ((size_t)s << 7) + (lane << 1));
    acc.x += v.x; acc.y += v.y;
  }
  float inv = 1.0f / (float)max(en - b, 1);
  acc.x *= inv; acc.y *= inv;
  *reinterpret_cast<float2*>(out + (wid << 7) + (lane << 1)) = acc;
}

// ---- GAT gather: softmax over in-edges + weighted mean over heads ---------
// xh: [N, G*128] bf16 (heads h0..h0+G-1). out[d] (+)= 0.25*sum_g alpha*xh[src,g,:]
__global__ __launch_bounds__(256) void k_gatg(
    const unsigned short* __restrict__ xh, const int* __restrict__ indptr,
    const int* __restrict__ csr, const float* __restrict__ asad,
    float* __restrict__ out, int N, int G, int h0) {
  long wid = ((long)blockIdx.x * blockDim.x + threadIdx.x) >> 6;
  if (wid >= N) return;
  int lane = threadIdx.x & 63;
  int b = indptr[wid], en = indptr[wid + 1];

  float ad[4];
  {
    float4 t = *reinterpret_cast<const float4*>(asad + wid * 8 + 4);
    ad[0] = t.x; ad[1] = t.y; ad[2] = t.z; ad[3] = t.w;
  }
  // pass 1: per-head max of leaky_relu(a_s[src]+a_d[dst])
  float m[4] = {-INFINITY, -INFINITY, -INFINITY, -INFINITY};
  for (int i = b; i < en; ++i) {
    int s = csr[i];
    float4 as4 = *reinterpret_cast<const float4*>(asad + (size_t)s * 8);
    float e0 = as4.x + ad[0], e1 = as4.y + ad[1];
    float e2 = as4.z + ad[2], e3 = as4.w + ad[3];
    e0 = e0 >= 0.f ? e0 : 0.2f * e0; e1 = e1 >= 0.f ? e1 : 0.2f * e1;
    e2 = e2 >= 0.f ? e2 : 0.2f * e2; e3 = e3 >= 0.f ? e3 : 0.2f * e3;
    m[0] = fmaxf(m[0], e0); m[1] = fmaxf(m[1], e1);
    m[2] = fmaxf(m[2], e2); m[3] = fmaxf(m[3], e3);
  }
  // pass 2: accumulate exp-weighted features and denominators
  float den[4] = {0.f, 0.f, 0.f, 0.f};
  float accx[4] = {0.f, 0.f, 0.f, 0.f};
  float accy[4] = {0.f, 0.f, 0.f, 0.f};
  for (int i = b; i < en; ++i) {
    int s = csr[i];
    float4 as4 = *reinterpret_cast<const float4*>(asad + (size_t)s * 8);
    float e[4];
    e[0] = as4.x + ad[0]; e[1] = as4.y + ad[1];
    e[2] = as4.z + ad[2]; e[3] = as4.w + ad[3];
    const unsigned short* xr = xh + (size_t)s * (G << 7) + (lane << 1);
    #pragma unroll 4
    for (int g = 0; g < G; ++g) {
      int h = h0 + g;
      float ev = e[h];
      ev = ev >= 0.f ? ev : 0.2f * ev;
      float w = __expf(ev - m[h]);
      den[g] += w;
      ushort2 u = *reinterpret_cast<const ushort2*>(xr + (g << 7));
      accx[g] = fmaf(w, bf2f(u.x), accx[g]);
      accy[g] = fmaf(w, bf2f(u.y), accy[g]);
    }
  }
  float ox = 0.f, oy = 0.f;
  #pragma unroll 4
  for (int g = 0; g < G; ++g) {
    float inv = 0.25f / fmaxf(den[g], 1e-16f);
    ox = fmaf(accx[g], inv, ox);
    oy = fmaf(accy[g], inv, oy);
  }
  float* po = out + (wid << 7) + (lane << 1);
  if (h0 > 0) { ox += po[0]; oy += po[1]; }
  *reinterpret_cast<float2*>(po) = make_float2(ox, oy);
}

// ---- fused GEMM: C = A1 @ W1 [+ A2 @ W2] + bias; optional bf16 out --------
template <bool OBF16>
__global__ __launch_bounds__(256) void k_gemm(
    const float* __restrict__ A1, const float* __restrict__ W1, int ldW1,
    const float* __restrict__ A2, const float* __restrict__ W2, int ldW2,
    const float* __restrict__ bias, void* __restrict__ Cout,
    int Nrows, int M, int Kout, int relu) {
  __shared__ alignas(16) float sA[32][128];
  __shared__ alignas(16) float sW[128][128];
  const int tid = threadIdx.x;
  const int tx = tid & 31;
  const int ty = tid >> 5;
  const int row0 = blockIdx.x * 32;
  const int col0 = blockIdx.y * 128;
  const int KT = min(128, Kout - col0);

  float acc[4][4] = {};

  const float* As[2] = {A1, A2};
  const float* Ws[2] = {W1, W2};
  const int lds[2] = {ldW1, ldW2};
  for (int pass = 0; pass < 2; ++pass) {
    const float* A = As[pass];
    const float* W = Ws[pass];
    const int ldW = lds[pass];
    if (!A) break;
    for (int i = tid; i < 32 * M; i += 256) {
      int r = i / M, k = i - r * M;
      int gr = row0 + r;
      sA[r][k] = (gr < Nrows) ? A[(size_t)gr * M + k] : 0.f;
    }
    for (int i = tid; i < (M << 7); i += 256) {
      int k = i >> 7, c = i & 127;
      sW[k][c] = (c < KT) ? W[(size_t)k * ldW + col0 + c] : 0.f;
    }
    __syncthreads();
    #pragma unroll 4
    for (int k = 0; k < M; ++k) {
      float4 w = *reinterpret_cast<const float4*>(&sW[k][tx << 2]);
      #pragma unroll
      for (int i = 0; i < 4; ++i) {
        float a = sA[(ty << 2) + i][k];
        acc[i][0] = fmaf(a, w.x, acc[i][0]);
        acc[i][1] = fmaf(a, w.y, acc[i][1]);
        acc[i][2] = fmaf(a, w.z, acc[i][2]);
        acc[i][3] = fmaf(a, w.w, acc[i][3]);
      }
    }
    __syncthreads();
  }

  if ((tx << 2) >= KT) return;
  float4 bv = make_float4(0.f, 0.f, 0.f, 0.f);
  if (bias) bv = *reinterpret_cast<const float4*>(bias + col0 + (tx << 2));
  #pragma unroll
  for (int i = 0; i < 4; ++i) {
    int gr = row0 + (ty << 2) + i;
    if (gr >= Nrows) continue;
    float o0 = acc[i][0] + bv.x, o1 = acc[i][1] + bv.y;
    float o2 = acc[i][2] + bv.z, o3 = acc[i][3] + bv.w;
    if (relu) {
      o0 = fmaxf(o0, 0.f); o1 = fmaxf(o1, 0.f);
      o2 = fmaxf(o2, 0.f); o3 = fmaxf(o3, 0.f);
    }
    if (OBF16) {
      ushort4 u;
      u.x = f2bf(o0); u.y = f2bf(o1); u.z = f2bf(o2); u.w = f2bf(o3);
      *reinterpret_cast<ushort4*>((unsigned short*)Cout + (size_t)gr * Kout + col0 + (tx << 2)) = u;
    } else {
      float4 o; o.x = o0; o.y = o1; o.z = o2; o.w = o3;
      *reinterpret_cast<float4*>((float*)Cout + (size_t)gr * Kout + col0 + (tx << 2)) = o;
    }
  }
}

// ---- per-column sum / sumsq (K in {64,128}) -------------------------------
__global__ void k_stats(const float* __restrict__ X, float* __restrict__ stats,
                        int Nrows, int K) {
  int c = threadIdx.x & (K - 1);
  int rl = threadIdx.x / K;
  int rpb = 256 / K;
  float s = 0.f, s2 = 0.f;
  for (long r = (long)blockIdx.x * rpb + rl; r < Nrows; r += (long)gridDim.x * rpb) {
    float v = X[r * K + c];
    s += v;
    s2 = fmaf(v, v, s2);
  }
  __shared__ float b1s[256], b2s[256];
  b1s[threadIdx.x] = s; b2s[threadIdx.x] = s2;
  __syncthreads();
  if (rl == 0) {
    for (int t = 1; t < rpb; ++t) { s += b1s[t * K + c]; s2 += b2s[t * K + c]; }
    atomicAdd(&stats[c], s);
    atomicAdd(&stats[128 + c], s2);
  }
}

// ---- BN + ReLU (+ optional bf16 residual added after relu), in place ------
__global__ void k_bn(float* __restrict__ X, const float* __restrict__ stats,
                     const float* __restrict__ g, const float* __restrict__ b,
                     const unsigned short* __restrict__ addAfter,
                     int Nrows, int K) {
  long i = (long)blockIdx.x * blockDim.x + threadIdx.x;
  if (i >= (long)Nrows * K) return;
  int c = (int)(i & (K - 1));
  float invN = 1.0f / (float)Nrows;
  float m = stats[c] * invN;
  float v = stats[128 + c] * invN - m * m;
  float y = g[c] * (X[i] - m) * rsqrtf(v + 1e-5f) + b[c];
  y = fmaxf(y, 0.f);
  if (addAfter) y += bf2f(addAfter[i]);
  X[i] = y;
}

// ---- fold attention vectors: attw[k][j] (j<4: Wg@att_s head j, j>=4: att_d)
__global__ void k_foldatt(const float* __restrict__ Wg, const float* __restrict__ atts,
                          const float* __restrict__ attd, float* __restrict__ attw) {
  int t = blockIdx.x * blockDim.x + threadIdx.x;
  if (t >= 1024) return;
  int k = t >> 3, j = t & 7, h = j & 3;
  const float* av = (j < 4 ? atts : attd) + h * 128;
  const float* wg = Wg + (size_t)k * 512 + h * 128;
  float s = 0.f;
  for (int c = 0; c < 128; ++c) s = fmaf(wg[c], av[c], s);
  attw[t] = s;
}

// ---- a_s/a_d per node: one wave each, grid-stride --------------------------
__global__ void k_attdots(const float* __restrict__ h1, const float* __restrict__ attw,
                          float* __restrict__ asad, int Nrows) {
  int lane = threadIdx.x & 63;
  float c0[8], c1[8];
  #pragma unroll
  for (int j = 0; j < 8; ++j) {
    c0[j] = attw[(2 * lane) * 8 + j];
    c1[j] = attw[(2 * lane + 1) * 8 + j];
  }
  long wid = ((long)blockIdx.x * blockDim.x + threadIdx.x) >> 6;
  long nw = ((long)gridDim.x * blockDim.x) >> 6;
  for (long n = wid; n < Nrows; n += nw) {
    float2 v = *reinterpret_cast<const float2*>(h1 + (n << 7) + (lane << 1));
    float a[8];
    #pragma unroll
    for (int j = 0; j < 8; ++j) a[j] = v.x * c0[j] + v.y * c1[j];
    #pragma unroll
    for (int off = 1; off < 64; off <<= 1) {
      #pragma unroll
      for (int j = 0; j < 8; ++j) a[j] += __shfl_xor(a[j], off);
    }
    if (lane == 0) {
      *reinterpret_cast<float4*>(asad + n * 8)     = make_float4(a[0], a[1], a[2], a[3]);
      *reinterpret_cast<float4*>(asad + n * 8 + 4) = make_float4(a[4], a[5], a[6], a[7]);
    }
  }
}

// ---- final: logits = z2 @ Wc3 + bc3; log_softmax ---------------------------
__global__ void k_final(const float* __restrict__ z2, const float* __restrict__ W,
                        const float* __restrict__ b, float* __restrict__ out, int Nrows) {
  int n = blockIdx.x * blockDim.x + threadIdx.x;
  if (n >= Nrows) return;
  float l0 = b[0], l1 = b[1];
  const float* z = z2 + (size_t)n * 32;
  #pragma unroll
  for (int k = 0; k < 32; ++k) {
    float v = z[k];
    l0 = fmaf(v, W[2 * k], l0);
    l1 = fmaf(v, W[2 * k + 1], l1);
  }
  float m = fmaxf(l0, l1);
  float lse = m + logf(expf(l0 - m) + expf(l1 - m));
  out[2 * n] = l0 - lse;
  out[2 * n + 1] = l1 - lse;
}

// ---------------------------------------------------------------------------
extern "C" void kernel_launch(void* const* d_in, const int* in_sizes, int n_in,
                              void* d_out, int out_size, void* d_ws, size_t ws_size,
                              hipStream_t stream) {
  const float* x    = (const float*)d_in[0];
  const int*   ei   = (const int*)  d_in[1];
  const float* Wl1  = (const float*)d_in[2];
  const float* Wr1  = (const float*)d_in[3];
  const float* b1   = (const float*)d_in[4];
  const float* g1   = (const float*)d_in[5];
  const float* be1  = (const float*)d_in[6];
  const float* Wg   = (const float*)d_in[7];
  const float* atts = (const float*)d_in[8];
  const float* attd = (const float*)d_in[9];
  // d_in[10] = bg: constant column offset, cancels exactly in the following BN.
  const float* g2   = (const float*)d_in[11];
  const float* be2  = (const float*)d_in[12];
  const float* Wl3  = (const float*)d_in[13];
  const float* Wr3  = (const float*)d_in[14];
  const float* b3   = (const float*)d_in[15];
  const float* g3   = (const float*)d_in[16];
  const float* be3  = (const float*)d_in[17];
  const float* Wsk  = (const float*)d_in[18];
  const float* bsk  = (const float*)d_in[19];
  const float* Wc1  = (const float*)d_in[20];
  const float* bc1  = (const float*)d_in[21];
  const float* gc   = (const float*)d_in[22];
  const float* bec  = (const float*)d_in[23];
  const float* Wc2  = (const float*)d_in[24];
  const float* bc2  = (const float*)d_in[25];
  const float* Wc3  = (const float*)d_in[26];
  const float* bc3  = (const float*)d_in[27];
  (void)n_in; (void)out_size;

  const int N = in_sizes[0] / 128;
  const int E = in_sizes[1] / 2;
  const int* src = ei;
  const int* dst = ei + E;

  // ---- workspace carve-out (fp32 words), 16B-aligned regions ---------------
  auto al4 = [](size_t w) { return (w + 3) & ~(size_t)3; };
  float* ws = (float*)d_ws;
  size_t o = 0;
  int* cnt      = (int*)(ws + o); o += al4((size_t)N);
  int* indptr   = (int*)(ws + o); o += al4((size_t)N + 1);
  int* cursor   = (int*)(ws + o); o += al4((size_t)N);
  int* csr_src  = (int*)(ws + o); o += al4((size_t)E);
  unsigned short* idbf = (unsigned short*)(ws + o); o += al4((size_t)N * 32);  // [N,64] bf16
  float* stats  = ws + o; o += 1024;
  float* attw   = ws + o; o += 1024;
  float* asad   = ws + o; o += al4((size_t)N * 8);
  float* bufA   = ws + o; o += (size_t)N * 128;   // mean1 / mean3 / z1
  float* hB     = ws + o; o += (size_t)N * 128;   // h1 / h3+z2
  float* h2     = ws + o; o += (size_t)N * 128;
  unsigned short* xh = (unsigned short*)(ws + o); // [N, G*128] bf16

  long avail = (long)(ws_size / 4) - (long)o;
  int G = 4;
  while (G > 1 && (long)N * 64 * G > avail) G >>= 1;

  float* st1 = stats, *st2 = stats + 256, *st3 = stats + 512, *st4 = stats + 768;
  float* h3 = hB;
  float* z1 = bufA;
  float* z2 = hB + (size_t)N * 64;

  dim3 blk(256);
  int gE     = (E + 255) / 256;
  int gN32   = (N + 31) / 32;
  int gW     = (int)(((long)N * 64 + 255) / 256);   // one wave per node
  int gBN128 = (int)(((long)N * 128 + 255) / 256);
  int gBN64  = (int)(((long)N * 64 + 255) / 256);

  hipMemsetAsync(cnt, 0, (size_t)N * 4, stream);
  hipMemsetAsync(stats, 0, 1024 * 4, stream);

  // ---- CSR build ----
  k_hist<<<gE, blk, 0, stream>>>(dst, cnt, E);
  k_scan<<<1, 1024, 0, stream>>>(cnt, indptr, N);
  hipMemcpyAsync(cursor, indptr, (size_t)N * 4, hipMemcpyDeviceToDevice, stream);
  k_fill<<<gE, blk, 0, stream>>>(src, dst, cursor, csr_src, E);

  // ---- SAGE1 ----
  k_gmean<<<gW, blk, 0, stream>>>(x, indptr, csr_src, bufA, N);
  k_gemm<true><<<dim3(gN32, 1), blk, 0, stream>>>(
      x, Wsk, 64, nullptr, nullptr, 0, bsk, idbf, N, 128, 64, 0);
  k_gemm<false><<<dim3(gN32, 1), blk, 0, stream>>>(
      bufA, Wl1, 128, x, Wr1, 128, b1, hB, N, 128, 128, 0);
  k_stats<<<256, blk, 0, stream>>>(hB, st1, N, 128);
  k_bn<<<gBN128, blk, 0, stream>>>(hB, st1, g1, be1, nullptr, N, 128);

  // ---- GAT ----
  k_foldatt<<<4, blk, 0, stream>>>(Wg, atts, attd, attw);
  k_attdots<<<2048, blk, 0, stream>>>(hB, attw, asad, N);
  for (int h0 = 0; h0 < 4; h0 += G) {
    k_gemm<true><<<dim3(gN32, G), blk, 0, stream>>>(
        hB, Wg + h0 * 128, 512, nullptr, nullptr, 0, nullptr,
        xh, N, 128, G * 128, 0);
    k_gatg<<<gW, blk, 0, stream>>>(xh, indptr, csr_src, asad, h2, N, G, h0);
  }
  k_stats<<<256, blk, 0, stream>>>(h2, st2, N, 128);
  k_bn<<<gBN128, blk, 0, stream>>>(h2, st2, g2, be2, nullptr, N, 128);

  // ---- SAGE3 ----
  k_gmean<<<gW, blk, 0, stream>>>(h2, indptr, csr_src, bufA, N);
  k_gemm<false><<<dim3(gN32, 1), blk, 0, stream>>>(
      bufA, Wl3, 64, h2, Wr3, 64, b3, h3, N, 128, 64, 0);
  k_stats<<<256, blk, 0, stream>>>(h3, st3, N, 64);
  k_bn<<<gBN64, blk, 0, stream>>>(h3, st3, g3, be3, idbf, N, 64);  // +identity

  // ---- classifier ----
  k_gemm<false><<<dim3(gN32, 1), blk, 0, stream>>>(
      h3, Wc1, 64, nullptr, nullptr, 0, bc1, z1, N, 64, 64, 0);
  k_stats<<<256, blk, 0, stream>>>(z1, st4, N, 64);
  k_bn<<<gBN64, blk, 0, stream>>>(z1, st4, gc, bec, nullptr, N, 64);
  k_gemm<false><<<dim3(gN32, 1), blk, 0, stream>>>(
      z1, Wc2, 32, nullptr, nullptr, 0, bc2, z2, N, 64, 32, 1);
  k_final<<<(N + 255) / 256, blk, 0, stream>>>(z2, Wc3, bc3, (float*)d_out, N);
}

// Round 6
// 1298.603 us; speedup vs baseline: 3.5597x; 1.8140x over previous
//
#include <hip/hip_runtime.h>
#include <hip/hip_bf16.h>
#include <cmath>

// ---------------------------------------------------------------------------
// MuleHunterGNN: SAGE -> GAT -> SAGE -> skip -> MLP classifier
// CSR-gather aggregation (no scatter atomics); all GEMMs on MFMA (bf16 in,
// fp32 accumulate); bf16 for bulky read-only intermediates (xh, identity).
// ---------------------------------------------------------------------------

typedef short s16x8 __attribute__((ext_vector_type(8)));
typedef float f32x4 __attribute__((ext_vector_type(4)));

__device__ __forceinline__ float bf2f(unsigned short u) {
  return __uint_as_float((unsigned)u << 16);
}
__device__ __forceinline__ unsigned short f2bf(float f) {
  __hip_bfloat16 h = __float2bfloat16(f);
  return *reinterpret_cast<unsigned short*>(&h);
}

// ---- CSR build -----------------------------------------------------------
__global__ void k_hist(const int* __restrict__ dst, int* __restrict__ cnt, int E) {
  int e = blockIdx.x * blockDim.x + threadIdx.x;
  if (e < E) atomicAdd(&cnt[dst[e]], 1);
}

// single-block exclusive scan: indptr[0]=0, indptr[i+1]=sum(cnt[0..i])
__global__ __launch_bounds__(1024) void k_scan(const int* __restrict__ cnt,
                                               int* __restrict__ indptr, int N) {
  __shared__ int wsum[16];
  __shared__ int carry;
  int lane = threadIdx.x & 63, w = threadIdx.x >> 6;
  if (threadIdx.x == 0) { carry = 0; indptr[0] = 0; }
  __syncthreads();
  for (int base = 0; base < N; base += 1024) {
    int i = base + threadIdx.x;
    int v = (i < N) ? cnt[i] : 0;
    #pragma unroll
    for (int off = 1; off < 64; off <<= 1) {
      int t = __shfl_up(v, off);
      if (lane >= off) v += t;
    }
    if (lane == 63) wsum[w] = v;
    __syncthreads();
    int add = carry;
    for (int j = 0; j < w; ++j) add += wsum[j];
    if (i < N) indptr[i + 1] = v + add;
    __syncthreads();
    if (threadIdx.x == 0) {
      int s = 0;
      for (int j = 0; j < 16; ++j) s += wsum[j];
      carry += s;
    }
    __syncthreads();
  }
}

__global__ void k_fill(const int* __restrict__ src, const int* __restrict__ dst,
                       int* __restrict__ cursor, int* __restrict__ csr_src, int E) {
  int e = blockIdx.x * blockDim.x + threadIdx.x;
  if (e >= E) return;
  int pos = atomicAdd(&cursor[dst[e]], 1);
  csr_src[pos] = src[e];
}

// ---- gather mean of 128-wide rows: out[d] = mean_{e in N(d)} X[src_e] -----
__global__ __launch_bounds__(256) void k_gmean(const float* __restrict__ X,
                                               const int* __restrict__ indptr,
                                               const int* __restrict__ csr,
                                               float* __restrict__ out, int N) {
  long wid = ((long)blockIdx.x * blockDim.x + threadIdx.x) >> 6;
  if (wid >= N) return;
  int lane = threadIdx.x & 63;
  int b = indptr[wid], en = indptr[wid + 1];
  float2 acc = make_float2(0.f, 0.f);
  for (int i = b; i < en; ++i) {
    int s = csr[i];
    float2 v = *reinterpret_cast<const float2*>(X + ((size_t)s << 7) + (lane << 1));
    acc.x += v.x; acc.y += v.y;
  }
  float inv = 1.0f / (float)max(en - b, 1);
  acc.x *= inv; acc.y *= inv;
  *reinterpret_cast<float2*>(out + (wid << 7) + (lane << 1)) = acc;
}

// ---- GAT gather: softmax over in-edges + weighted mean over heads ---------
__global__ __launch_bounds__(256) void k_gatg(
    const unsigned short* __restrict__ xh, const int* __restrict__ indptr,
    const int* __restrict__ csr, const float* __restrict__ asad,
    float* __restrict__ out, int N, int G, int h0) {
  long wid = ((long)blockIdx.x * blockDim.x + threadIdx.x) >> 6;
  if (wid >= N) return;
  int lane = threadIdx.x & 63;
  int b = indptr[wid], en = indptr[wid + 1];

  float ad[4];
  {
    float4 t = *reinterpret_cast<const float4*>(asad + wid * 8 + 4);
    ad[0] = t.x; ad[1] = t.y; ad[2] = t.z; ad[3] = t.w;
  }
  float m[4] = {-INFINITY, -INFINITY, -INFINITY, -INFINITY};
  for (int i = b; i < en; ++i) {
    int s = csr[i];
    float4 as4 = *reinterpret_cast<const float4*>(asad + (size_t)s * 8);
    float e0 = as4.x + ad[0], e1 = as4.y + ad[1];
    float e2 = as4.z + ad[2], e3 = as4.w + ad[3];
    e0 = e0 >= 0.f ? e0 : 0.2f * e0; e1 = e1 >= 0.f ? e1 : 0.2f * e1;
    e2 = e2 >= 0.f ? e2 : 0.2f * e2; e3 = e3 >= 0.f ? e3 : 0.2f * e3;
    m[0] = fmaxf(m[0], e0); m[1] = fmaxf(m[1], e1);
    m[2] = fmaxf(m[2], e2); m[3] = fmaxf(m[3], e3);
  }
  float den[4] = {0.f, 0.f, 0.f, 0.f};
  float accx[4] = {0.f, 0.f, 0.f, 0.f};
  float accy[4] = {0.f, 0.f, 0.f, 0.f};
  for (int i = b; i < en; ++i) {
    int s = csr[i];
    float4 as4 = *reinterpret_cast<const float4*>(asad + (size_t)s * 8);
    float e[4];
    e[0] = as4.x + ad[0]; e[1] = as4.y + ad[1];
    e[2] = as4.z + ad[2]; e[3] = as4.w + ad[3];
    const unsigned short* xr = xh + (size_t)s * (G << 7) + (lane << 1);
    #pragma unroll 4
    for (int g = 0; g < G; ++g) {
      int h = h0 + g;
      float ev = e[h];
      ev = ev >= 0.f ? ev : 0.2f * ev;
      float w = __expf(ev - m[h]);
      den[g] += w;
      ushort2 u = *reinterpret_cast<const ushort2*>(xr + (g << 7));
      accx[g] = fmaf(w, bf2f(u.x), accx[g]);
      accy[g] = fmaf(w, bf2f(u.y), accy[g]);
    }
  }
  float ox = 0.f, oy = 0.f;
  #pragma unroll 4
  for (int g = 0; g < G; ++g) {
    float inv = 0.25f / fmaxf(den[g], 1e-16f);
    ox = fmaf(accx[g], inv, ox);
    oy = fmaf(accy[g], inv, oy);
  }
  float* po = out + (wid << 7) + (lane << 1);
  if (h0 > 0) { ox += po[0]; oy += po[1]; }
  *reinterpret_cast<float2*>(po) = make_float2(ox, oy);
}

// ---- weight pack: Wt[c][k] = bf16(W[k][c]), pitch M -----------------------
__global__ void k_pack(const float* __restrict__ W, unsigned short* __restrict__ Wt,
                       int M, int cols, int ldW) {
  int t = blockIdx.x * blockDim.x + threadIdx.x;
  if (t >= M * cols) return;
  int c = t / M, k = t - c * M;
  Wt[t] = f2bf(W[(size_t)k * ldW + c]);
}

// ---- MFMA GEMM: C = A1@W1 [+ A2@W2] + bias ; A fp32 [N,M], Wt bf16 [cols][M]
// Block 256 thr = 4 waves (2x2 over rows x cols). Tile 64 x (CF*32).
template <int CF>
__global__ __launch_bounds__(256) void k_mgemm(
    const float* __restrict__ A1, const unsigned short* __restrict__ Wt1,
    const float* __restrict__ A2, const unsigned short* __restrict__ Wt2,
    const float* __restrict__ bias, void* __restrict__ Cout, int obf16,
    int Nrows, int M, int ldC, int relu) {
  constexpr int BN = CF * 32;
  __shared__ alignas(16) unsigned short sA[64][136];
  __shared__ alignas(16) unsigned short sBt[128][136];
  const int tid = threadIdx.x;
  const int lane = tid & 63;
  const int w = tid >> 6;
  const int wr = (w >> 1) * 32;           // wave row offset
  const int wc = (w & 1) * (CF * 16);     // wave col offset
  const int lr = lane & 15;
  const int lk = (lane >> 4) << 3;        // k offset within 32
  const int row0 = blockIdx.x * 64;
  const int colb = blockIdx.y * BN;

  f32x4 acc[2][CF];
  #pragma unroll
  for (int i = 0; i < 2; ++i)
    #pragma unroll
    for (int j = 0; j < CF; ++j) acc[i][j] = (f32x4){0.f, 0.f, 0.f, 0.f};

  for (int pass = 0; pass < 2; ++pass) {
    const float* A = pass ? A2 : A1;
    const unsigned short* Wt = pass ? Wt2 : Wt1;
    if (!A) break;
    // stage A tile (fp32 -> bf16)
    for (int i = tid * 4; i < 64 * M; i += 1024) {
      int r = i / M, k = i - r * M;
      int gr = row0 + r;
      float4 v = make_float4(0.f, 0.f, 0.f, 0.f);
      if (gr < Nrows) v = *reinterpret_cast<const float4*>(A + (size_t)gr * M + k);
      ushort4 u;
      u.x = f2bf(v.x); u.y = f2bf(v.y); u.z = f2bf(v.z); u.w = f2bf(v.w);
      *reinterpret_cast<ushort4*>(&sA[r][k]) = u;
    }
    // stage B tile (already bf16, [col][k] pitch M)
    for (int i = tid * 4; i < BN * M; i += 1024) {
      int c = i / M, k = i - c * M;
      ushort4 u = *reinterpret_cast<const ushort4*>(Wt + (size_t)(colb + c) * M + k);
      *reinterpret_cast<ushort4*>(&sBt[c][k]) = u;
    }
    __syncthreads();
    for (int k0 = lk; k0 < M; k0 += 32) {
      s16x8 a0 = *reinterpret_cast<const s16x8*>(&sA[wr + lr][k0]);
      s16x8 a1 = *reinterpret_cast<const s16x8*>(&sA[wr + lr + 16][k0]);
      #pragma unroll
      for (int j = 0; j < CF; ++j) {
        s16x8 bj = *reinterpret_cast<const s16x8*>(&sBt[wc + lr + 16 * j][k0]);
        acc[0][j] = __builtin_amdgcn_mfma_f32_16x16x32_bf16(a0, bj, acc[0][j], 0, 0, 0);
        acc[1][j] = __builtin_amdgcn_mfma_f32_16x16x32_bf16(a1, bj, acc[1][j], 0, 0, 0);
      }
    }
    __syncthreads();
  }

  // epilogue: D col = lane&15, row = 4*(lane>>4)+reg  [m89/m91]
  const int rbase = (lane >> 4) << 2;
  #pragma unroll
  for (int i = 0; i < 2; ++i) {
    int grow = row0 + wr + 16 * i + rbase;
    #pragma unroll
    for (int j = 0; j < CF; ++j) {
      int col = colb + wc + 16 * j + lr;
      float bv = bias ? bias[col] : 0.f;
      #pragma unroll
      for (int r = 0; r < 4; ++r) {
        if (grow + r >= Nrows) continue;
        float v = acc[i][j][r] + bv;
        if (relu) v = fmaxf(v, 0.f);
        if (obf16)
          ((unsigned short*)Cout)[(size_t)(grow + r) * ldC + col] = f2bf(v);
        else
          ((float*)Cout)[(size_t)(grow + r) * ldC + col] = v;
      }
    }
  }
}

// ---- per-column sum / sumsq (K in {64,128}) -------------------------------
__global__ void k_stats(const float* __restrict__ X, float* __restrict__ stats,
                        int Nrows, int K) {
  int c = threadIdx.x & (K - 1);
  int rl = threadIdx.x / K;
  int rpb = 256 / K;
  float s = 0.f, s2 = 0.f;
  for (long r = (long)blockIdx.x * rpb + rl; r < Nrows; r += (long)gridDim.x * rpb) {
    float v = X[r * K + c];
    s += v;
    s2 = fmaf(v, v, s2);
  }
  __shared__ float b1s[256], b2s[256];
  b1s[threadIdx.x] = s; b2s[threadIdx.x] = s2;
  __syncthreads();
  if (rl == 0) {
    for (int t = 1; t < rpb; ++t) { s += b1s[t * K + c]; s2 += b2s[t * K + c]; }
    atomicAdd(&stats[c], s);
    atomicAdd(&stats[128 + c], s2);
  }
}

// ---- BN + ReLU (+ optional bf16 residual added after relu), in place ------
__global__ void k_bn(float* __restrict__ X, const float* __restrict__ stats,
                     const float* __restrict__ g, const float* __restrict__ b,
                     const unsigned short* __restrict__ addAfter,
                     int Nrows, int K) {
  long i = (long)blockIdx.x * blockDim.x + threadIdx.x;
  if (i >= (long)Nrows * K) return;
  int c = (int)(i & (K - 1));
  float invN = 1.0f / (float)Nrows;
  float m = stats[c] * invN;
  float v = stats[128 + c] * invN - m * m;
  float y = g[c] * (X[i] - m) * rsqrtf(v + 1e-5f) + b[c];
  y = fmaxf(y, 0.f);
  if (addAfter) y += bf2f(addAfter[i]);
  X[i] = y;
}

// ---- fold attention vectors: attw[k][j] (j<4: Wg@att_s head j, j>=4: att_d)
__global__ void k_foldatt(const float* __restrict__ Wg, const float* __restrict__ atts,
                          const float* __restrict__ attd, float* __restrict__ attw) {
  int t = blockIdx.x * blockDim.x + threadIdx.x;
  if (t >= 1024) return;
  int k = t >> 3, j = t & 7, h = j & 3;
  const float* av = (j < 4 ? atts : attd) + h * 128;
  const float* wg = Wg + (size_t)k * 512 + h * 128;
  float s = 0.f;
  for (int c = 0; c < 128; ++c) s = fmaf(wg[c], av[c], s);
  attw[t] = s;
}

// ---- a_s/a_d per node: one wave each, grid-stride --------------------------
__global__ void k_attdots(const float* __restrict__ h1, const float* __restrict__ attw,
                          float* __restrict__ asad, int Nrows) {
  int lane = threadIdx.x & 63;
  float c0[8], c1[8];
  #pragma unroll
  for (int j = 0; j < 8; ++j) {
    c0[j] = attw[(2 * lane) * 8 + j];
    c1[j] = attw[(2 * lane + 1) * 8 + j];
  }
  long wid = ((long)blockIdx.x * blockDim.x + threadIdx.x) >> 6;
  long nw = ((long)gridDim.x * blockDim.x) >> 6;
  for (long n = wid; n < Nrows; n += nw) {
    float2 v = *reinterpret_cast<const float2*>(h1 + (n << 7) + (lane << 1));
    float a[8];
    #pragma unroll
    for (int j = 0; j < 8; ++j) a[j] = v.x * c0[j] + v.y * c1[j];
    #pragma unroll
    for (int off = 1; off < 64; off <<= 1) {
      #pragma unroll
      for (int j = 0; j < 8; ++j) a[j] += __shfl_xor(a[j], off);
    }
    if (lane == 0) {
      *reinterpret_cast<float4*>(asad + n * 8)     = make_float4(a[0], a[1], a[2], a[3]);
      *reinterpret_cast<float4*>(asad + n * 8 + 4) = make_float4(a[4], a[5], a[6], a[7]);
    }
  }
}

// ---- final: logits = z2 @ Wc3 + bc3; log_softmax ---------------------------
__global__ void k_final(const float* __restrict__ z2, const float* __restrict__ W,
                        const float* __restrict__ b, float* __restrict__ out, int Nrows) {
  int n = blockIdx.x * blockDim.x + threadIdx.x;
  if (n >= Nrows) return;
  float l0 = b[0], l1 = b[1];
  const float* z = z2 + (size_t)n * 32;
  #pragma unroll
  for (int k = 0; k < 32; ++k) {
    float v = z[k];
    l0 = fmaf(v, W[2 * k], l0);
    l1 = fmaf(v, W[2 * k + 1], l1);
  }
  float m = fmaxf(l0, l1);
  float lse = m + logf(expf(l0 - m) + expf(l1 - m));
  out[2 * n] = l0 - lse;
  out[2 * n + 1] = l1 - lse;
}

// ---------------------------------------------------------------------------
extern "C" void kernel_launch(void* const* d_in, const int* in_sizes, int n_in,
                              void* d_out, int out_size, void* d_ws, size_t ws_size,
                              hipStream_t stream) {
  const float* x    = (const float*)d_in[0];
  const int*   ei   = (const int*)  d_in[1];
  const float* Wl1  = (const float*)d_in[2];
  const float* Wr1  = (const float*)d_in[3];
  const float* b1   = (const float*)d_in[4];
  const float* g1   = (const float*)d_in[5];
  const float* be1  = (const float*)d_in[6];
  const float* Wg   = (const float*)d_in[7];
  const float* atts = (const float*)d_in[8];
  const float* attd = (const float*)d_in[9];
  // d_in[10] = bg: constant column offset, cancels exactly in the following BN.
  const float* g2   = (const float*)d_in[11];
  const float* be2  = (const float*)d_in[12];
  const float* Wl3  = (const float*)d_in[13];
  const float* Wr3  = (const float*)d_in[14];
  const float* b3   = (const float*)d_in[15];
  const float* g3   = (const float*)d_in[16];
  const float* be3  = (const float*)d_in[17];
  const float* Wsk  = (const float*)d_in[18];
  const float* bsk  = (const float*)d_in[19];
  const float* Wc1  = (const float*)d_in[20];
  const float* bc1  = (const float*)d_in[21];
  const float* gc   = (const float*)d_in[22];
  const float* bec  = (const float*)d_in[23];
  const float* Wc2  = (const float*)d_in[24];
  const float* bc2  = (const float*)d_in[25];
  const float* Wc3  = (const float*)d_in[26];
  const float* bc3  = (const float*)d_in[27];
  (void)n_in; (void)out_size;

  const int N = in_sizes[0] / 128;
  const int E = in_sizes[1] / 2;
  const int* src = ei;
  const int* dst = ei + E;

  // ---- workspace carve-out (fp32 words), 16B-aligned regions ---------------
  auto al4 = [](size_t w) { return (w + 3) & ~(size_t)3; };
  float* ws = (float*)d_ws;
  size_t o = 0;
  int* cnt      = (int*)(ws + o); o += al4((size_t)N);
  int* indptr   = (int*)(ws + o); o += al4((size_t)N + 1);
  int* cursor   = (int*)(ws + o); o += al4((size_t)N);
  int* csr_src  = (int*)(ws + o); o += al4((size_t)E);
  unsigned short* idbf = (unsigned short*)(ws + o); o += al4((size_t)N * 32);  // [N,64] bf16
  float* stats  = ws + o; o += 1024;
  float* attw   = ws + o; o += 1024;
  float* asad   = ws + o; o += al4((size_t)N * 8);
  // packed weights: 129024 ushorts = 64512 floats (round-4 bug: reserved half)
  unsigned short* wt = (unsigned short*)(ws + o); o += 64512 + 64;
  float* bufA   = ws + o; o += (size_t)N * 128;   // mean1 / mean3 / z1
  float* hB     = ws + o; o += (size_t)N * 128;   // h1 / h3+z2
  float* h2     = ws + o; o += (size_t)N * 128;
  unsigned short* xh = (unsigned short*)(ws + o); // [N, G*128] bf16

  long avail = (long)(ws_size / 4) - (long)o;
  int G = 4;
  while (G > 1 && (long)N * 64 * G > avail) G >>= 1;

  // packed-weight offsets (ushort units)
  unsigned short* WtSk = wt;                 // 64 x128
  unsigned short* WtL1 = WtSk + 8192;        // 128x128
  unsigned short* WtR1 = WtL1 + 16384;       // 128x128
  unsigned short* WtG  = WtR1 + 16384;       // 512x128
  unsigned short* WtL3 = WtG  + 65536;       // 64 x128
  unsigned short* WtR3 = WtL3 + 8192;        // 64 x128
  unsigned short* WtC1 = WtR3 + 8192;        // 64 x64
  unsigned short* WtC2 = WtC1 + 4096;        // 32 x64

  float* st1 = stats, *st2 = stats + 256, *st3 = stats + 512, *st4 = stats + 768;
  float* h3 = hB;
  float* z1 = bufA;
  float* z2 = hB + (size_t)N * 64;

  dim3 blk(256);
  int gE     = (E + 255) / 256;
  int gN64   = (N + 63) / 64;
  int gW     = (int)(((long)N * 64 + 255) / 256);   // one wave per node
  int gBN128 = (int)(((long)N * 128 + 255) / 256);
  int gBN64  = (int)(((long)N * 64 + 255) / 256);

  hipMemsetAsync(cnt, 0, (size_t)N * 4, stream);
  hipMemsetAsync(stats, 0, 1024 * 4, stream);

  // ---- CSR build + weight packing ----
  k_hist<<<gE, blk, 0, stream>>>(dst, cnt, E);
  k_scan<<<1, 1024, 0, stream>>>(cnt, indptr, N);
  hipMemcpyAsync(cursor, indptr, (size_t)N * 4, hipMemcpyDeviceToDevice, stream);
  k_fill<<<gE, blk, 0, stream>>>(src, dst, cursor, csr_src, E);
  k_pack<<<32,  blk, 0, stream>>>(Wsk, WtSk, 128, 64, 64);
  k_pack<<<64,  blk, 0, stream>>>(Wl1, WtL1, 128, 128, 128);
  k_pack<<<64,  blk, 0, stream>>>(Wr1, WtR1, 128, 128, 128);
  k_pack<<<256, blk, 0, stream>>>(Wg,  WtG,  128, 512, 512);
  k_pack<<<32,  blk, 0, stream>>>(Wl3, WtL3, 128, 64, 64);
  k_pack<<<32,  blk, 0, stream>>>(Wr3, WtR3, 128, 64, 64);
  k_pack<<<16,  blk, 0, stream>>>(Wc1, WtC1, 64, 64, 64);
  k_pack<<<8,   blk, 0, stream>>>(Wc2, WtC2, 64, 32, 32);

  // ---- SAGE1 ----
  k_gmean<<<gW, blk, 0, stream>>>(x, indptr, csr_src, bufA, N);
  k_mgemm<2><<<dim3(gN64, 1), blk, 0, stream>>>(
      x, WtSk, nullptr, nullptr, bsk, idbf, 1, N, 128, 64, 0);
  k_mgemm<4><<<dim3(gN64, 1), blk, 0, stream>>>(
      bufA, WtL1, x, WtR1, b1, hB, 0, N, 128, 128, 0);
  k_stats<<<256, blk, 0, stream>>>(hB, st1, N, 128);
  k_bn<<<gBN128, blk, 0, stream>>>(hB, st1, g1, be1, nullptr, N, 128);

  // ---- GAT ----
  k_foldatt<<<4, blk, 0, stream>>>(Wg, atts, attd, attw);
  k_attdots<<<2048, blk, 0, stream>>>(hB, attw, asad, N);
  for (int h0 = 0; h0 < 4; h0 += G) {
    k_mgemm<4><<<dim3(gN64, G), blk, 0, stream>>>(
        hB, WtG + (size_t)h0 * 128 * 128, nullptr, nullptr, nullptr,
        xh, 1, N, 128, G * 128, 0);
    k_gatg<<<gW, blk, 0, stream>>>(xh, indptr, csr_src, asad, h2, N, G, h0);
  }
  k_stats<<<256, blk, 0, stream>>>(h2, st2, N, 128);
  k_bn<<<gBN128, blk, 0, stream>>>(h2, st2, g2, be2, nullptr, N, 128);

  // ---- SAGE3 ----
  k_gmean<<<gW, blk, 0, stream>>>(h2, indptr, csr_src, bufA, N);
  k_mgemm<2><<<dim3(gN64, 1), blk, 0, stream>>>(
      bufA, WtL3, h2, WtR3, b3, h3, 0, N, 128, 64, 0);
  k_stats<<<256, blk, 0, stream>>>(h3, st3, N, 64);
  k_bn<<<gBN64, blk, 0, stream>>>(h3, st3, g3, be3, idbf, N, 64);  // +identity

  // ---- classifier ----
  k_mgemm<2><<<dim3(gN64, 1), blk, 0, stream>>>(
      h3, WtC1, nullptr, nullptr, bc1, z1, 0, N, 64, 64, 0);
  k_stats<<<256, blk, 0, stream>>>(z1, st4, N, 64);
  k_bn<<<gBN64, blk, 0, stream>>>(z1, st4, gc, bec, nullptr, N, 64);
  k_mgemm<1><<<dim3(gN64, 1), blk, 0, stream>>>(
      z1, WtC2, nullptr, nullptr, bc2, z2, 0, N, 64, 32, 1);
  k_final<<<(N + 255) / 256, blk, 0, stream>>>(z2, Wc3, bc3, (float*)d_out, N);
}

// Round 7
// 1154.967 us; speedup vs baseline: 4.0024x; 1.1244x over previous
//
#include <hip/hip_runtime.h>
#include <hip/hip_bf16.h>
#include <cmath>

// ---------------------------------------------------------------------------
// MuleHunterGNN: SAGE -> GAT -> SAGE -> skip -> MLP classifier
// CSR-gather aggregation; GAT softmax split out of gather; all GEMMs on MFMA
// (bf16 in, fp32 acc); bf16 for all gathered / GEMM-A intermediates.
// ---------------------------------------------------------------------------

typedef short s16x8 __attribute__((ext_vector_type(8)));
typedef float f32x4 __attribute__((ext_vector_type(4)));

__device__ __forceinline__ float bf2f(unsigned short u) {
  return __uint_as_float((unsigned)u << 16);
}
__device__ __forceinline__ unsigned short f2bf(float f) {
  __hip_bfloat16 h = __float2bfloat16(f);
  return *reinterpret_cast<unsigned short*>(&h);
}

// ---- CSR build -----------------------------------------------------------
__global__ void k_hist(const int* __restrict__ dst, int* __restrict__ cnt, int E) {
  int e = blockIdx.x * blockDim.x + threadIdx.x;
  if (e < E) atomicAdd(&cnt[dst[e]], 1);
}

__global__ __launch_bounds__(1024) void k_scan(const int* __restrict__ cnt,
                                               int* __restrict__ indptr, int N) {
  __shared__ int wsum[16];
  __shared__ int carry;
  int lane = threadIdx.x & 63, w = threadIdx.x >> 6;
  if (threadIdx.x == 0) { carry = 0; indptr[0] = 0; }
  __syncthreads();
  for (int base = 0; base < N; base += 1024) {
    int i = base + threadIdx.x;
    int v = (i < N) ? cnt[i] : 0;
    #pragma unroll
    for (int off = 1; off < 64; off <<= 1) {
      int t = __shfl_up(v, off);
      if (lane >= off) v += t;
    }
    if (lane == 63) wsum[w] = v;
    __syncthreads();
    int add = carry;
    for (int j = 0; j < w; ++j) add += wsum[j];
    if (i < N) indptr[i + 1] = v + add;
    __syncthreads();
    if (threadIdx.x == 0) {
      int s = 0;
      for (int j = 0; j < 16; ++j) s += wsum[j];
      carry += s;
    }
    __syncthreads();
  }
}

__global__ void k_fill(const int* __restrict__ src, const int* __restrict__ dst,
                       int* __restrict__ cursor, int* __restrict__ csr_src, int E) {
  int e = blockIdx.x * blockDim.x + threadIdx.x;
  if (e >= E) return;
  int pos = atomicAdd(&cursor[dst[e]], 1);
  csr_src[pos] = src[e];
}

// ---- fp32 -> bf16 cast ----------------------------------------------------
__global__ void k_cast(const float* __restrict__ in, unsigned short* __restrict__ out,
                       long n4) {
  long t = (long)blockIdx.x * blockDim.x + threadIdx.x;
  if (t >= n4) return;
  float4 v = *reinterpret_cast<const float4*>(in + t * 4);
  ushort4 u;
  u.x = f2bf(v.x); u.y = f2bf(v.y); u.z = f2bf(v.z); u.w = f2bf(v.w);
  *reinterpret_cast<ushort4*>(out + t * 4) = u;
}

// ---- gather mean of bf16 rows (W = 128 or 64), bf16 out -------------------
template <int W>
__global__ __launch_bounds__(256) void k_gmean_bf(const unsigned short* __restrict__ X,
                                                  const int* __restrict__ indptr,
                                                  const int* __restrict__ csr,
                                                  unsigned short* __restrict__ out, int N) {
  long wid = ((long)blockIdx.x * blockDim.x + threadIdx.x) >> 6;
  if (wid >= N) return;
  int lane = threadIdx.x & 63;
  int b = indptr[wid], en = indptr[wid + 1];
  if (W == 128) {
    float ax = 0.f, ay = 0.f;
    for (int i = b; i < en; ++i) {
      int s = csr[i];
      ushort2 u = *reinterpret_cast<const ushort2*>(X + ((size_t)s << 7) + (lane << 1));
      ax += bf2f(u.x); ay += bf2f(u.y);
    }
    float inv = 1.0f / (float)max(en - b, 1);
    ushort2 o; o.x = f2bf(ax * inv); o.y = f2bf(ay * inv);
    *reinterpret_cast<ushort2*>(out + (wid << 7) + (lane << 1)) = o;
  } else {
    float a = 0.f;
    for (int i = b; i < en; ++i) {
      int s = csr[i];
      a += bf2f(X[((size_t)s << 6) + lane]);
    }
    float inv = 1.0f / (float)max(en - b, 1);
    out[(wid << 6) + lane] = f2bf(a * inv);
  }
}

// ---- GAT alpha: per-dst segment softmax, 8 lanes per dst ------------------
__global__ __launch_bounds__(256) void k_alpha(const int* __restrict__ indptr,
                                               const int* __restrict__ csr,
                                               const float* __restrict__ asad,
                                               float* __restrict__ alpha, int N) {
  long g = ((long)blockIdx.x * blockDim.x + threadIdx.x) >> 3;
  if (g >= N) return;
  int l8 = threadIdx.x & 7;
  int b = indptr[g], en = indptr[g + 1];
  float4 adv = *reinterpret_cast<const float4*>(asad + g * 8 + 4);
  float m[4] = {-INFINITY, -INFINITY, -INFINITY, -INFINITY};
  for (int i = b + l8; i < en; i += 8) {
    int s = csr[i];
    float4 a = *reinterpret_cast<const float4*>(asad + (size_t)s * 8);
    float e0 = a.x + adv.x, e1 = a.y + adv.y, e2 = a.z + adv.z, e3 = a.w + adv.w;
    e0 = e0 >= 0.f ? e0 : 0.2f * e0; e1 = e1 >= 0.f ? e1 : 0.2f * e1;
    e2 = e2 >= 0.f ? e2 : 0.2f * e2; e3 = e3 >= 0.f ? e3 : 0.2f * e3;
    m[0] = fmaxf(m[0], e0); m[1] = fmaxf(m[1], e1);
    m[2] = fmaxf(m[2], e2); m[3] = fmaxf(m[3], e3);
  }
  #pragma unroll
  for (int off = 1; off < 8; off <<= 1) {
    #pragma unroll
    for (int h = 0; h < 4; ++h) m[h] = fmaxf(m[h], __shfl_xor(m[h], off));
  }
  float den[4] = {0.f, 0.f, 0.f, 0.f};
  for (int i = b + l8; i < en; i += 8) {
    int s = csr[i];
    float4 a = *reinterpret_cast<const float4*>(asad + (size_t)s * 8);
    float e0 = a.x + adv.x, e1 = a.y + adv.y, e2 = a.z + adv.z, e3 = a.w + adv.w;
    e0 = e0 >= 0.f ? e0 : 0.2f * e0; e1 = e1 >= 0.f ? e1 : 0.2f * e1;
    e2 = e2 >= 0.f ? e2 : 0.2f * e2; e3 = e3 >= 0.f ? e3 : 0.2f * e3;
    float4 w;
    w.x = __expf(e0 - m[0]); w.y = __expf(e1 - m[1]);
    w.z = __expf(e2 - m[2]); w.w = __expf(e3 - m[3]);
    den[0] += w.x; den[1] += w.y; den[2] += w.z; den[3] += w.w;
    *reinterpret_cast<float4*>(alpha + (size_t)i * 4) = w;
  }
  #pragma unroll
  for (int off = 1; off < 8; off <<= 1) {
    #pragma unroll
    for (int h = 0; h < 4; ++h) den[h] += __shfl_xor(den[h], off);
  }
  float s0 = 0.25f / fmaxf(den[0], 1e-16f);
  float s1 = 0.25f / fmaxf(den[1], 1e-16f);
  float s2 = 0.25f / fmaxf(den[2], 1e-16f);
  float s3 = 0.25f / fmaxf(den[3], 1e-16f);
  for (int i = b + l8; i < en; i += 8) {
    float4 w = *reinterpret_cast<const float4*>(alpha + (size_t)i * 4);
    w.x *= s0; w.y *= s1; w.z *= s2; w.w *= s3;
    *reinterpret_cast<float4*>(alpha + (size_t)i * 4) = w;
  }
}

// ---- GAT weighted gather: h2[d] (+)= sum_g alpha[e][g] * xh[src,g,:] -------
__global__ __launch_bounds__(256) void k_gatw(
    const unsigned short* __restrict__ xh, const int* __restrict__ indptr,
    const int* __restrict__ csr, const float* __restrict__ alpha,
    float* __restrict__ out, int N, int G, int h0) {
  long wid = ((long)blockIdx.x * blockDim.x + threadIdx.x) >> 6;
  if (wid >= N) return;
  int lane = threadIdx.x & 63;
  int b = indptr[wid], en = indptr[wid + 1];
  float ox = 0.f, oy = 0.f;
  for (int i = b; i < en; ++i) {
    int s = csr[i];
    float4 a4 = *reinterpret_cast<const float4*>(alpha + (size_t)i * 4);
    float aa[4] = {a4.x, a4.y, a4.z, a4.w};
    const unsigned short* xr = xh + (size_t)s * (G << 7) + (lane << 1);
    #pragma unroll 4
    for (int g = 0; g < G; ++g) {
      float w = aa[h0 + g];
      ushort2 u = *reinterpret_cast<const ushort2*>(xr + (g << 7));
      ox = fmaf(w, bf2f(u.x), ox);
      oy = fmaf(w, bf2f(u.y), oy);
    }
  }
  float* po = out + (wid << 7) + (lane << 1);
  if (h0 > 0) { ox += po[0]; oy += po[1]; }
  *reinterpret_cast<float2*>(po) = make_float2(ox, oy);
}

// ---- weight pack: Wt[c][k] = bf16(W[k][c]), pitch M ------------------------
__global__ void k_pack(const float* __restrict__ W, unsigned short* __restrict__ Wt,
                       int M, int cols, int ldW) {
  int t = blockIdx.x * blockDim.x + threadIdx.x;
  if (t >= M * cols) return;
  int c = t / M, k = t - c * M;
  Wt[t] = f2bf(W[(size_t)k * ldW + c]);
}

// ---- MFMA GEMM: C = A1@W1 [+ A2@W2] + bias [+ Cadd]; A fp32 or bf16 -------
// Wt bf16 [cols][M]; block 256 thr = 4 waves (2x2); tile 64 x (CF*32).
template <int CF>
__global__ __launch_bounds__(256) void k_mgemm(
    const void* __restrict__ A1, int a1bf, const unsigned short* __restrict__ Wt1,
    const void* __restrict__ A2, int a2bf, const unsigned short* __restrict__ Wt2,
    const float* __restrict__ bias, const unsigned short* __restrict__ Cadd,
    void* __restrict__ Cout, int obf16,
    int Nrows, int M, int ldC, int relu) {
  constexpr int BN = CF * 32;
  __shared__ alignas(16) unsigned short sA[64][136];
  __shared__ alignas(16) unsigned short sBt[128][136];
  const int tid = threadIdx.x;
  const int lane = tid & 63;
  const int w = tid >> 6;
  const int wr = (w >> 1) * 32;
  const int wc = (w & 1) * (CF * 16);
  const int lr = lane & 15;
  const int lk = (lane >> 4) << 3;
  const int row0 = blockIdx.x * 64;
  const int colb = blockIdx.y * BN;

  f32x4 acc[2][CF];
  #pragma unroll
  for (int i = 0; i < 2; ++i)
    #pragma unroll
    for (int j = 0; j < CF; ++j) acc[i][j] = (f32x4){0.f, 0.f, 0.f, 0.f};

  for (int pass = 0; pass < 2; ++pass) {
    const void* A = pass ? A2 : A1;
    const int abf = pass ? a2bf : a1bf;
    const unsigned short* Wt = pass ? Wt2 : Wt1;
    if (!A) break;
    for (int i = tid * 4; i < 64 * M; i += 1024) {
      int r = i / M, k = i - r * M;
      int gr = row0 + r;
      ushort4 u = make_ushort4(0, 0, 0, 0);
      if (gr < Nrows) {
        if (abf) {
          u = *reinterpret_cast<const ushort4*>((const unsigned short*)A + (size_t)gr * M + k);
        } else {
          float4 v = *reinterpret_cast<const float4*>((const float*)A + (size_t)gr * M + k);
          u.x = f2bf(v.x); u.y = f2bf(v.y); u.z = f2bf(v.z); u.w = f2bf(v.w);
        }
      }
      *reinterpret_cast<ushort4*>(&sA[r][k]) = u;
    }
    for (int i = tid * 4; i < BN * M; i += 1024) {
      int c = i / M, k = i - c * M;
      ushort4 u = *reinterpret_cast<const ushort4*>(Wt + (size_t)(colb + c) * M + k);
      *reinterpret_cast<ushort4*>(&sBt[c][k]) = u;
    }
    __syncthreads();
    for (int k0 = lk; k0 < M; k0 += 32) {
      s16x8 a0 = *reinterpret_cast<const s16x8*>(&sA[wr + lr][k0]);
      s16x8 a1 = *reinterpret_cast<const s16x8*>(&sA[wr + lr + 16][k0]);
      #pragma unroll
      for (int j = 0; j < CF; ++j) {
        s16x8 bj = *reinterpret_cast<const s16x8*>(&sBt[wc + lr + 16 * j][k0]);
        acc[0][j] = __builtin_amdgcn_mfma_f32_16x16x32_bf16(a0, bj, acc[0][j], 0, 0, 0);
        acc[1][j] = __builtin_amdgcn_mfma_f32_16x16x32_bf16(a1, bj, acc[1][j], 0, 0, 0);
      }
    }
    __syncthreads();
  }

  // epilogue: D col = lane&15, row = 4*(lane>>4)+reg  [m89/m91]
  const int rbase = (lane >> 4) << 2;
  #pragma unroll
  for (int i = 0; i < 2; ++i) {
    int grow = row0 + wr + 16 * i + rbase;
    #pragma unroll
    for (int j = 0; j < CF; ++j) {
      int col = colb + wc + 16 * j + lr;
      float bv = bias ? bias[col] : 0.f;
      #pragma unroll
      for (int r = 0; r < 4; ++r) {
        if (grow + r >= Nrows) continue;
        float v = acc[i][j][r] + bv;
        if (Cadd) v += bf2f(Cadd[(size_t)(grow + r) * ldC + col]);
        if (relu) v = fmaxf(v, 0.f);
        if (obf16)
          ((unsigned short*)Cout)[(size_t)(grow + r) * ldC + col] = f2bf(v);
        else
          ((float*)Cout)[(size_t)(grow + r) * ldC + col] = v;
      }
    }
  }
}

// ---- per-column sum / sumsq (K in {64,128}) --------------------------------
__global__ void k_stats(const float* __restrict__ X, float* __restrict__ stats,
                        int Nrows, int K) {
  int c = threadIdx.x & (K - 1);
  int rl = threadIdx.x / K;
  int rpb = 256 / K;
  float s = 0.f, s2 = 0.f;
  for (long r = (long)blockIdx.x * rpb + rl; r < Nrows; r += (long)gridDim.x * rpb) {
    float v = X[r * K + c];
    s += v;
    s2 = fmaf(v, v, s2);
  }
  __shared__ float b1s[256], b2s[256];
  b1s[threadIdx.x] = s; b2s[threadIdx.x] = s2;
  __syncthreads();
  if (rl == 0) {
    for (int t = 1; t < rpb; ++t) { s += b1s[t * K + c]; s2 += b2s[t * K + c]; }
    atomicAdd(&stats[c], s);
    atomicAdd(&stats[128 + c], s2);
  }
}

// ---- BN + ReLU (+ bf16 residual after relu) (+ optional bf16 mirror) -------
__global__ void k_bn(float* __restrict__ X, const float* __restrict__ stats,
                     const float* __restrict__ g, const float* __restrict__ b,
                     const unsigned short* __restrict__ addAfter,
                     unsigned short* __restrict__ mirror,
                     int Nrows, int K) {
  long i = (long)blockIdx.x * blockDim.x + threadIdx.x;
  if (i >= (long)Nrows * K) return;
  int c = (int)(i & (K - 1));
  float invN = 1.0f / (float)Nrows;
  float m = stats[c] * invN;
  float v = stats[128 + c] * invN - m * m;
  float y = g[c] * (X[i] - m) * rsqrtf(v + 1e-5f) + b[c];
  y = fmaxf(y, 0.f);
  if (addAfter) y += bf2f(addAfter[i]);
  X[i] = y;
  if (mirror) mirror[i] = f2bf(y);
}

// ---- fold attention vectors -------------------------------------------------
__global__ void k_foldatt(const float* __restrict__ Wg, const float* __restrict__ atts,
                          const float* __restrict__ attd, float* __restrict__ attw) {
  int t = blockIdx.x * blockDim.x + threadIdx.x;
  if (t >= 1024) return;
  int k = t >> 3, j = t & 7, h = j & 3;
  const float* av = (j < 4 ? atts : attd) + h * 128;
  const float* wg = Wg + (size_t)k * 512 + h * 128;
  float s = 0.f;
  for (int c = 0; c < 128; ++c) s = fmaf(wg[c], av[c], s);
  attw[t] = s;
}

// ---- a_s/a_d per node: one wave each, grid-stride ---------------------------
__global__ void k_attdots(const float* __restrict__ h1, const float* __restrict__ attw,
                          float* __restrict__ asad, int Nrows) {
  int lane = threadIdx.x & 63;
  float c0[8], c1[8];
  #pragma unroll
  for (int j = 0; j < 8; ++j) {
    c0[j] = attw[(2 * lane) * 8 + j];
    c1[j] = attw[(2 * lane + 1) * 8 + j];
  }
  long wid = ((long)blockIdx.x * blockDim.x + threadIdx.x) >> 6;
  long nw = ((long)gridDim.x * blockDim.x) >> 6;
  for (long n = wid; n < Nrows; n += nw) {
    float2 v = *reinterpret_cast<const float2*>(h1 + (n << 7) + (lane << 1));
    float a[8];
    #pragma unroll
    for (int j = 0; j < 8; ++j) a[j] = v.x * c0[j] + v.y * c1[j];
    #pragma unroll
    for (int off = 1; off < 64; off <<= 1) {
      #pragma unroll
      for (int j = 0; j < 8; ++j) a[j] += __shfl_xor(a[j], off);
    }
    if (lane == 0) {
      *reinterpret_cast<float4*>(asad + n * 8)     = make_float4(a[0], a[1], a[2], a[3]);
      *reinterpret_cast<float4*>(asad + n * 8 + 4) = make_float4(a[4], a[5], a[6], a[7]);
    }
  }
}

// ---- final: logits = z2 @ Wc3 + bc3; log_softmax ----------------------------
__global__ void k_final(const float* __restrict__ z2, const float* __restrict__ W,
                        const float* __restrict__ b, float* __restrict__ out, int Nrows) {
  int n = blockIdx.x * blockDim.x + threadIdx.x;
  if (n >= Nrows) return;
  float l0 = b[0], l1 = b[1];
  const float* z = z2 + (size_t)n * 32;
  #pragma unroll
  for (int k = 0; k < 32; ++k) {
    float v = z[k];
    l0 = fmaf(v, W[2 * k], l0);
    l1 = fmaf(v, W[2 * k + 1], l1);
  }
  float m = fmaxf(l0, l1);
  float lse = m + logf(expf(l0 - m) + expf(l1 - m));
  out[2 * n] = l0 - lse;
  out[2 * n + 1] = l1 - lse;
}

// ---------------------------------------------------------------------------
extern "C" void kernel_launch(void* const* d_in, const int* in_sizes, int n_in,
                              void* d_out, int out_size, void* d_ws, size_t ws_size,
                              hipStream_t stream) {
  const float* x    = (const float*)d_in[0];
  const int*   ei   = (const int*)  d_in[1];
  const float* Wl1  = (const float*)d_in[2];
  const float* Wr1  = (const float*)d_in[3];
  const float* b1   = (const float*)d_in[4];
  const float* g1   = (const float*)d_in[5];
  const float* be1  = (const float*)d_in[6];
  const float* Wg   = (const float*)d_in[7];
  const float* atts = (const float*)d_in[8];
  const float* attd = (const float*)d_in[9];
  // d_in[10] = bg: constant column offset, cancels exactly in the following BN.
  const float* g2   = (const float*)d_in[11];
  const float* be2  = (const float*)d_in[12];
  const float* Wl3  = (const float*)d_in[13];
  const float* Wr3  = (const float*)d_in[14];
  const float* b3   = (const float*)d_in[15];
  const float* g3   = (const float*)d_in[16];
  const float* be3  = (const float*)d_in[17];
  const float* Wsk  = (const float*)d_in[18];
  const float* bsk  = (const float*)d_in[19];
  const float* Wc1  = (const float*)d_in[20];
  const float* bc1  = (const float*)d_in[21];
  const float* gc   = (const float*)d_in[22];
  const float* bec  = (const float*)d_in[23];
  const float* Wc2  = (const float*)d_in[24];
  const float* bc2  = (const float*)d_in[25];
  const float* Wc3  = (const float*)d_in[26];
  const float* bc3  = (const float*)d_in[27];
  (void)n_in; (void)out_size;

  const int N = in_sizes[0] / 128;
  const int E = in_sizes[1] / 2;
  const int* src = ei;
  const int* dst = ei + E;

  // ---- workspace carve-out (fp32 words) -------------------------------------
  auto al4 = [](size_t w) { return (w + 3) & ~(size_t)3; };
  float* ws = (float*)d_ws;
  size_t o = 0;
  int* cnt      = (int*)(ws + o); o += al4((size_t)N);
  int* indptr   = (int*)(ws + o); o += al4((size_t)N + 1);
  int* cursor   = (int*)(ws + o); o += al4((size_t)N);
  int* csr_src  = (int*)(ws + o); o += al4((size_t)E);
  unsigned short* idbf = (unsigned short*)(ws + o); o += al4((size_t)N * 32);  // [N,64] bf16
  float* stats  = ws + o; o += 1024;
  float* attw   = ws + o; o += 1024;
  float* asad   = ws + o; o += al4((size_t)N * 8);
  float* alpha  = ws + o; o += al4((size_t)E * 4);
  unsigned short* wt = (unsigned short*)(ws + o); o += 64512 + 64;  // packed weights
  float* bufA   = ws + o; o += (size_t)N * 128;   // xbf+mean1bf / h1bf+h2bf / z1
  float* hB     = ws + o; o += (size_t)N * 128;   // h1 / h3+z2
  float* h2     = ws + o; o += (size_t)N * 128;
  unsigned short* xh = (unsigned short*)(ws + o); // [N, G*128] bf16; later yl3+mean3

  long avail = (long)(ws_size / 4) - (long)o;
  int G = 4;
  while (G > 1 && (long)N * 64 * G > avail) G >>= 1;

  // bufA aliases (bf16)
  unsigned short* xbf     = (unsigned short*)bufA;                    // [N,128] bf16
  unsigned short* mean1bf = (unsigned short*)(bufA + (size_t)N * 64); // [N,128] bf16
  unsigned short* h1bf    = (unsigned short*)bufA;                    // after SAGE1
  unsigned short* h2bf    = (unsigned short*)(bufA + (size_t)N * 64); // after SAGE1
  // xh aliases after GAT
  unsigned short* yl3     = xh;                                       // [N,64] bf16
  unsigned short* mean3bf = xh + (size_t)N * 64;                      // [N,64] bf16

  // packed-weight offsets (ushort units)
  unsigned short* WtSk = wt;                 // 64 x128
  unsigned short* WtL1 = WtSk + 8192;        // 128x128
  unsigned short* WtR1 = WtL1 + 16384;       // 128x128
  unsigned short* WtG  = WtR1 + 16384;       // 512x128
  unsigned short* WtL3 = WtG  + 65536;       // 64 x128
  unsigned short* WtR3 = WtL3 + 8192;        // 64 x128
  unsigned short* WtC1 = WtR3 + 8192;        // 64 x64
  unsigned short* WtC2 = WtC1 + 4096;        // 32 x64

  float* st1 = stats, *st2 = stats + 256, *st3 = stats + 512, *st4 = stats + 768;
  float* h3 = hB;
  float* z1 = bufA;
  float* z2 = hB + (size_t)N * 64;

  dim3 blk(256);
  int gE     = (E + 255) / 256;
  int gN64   = (N + 63) / 64;
  int gW     = (int)(((long)N * 64 + 255) / 256);   // one wave per node
  int gA     = (int)(((long)N * 8 + 255) / 256);    // 8 lanes per node
  int gC     = (int)(((long)N * 32 + 255) / 256);   // cast: 4 elems/thread
  int gBN128 = (int)(((long)N * 128 + 255) / 256);
  int gBN64  = (int)(((long)N * 64 + 255) / 256);

  hipMemsetAsync(cnt, 0, (size_t)N * 4, stream);
  hipMemsetAsync(stats, 0, 1024 * 4, stream);

  // ---- CSR build + weight packing + x cast ----
  k_hist<<<gE, blk, 0, stream>>>(dst, cnt, E);
  k_scan<<<1, 1024, 0, stream>>>(cnt, indptr, N);
  hipMemcpyAsync(cursor, indptr, (size_t)N * 4, hipMemcpyDeviceToDevice, stream);
  k_fill<<<gE, blk, 0, stream>>>(src, dst, cursor, csr_src, E);
  k_cast<<<gC, blk, 0, stream>>>(x, xbf, (long)N * 32);
  k_pack<<<32,  blk, 0, stream>>>(Wsk, WtSk, 128, 64, 64);
  k_pack<<<64,  blk, 0, stream>>>(Wl1, WtL1, 128, 128, 128);
  k_pack<<<64,  blk, 0, stream>>>(Wr1, WtR1, 128, 128, 128);
  k_pack<<<256, blk, 0, stream>>>(Wg,  WtG,  128, 512, 512);
  k_pack<<<32,  blk, 0, stream>>>(Wl3, WtL3, 128, 64, 64);
  k_pack<<<32,  blk, 0, stream>>>(Wr3, WtR3, 128, 64, 64);
  k_pack<<<16,  blk, 0, stream>>>(Wc1, WtC1, 64, 64, 64);
  k_pack<<<8,   blk, 0, stream>>>(Wc2, WtC2, 64, 32, 32);

  // ---- SAGE1 ----
  k_gmean_bf<128><<<gW, blk, 0, stream>>>(xbf, indptr, csr_src, mean1bf, N);
  k_mgemm<2><<<dim3(gN64, 1), blk, 0, stream>>>(
      xbf, 1, WtSk, nullptr, 0, nullptr, bsk, nullptr, idbf, 1, N, 128, 64, 0);
  k_mgemm<4><<<dim3(gN64, 1), blk, 0, stream>>>(
      mean1bf, 1, WtL1, xbf, 1, WtR1, b1, nullptr, hB, 0, N, 128, 128, 0);
  k_stats<<<256, blk, 0, stream>>>(hB, st1, N, 128);
  k_bn<<<gBN128, blk, 0, stream>>>(hB, st1, g1, be1, nullptr, h1bf, N, 128);

  // ---- GAT ----
  k_foldatt<<<4, blk, 0, stream>>>(Wg, atts, attd, attw);
  k_attdots<<<2048, blk, 0, stream>>>(hB, attw, asad, N);
  k_alpha<<<gA, blk, 0, stream>>>(indptr, csr_src, asad, alpha, N);
  for (int h0 = 0; h0 < 4; h0 += G) {
    k_mgemm<4><<<dim3(gN64, G), blk, 0, stream>>>(
        h1bf, 1, WtG + (size_t)h0 * 128 * 128, nullptr, 0, nullptr,
        nullptr, nullptr, xh, 1, N, 128, G * 128, 0);
    k_gatw<<<gW, blk, 0, stream>>>(xh, indptr, csr_src, alpha, h2, N, G, h0);
  }
  k_stats<<<256, blk, 0, stream>>>(h2, st2, N, 128);
  k_bn<<<gBN128, blk, 0, stream>>>(h2, st2, g2, be2, nullptr, h2bf, N, 128);

  // ---- SAGE3 (mean commutes with @Wl3: project first, gather 64-wide) ----
  k_mgemm<2><<<dim3(gN64, 1), blk, 0, stream>>>(
      h2bf, 1, WtL3, nullptr, 0, nullptr, nullptr, nullptr, yl3, 1, N, 128, 64, 0);
  k_gmean_bf<64><<<gW, blk, 0, stream>>>(yl3, indptr, csr_src, mean3bf, N);
  k_mgemm<2><<<dim3(gN64, 1), blk, 0, stream>>>(
      h2bf, 1, WtR3, nullptr, 0, nullptr, b3, mean3bf, h3, 0, N, 128, 64, 0);
  k_stats<<<256, blk, 0, stream>>>(h3, st3, N, 64);
  k_bn<<<gBN64, blk, 0, stream>>>(h3, st3, g3, be3, idbf, nullptr, N, 64);  // +identity

  // ---- classifier ----
  k_mgemm<2><<<dim3(gN64, 1), blk, 0, stream>>>(
      h3, 0, WtC1, nullptr, 0, nullptr, bc1, nullptr, z1, 0, N, 64, 64, 0);
  k_stats<<<256, blk, 0, stream>>>(z1, st4, N, 64);
  k_bn<<<gBN64, blk, 0, stream>>>(z1, st4, gc, bec, nullptr, nullptr, N, 64);
  k_mgemm<1><<<dim3(gN64, 1), blk, 0, stream>>>(
      z1, 0, WtC2, nullptr, 0, nullptr, bc2, nullptr, z2, 0, N, 64, 32, 1);
  k_final<<<(N + 255) / 256, blk, 0, stream>>>(z2, Wc3, bc3, (float*)d_out, N);
}

// Round 8
// 1054.401 us; speedup vs baseline: 4.3841x; 1.0954x over previous
//
#include <hip/hip_runtime.h>
#include <hip/hip_bf16.h>
#include <cmath>

// ---------------------------------------------------------------------------
// MuleHunterGNN: SAGE -> GAT -> SAGE -> skip -> MLP classifier
// CSR-gather aggregation; GAT softmax split out of gather; all GEMMs on MFMA
// (bf16 in, fp32 acc); bf16 for all gathered / GEMM-A intermediates.
// Round 7: multi-block scan (was 112us single-block), attdots reads bf16.
// ---------------------------------------------------------------------------

typedef short s16x8 __attribute__((ext_vector_type(8)));
typedef float f32x4 __attribute__((ext_vector_type(4)));

__device__ __forceinline__ float bf2f(unsigned short u) {
  return __uint_as_float((unsigned)u << 16);
}
__device__ __forceinline__ unsigned short f2bf(float f) {
  __hip_bfloat16 h = __float2bfloat16(f);
  return *reinterpret_cast<unsigned short*>(&h);
}

// ---- CSR build -----------------------------------------------------------
__global__ void k_hist(const int* __restrict__ dst, int* __restrict__ cnt, int E) {
  int e = blockIdx.x * blockDim.x + threadIdx.x;
  if (e < E) atomicAdd(&cnt[dst[e]], 1);
}

// multi-block exclusive scan, chunk = 1024 elements per 256-thread block
__global__ __launch_bounds__(256) void k_scan1(const int* __restrict__ cnt,
                                               int* __restrict__ bsum, int N) {
  int base = blockIdx.x << 10;
  int t = threadIdx.x;
  int s = 0;
  #pragma unroll
  for (int j = 0; j < 4; ++j) {
    int i = base + t * 4 + j;
    if (i < N) s += cnt[i];
  }
  __shared__ int red[256];
  red[t] = s;
  __syncthreads();
  for (int off = 128; off; off >>= 1) {
    if (t < off) red[t] += red[t + off];
    __syncthreads();
  }
  if (t == 0) bsum[blockIdx.x] = red[0];
}

__global__ __launch_bounds__(1024) void k_scan2(int* __restrict__ bsum, int nb) {
  __shared__ int sh[1024];
  int t = threadIdx.x;
  int v = (t < nb) ? bsum[t] : 0;
  sh[t] = v;
  __syncthreads();
  for (int off = 1; off < 1024; off <<= 1) {
    int u = (t >= off) ? sh[t - off] : 0;
    __syncthreads();
    sh[t] += u;
    __syncthreads();
  }
  if (t < nb) bsum[t] = sh[t] - v;  // exclusive prefix
}

__global__ __launch_bounds__(256) void k_scan3(const int* __restrict__ cnt,
                                               const int* __restrict__ bsum,
                                               int* __restrict__ indptr,
                                               int* __restrict__ cursor, int N) {
  int base = blockIdx.x << 10;
  int t = threadIdx.x;
  int lane = t & 63, w = t >> 6;
  int i0 = base + t * 4;
  int v[4], s = 0;
  #pragma unroll
  for (int j = 0; j < 4; ++j) {
    int i = i0 + j;
    v[j] = (i < N) ? cnt[i] : 0;
    s += v[j];
  }
  int incl = s;
  #pragma unroll
  for (int off = 1; off < 64; off <<= 1) {
    int u = __shfl_up(incl, off);
    if (lane >= off) incl += u;
  }
  __shared__ int wsum[4];
  if (lane == 63) wsum[w] = incl;
  __syncthreads();
  int add = 0;
  for (int j = 0; j < w; ++j) add += wsum[j];
  int run = incl - s + add + bsum[blockIdx.x];
  #pragma unroll
  for (int j = 0; j < 4; ++j) {
    int i = i0 + j;
    if (i < N) {
      cursor[i] = run;
      run += v[j];
      indptr[i + 1] = run;
    }
  }
  if (blockIdx.x == 0 && t == 0) indptr[0] = 0;
}

__global__ void k_fill(const int* __restrict__ src, const int* __restrict__ dst,
                       int* __restrict__ cursor, int* __restrict__ csr_src, int E) {
  int e = blockIdx.x * blockDim.x + threadIdx.x;
  if (e >= E) return;
  int pos = atomicAdd(&cursor[dst[e]], 1);
  csr_src[pos] = src[e];
}

// ---- fp32 -> bf16 cast ----------------------------------------------------
__global__ void k_cast(const float* __restrict__ in, unsigned short* __restrict__ out,
                       long n4) {
  long t = (long)blockIdx.x * blockDim.x + threadIdx.x;
  if (t >= n4) return;
  float4 v = *reinterpret_cast<const float4*>(in + t * 4);
  ushort4 u;
  u.x = f2bf(v.x); u.y = f2bf(v.y); u.z = f2bf(v.z); u.w = f2bf(v.w);
  *reinterpret_cast<ushort4*>(out + t * 4) = u;
}

// ---- gather mean of bf16 rows (W = 128 or 64), bf16 out -------------------
template <int W>
__global__ __launch_bounds__(256) void k_gmean_bf(const unsigned short* __restrict__ X,
                                                  const int* __restrict__ indptr,
                                                  const int* __restrict__ csr,
                                                  unsigned short* __restrict__ out, int N) {
  long wid = ((long)blockIdx.x * blockDim.x + threadIdx.x) >> 6;
  if (wid >= N) return;
  int lane = threadIdx.x & 63;
  int b = indptr[wid], en = indptr[wid + 1];
  if (W == 128) {
    float ax = 0.f, ay = 0.f;
    for (int i = b; i < en; ++i) {
      int s = csr[i];
      ushort2 u = *reinterpret_cast<const ushort2*>(X + ((size_t)s << 7) + (lane << 1));
      ax += bf2f(u.x); ay += bf2f(u.y);
    }
    float inv = 1.0f / (float)max(en - b, 1);
    ushort2 o; o.x = f2bf(ax * inv); o.y = f2bf(ay * inv);
    *reinterpret_cast<ushort2*>(out + (wid << 7) + (lane << 1)) = o;
  } else {
    float a = 0.f;
    for (int i = b; i < en; ++i) {
      int s = csr[i];
      a += bf2f(X[((size_t)s << 6) + lane]);
    }
    float inv = 1.0f / (float)max(en - b, 1);
    out[(wid << 6) + lane] = f2bf(a * inv);
  }
}

// ---- GAT alpha: per-dst segment softmax, 8 lanes per dst ------------------
__global__ __launch_bounds__(256) void k_alpha(const int* __restrict__ indptr,
                                               const int* __restrict__ csr,
                                               const float* __restrict__ asad,
                                               float* __restrict__ alpha, int N) {
  long g = ((long)blockIdx.x * blockDim.x + threadIdx.x) >> 3;
  if (g >= N) return;
  int l8 = threadIdx.x & 7;
  int b = indptr[g], en = indptr[g + 1];
  float4 adv = *reinterpret_cast<const float4*>(asad + g * 8 + 4);
  float m[4] = {-INFINITY, -INFINITY, -INFINITY, -INFINITY};
  for (int i = b + l8; i < en; i += 8) {
    int s = csr[i];
    float4 a = *reinterpret_cast<const float4*>(asad + (size_t)s * 8);
    float e0 = a.x + adv.x, e1 = a.y + adv.y, e2 = a.z + adv.z, e3 = a.w + adv.w;
    e0 = e0 >= 0.f ? e0 : 0.2f * e0; e1 = e1 >= 0.f ? e1 : 0.2f * e1;
    e2 = e2 >= 0.f ? e2 : 0.2f * e2; e3 = e3 >= 0.f ? e3 : 0.2f * e3;
    m[0] = fmaxf(m[0], e0); m[1] = fmaxf(m[1], e1);
    m[2] = fmaxf(m[2], e2); m[3] = fmaxf(m[3], e3);
  }
  #pragma unroll
  for (int off = 1; off < 8; off <<= 1) {
    #pragma unroll
    for (int h = 0; h < 4; ++h) m[h] = fmaxf(m[h], __shfl_xor(m[h], off));
  }
  float den[4] = {0.f, 0.f, 0.f, 0.f};
  for (int i = b + l8; i < en; i += 8) {
    int s = csr[i];
    float4 a = *reinterpret_cast<const float4*>(asad + (size_t)s * 8);
    float e0 = a.x + adv.x, e1 = a.y + adv.y, e2 = a.z + adv.z, e3 = a.w + adv.w;
    e0 = e0 >= 0.f ? e0 : 0.2f * e0; e1 = e1 >= 0.f ? e1 : 0.2f * e1;
    e2 = e2 >= 0.f ? e2 : 0.2f * e2; e3 = e3 >= 0.f ? e3 : 0.2f * e3;
    float4 w;
    w.x = __expf(e0 - m[0]); w.y = __expf(e1 - m[1]);
    w.z = __expf(e2 - m[2]); w.w = __expf(e3 - m[3]);
    den[0] += w.x; den[1] += w.y; den[2] += w.z; den[3] += w.w;
    *reinterpret_cast<float4*>(alpha + (size_t)i * 4) = w;
  }
  #pragma unroll
  for (int off = 1; off < 8; off <<= 1) {
    #pragma unroll
    for (int h = 0; h < 4; ++h) den[h] += __shfl_xor(den[h], off);
  }
  float s0 = 0.25f / fmaxf(den[0], 1e-16f);
  float s1 = 0.25f / fmaxf(den[1], 1e-16f);
  float s2 = 0.25f / fmaxf(den[2], 1e-16f);
  float s3 = 0.25f / fmaxf(den[3], 1e-16f);
  for (int i = b + l8; i < en; i += 8) {
    float4 w = *reinterpret_cast<const float4*>(alpha + (size_t)i * 4);
    w.x *= s0; w.y *= s1; w.z *= s2; w.w *= s3;
    *reinterpret_cast<float4*>(alpha + (size_t)i * 4) = w;
  }
}

// ---- GAT weighted gather: h2[d] (+)= sum_g alpha[e][g] * xh[src,g,:] -------
__global__ __launch_bounds__(256) void k_gatw(
    const unsigned short* __restrict__ xh, const int* __restrict__ indptr,
    const int* __restrict__ csr, const float* __restrict__ alpha,
    float* __restrict__ out, int N, int G, int h0) {
  long wid = ((long)blockIdx.x * blockDim.x + threadIdx.x) >> 6;
  if (wid >= N) return;
  int lane = threadIdx.x & 63;
  int b = indptr[wid], en = indptr[wid + 1];
  float ox = 0.f, oy = 0.f;
  for (int i = b; i < en; ++i) {
    int s = csr[i];
    float4 a4 = *reinterpret_cast<const float4*>(alpha + (size_t)i * 4);
    float aa[4] = {a4.x, a4.y, a4.z, a4.w};
    const unsigned short* xr = xh + (size_t)s * (G << 7) + (lane << 1);
    #pragma unroll 4
    for (int g = 0; g < G; ++g) {
      float w = aa[h0 + g];
      ushort2 u = *reinterpret_cast<const ushort2*>(xr + (g << 7));
      ox = fmaf(w, bf2f(u.x), ox);
      oy = fmaf(w, bf2f(u.y), oy);
    }
  }
  float* po = out + (wid << 7) + (lane << 1);
  if (h0 > 0) { ox += po[0]; oy += po[1]; }
  *reinterpret_cast<float2*>(po) = make_float2(ox, oy);
}

// ---- weight pack: Wt[c][k] = bf16(W[k][c]), pitch M ------------------------
__global__ void k_pack(const float* __restrict__ W, unsigned short* __restrict__ Wt,
                       int M, int cols, int ldW) {
  int t = blockIdx.x * blockDim.x + threadIdx.x;
  if (t >= M * cols) return;
  int c = t / M, k = t - c * M;
  Wt[t] = f2bf(W[(size_t)k * ldW + c]);
}

// ---- MFMA GEMM: C = A1@W1 [+ A2@W2] + bias [+ Cadd]; A fp32 or bf16 -------
template <int CF>
__global__ __launch_bounds__(256) void k_mgemm(
    const void* __restrict__ A1, int a1bf, const unsigned short* __restrict__ Wt1,
    const void* __restrict__ A2, int a2bf, const unsigned short* __restrict__ Wt2,
    const float* __restrict__ bias, const unsigned short* __restrict__ Cadd,
    void* __restrict__ Cout, int obf16,
    int Nrows, int M, int ldC, int relu) {
  constexpr int BN = CF * 32;
  __shared__ alignas(16) unsigned short sA[64][136];
  __shared__ alignas(16) unsigned short sBt[128][136];
  const int tid = threadIdx.x;
  const int lane = tid & 63;
  const int w = tid >> 6;
  const int wr = (w >> 1) * 32;
  const int wc = (w & 1) * (CF * 16);
  const int lr = lane & 15;
  const int lk = (lane >> 4) << 3;
  const int row0 = blockIdx.x * 64;
  const int colb = blockIdx.y * BN;

  f32x4 acc[2][CF];
  #pragma unroll
  for (int i = 0; i < 2; ++i)
    #pragma unroll
    for (int j = 0; j < CF; ++j) acc[i][j] = (f32x4){0.f, 0.f, 0.f, 0.f};

  for (int pass = 0; pass < 2; ++pass) {
    const void* A = pass ? A2 : A1;
    const int abf = pass ? a2bf : a1bf;
    const unsigned short* Wt = pass ? Wt2 : Wt1;
    if (!A) break;
    for (int i = tid * 4; i < 64 * M; i += 1024) {
      int r = i / M, k = i - r * M;
      int gr = row0 + r;
      ushort4 u = make_ushort4(0, 0, 0, 0);
      if (gr < Nrows) {
        if (abf) {
          u = *reinterpret_cast<const ushort4*>((const unsigned short*)A + (size_t)gr * M + k);
        } else {
          float4 v = *reinterpret_cast<const float4*>((const float*)A + (size_t)gr * M + k);
          u.x = f2bf(v.x); u.y = f2bf(v.y); u.z = f2bf(v.z); u.w = f2bf(v.w);
        }
      }
      *reinterpret_cast<ushort4*>(&sA[r][k]) = u;
    }
    for (int i = tid * 4; i < BN * M; i += 1024) {
      int c = i / M, k = i - c * M;
      ushort4 u = *reinterpret_cast<const ushort4*>(Wt + (size_t)(colb + c) * M + k);
      *reinterpret_cast<ushort4*>(&sBt[c][k]) = u;
    }
    __syncthreads();
    for (int k0 = lk; k0 < M; k0 += 32) {
      s16x8 a0 = *reinterpret_cast<const s16x8*>(&sA[wr + lr][k0]);
      s16x8 a1 = *reinterpret_cast<const s16x8*>(&sA[wr + lr + 16][k0]);
      #pragma unroll
      for (int j = 0; j < CF; ++j) {
        s16x8 bj = *reinterpret_cast<const s16x8*>(&sBt[wc + lr + 16 * j][k0]);
        acc[0][j] = __builtin_amdgcn_mfma_f32_16x16x32_bf16(a0, bj, acc[0][j], 0, 0, 0);
        acc[1][j] = __builtin_amdgcn_mfma_f32_16x16x32_bf16(a1, bj, acc[1][j], 0, 0, 0);
      }
    }
    __syncthreads();
  }

  // epilogue: D col = lane&15, row = 4*(lane>>4)+reg  [m89/m91]
  const int rbase = (lane >> 4) << 2;
  #pragma unroll
  for (int i = 0; i < 2; ++i) {
    int grow = row0 + wr + 16 * i + rbase;
    #pragma unroll
    for (int j = 0; j < CF; ++j) {
      int col = colb + wc + 16 * j + lr;
      float bv = bias ? bias[col] : 0.f;
      #pragma unroll
      for (int r = 0; r < 4; ++r) {
        if (grow + r >= Nrows) continue;
        float v = acc[i][j][r] + bv;
        if (Cadd) v += bf2f(Cadd[(size_t)(grow + r) * ldC + col]);
        if (relu) v = fmaxf(v, 0.f);
        if (obf16)
          ((unsigned short*)Cout)[(size_t)(grow + r) * ldC + col] = f2bf(v);
        else
          ((float*)Cout)[(size_t)(grow + r) * ldC + col] = v;
      }
    }
  }
}

// ---- per-column sum / sumsq (K in {64,128}) --------------------------------
__global__ void k_stats(const float* __restrict__ X, float* __restrict__ stats,
                        int Nrows, int K) {
  int c = threadIdx.x & (K - 1);
  int rl = threadIdx.x / K;
  int rpb = 256 / K;
  float s = 0.f, s2 = 0.f;
  for (long r = (long)blockIdx.x * rpb + rl; r < Nrows; r += (long)gridDim.x * rpb) {
    float v = X[r * K + c];
    s += v;
    s2 = fmaf(v, v, s2);
  }
  __shared__ float b1s[256], b2s[256];
  b1s[threadIdx.x] = s; b2s[threadIdx.x] = s2;
  __syncthreads();
  if (rl == 0) {
    for (int t = 1; t < rpb; ++t) { s += b1s[t * K + c]; s2 += b2s[t * K + c]; }
    atomicAdd(&stats[c], s);
    atomicAdd(&stats[128 + c], s2);
  }
}

// ---- BN + ReLU (+ bf16 residual after relu) (+ optional bf16 mirror) -------
__global__ void k_bn(float* __restrict__ X, const float* __restrict__ stats,
                     const float* __restrict__ g, const float* __restrict__ b,
                     const unsigned short* __restrict__ addAfter,
                     unsigned short* __restrict__ mirror,
                     int Nrows, int K) {
  long i = (long)blockIdx.x * blockDim.x + threadIdx.x;
  if (i >= (long)Nrows * K) return;
  int c = (int)(i & (K - 1));
  float invN = 1.0f / (float)Nrows;
  float m = stats[c] * invN;
  float v = stats[128 + c] * invN - m * m;
  float y = g[c] * (X[i] - m) * rsqrtf(v + 1e-5f) + b[c];
  y = fmaxf(y, 0.f);
  if (addAfter) y += bf2f(addAfter[i]);
  X[i] = y;
  if (mirror) mirror[i] = f2bf(y);
}

// ---- fold attention vectors -------------------------------------------------
__global__ void k_foldatt(const float* __restrict__ Wg, const float* __restrict__ atts,
                          const float* __restrict__ attd, float* __restrict__ attw) {
  int t = blockIdx.x * blockDim.x + threadIdx.x;
  if (t >= 1024) return;
  int k = t >> 3, j = t & 7, h = j & 3;
  const float* av = (j < 4 ? atts : attd) + h * 128;
  const float* wg = Wg + (size_t)k * 512 + h * 128;
  float s = 0.f;
  for (int c = 0; c < 128; ++c) s = fmaf(wg[c], av[c], s);
  attw[t] = s;
}

// ---- a_s/a_d per node from bf16 h1, one wave each, grid-stride --------------
__global__ void k_attdots(const unsigned short* __restrict__ h1bf,
                          const float* __restrict__ attw,
                          float* __restrict__ asad, int Nrows) {
  int lane = threadIdx.x & 63;
  float c0[8], c1[8];
  #pragma unroll
  for (int j = 0; j < 8; ++j) {
    c0[j] = attw[(2 * lane) * 8 + j];
    c1[j] = attw[(2 * lane + 1) * 8 + j];
  }
  long wid = ((long)blockIdx.x * blockDim.x + threadIdx.x) >> 6;
  long nw = ((long)gridDim.x * blockDim.x) >> 6;
  for (long n = wid; n < Nrows; n += nw) {
    ushort2 u = *reinterpret_cast<const ushort2*>(h1bf + (n << 7) + (lane << 1));
    float vx = bf2f(u.x), vy = bf2f(u.y);
    float a[8];
    #pragma unroll
    for (int j = 0; j < 8; ++j) a[j] = vx * c0[j] + vy * c1[j];
    #pragma unroll
    for (int off = 1; off < 64; off <<= 1) {
      #pragma unroll
      for (int j = 0; j < 8; ++j) a[j] += __shfl_xor(a[j], off);
    }
    if (lane == 0) {
      *reinterpret_cast<float4*>(asad + n * 8)     = make_float4(a[0], a[1], a[2], a[3]);
      *reinterpret_cast<float4*>(asad + n * 8 + 4) = make_float4(a[4], a[5], a[6], a[7]);
    }
  }
}

// ---- final: logits = z2 @ Wc3 + bc3; log_softmax ----------------------------
__global__ void k_final(const float* __restrict__ z2, const float* __restrict__ W,
                        const float* __restrict__ b, float* __restrict__ out, int Nrows) {
  int n = blockIdx.x * blockDim.x + threadIdx.x;
  if (n >= Nrows) return;
  float l0 = b[0], l1 = b[1];
  const float* z = z2 + (size_t)n * 32;
  #pragma unroll
  for (int k = 0; k < 32; ++k) {
    float v = z[k];
    l0 = fmaf(v, W[2 * k], l0);
    l1 = fmaf(v, W[2 * k + 1], l1);
  }
  float m = fmaxf(l0, l1);
  float lse = m + logf(expf(l0 - m) + expf(l1 - m));
  out[2 * n] = l0 - lse;
  out[2 * n + 1] = l1 - lse;
}

// ---------------------------------------------------------------------------
extern "C" void kernel_launch(void* const* d_in, const int* in_sizes, int n_in,
                              void* d_out, int out_size, void* d_ws, size_t ws_size,
                              hipStream_t stream) {
  const float* x    = (const float*)d_in[0];
  const int*   ei   = (const int*)  d_in[1];
  const float* Wl1  = (const float*)d_in[2];
  const float* Wr1  = (const float*)d_in[3];
  const float* b1   = (const float*)d_in[4];
  const float* g1   = (const float*)d_in[5];
  const float* be1  = (const float*)d_in[6];
  const float* Wg   = (const float*)d_in[7];
  const float* atts = (const float*)d_in[8];
  const float* attd = (const float*)d_in[9];
  // d_in[10] = bg: constant column offset, cancels exactly in the following BN.
  const float* g2   = (const float*)d_in[11];
  const float* be2  = (const float*)d_in[12];
  const float* Wl3  = (const float*)d_in[13];
  const float* Wr3  = (const float*)d_in[14];
  const float* b3   = (const float*)d_in[15];
  const float* g3   = (const float*)d_in[16];
  const float* be3  = (const float*)d_in[17];
  const float* Wsk  = (const float*)d_in[18];
  const float* bsk  = (const float*)d_in[19];
  const float* Wc1  = (const float*)d_in[20];
  const float* bc1  = (const float*)d_in[21];
  const float* gc   = (const float*)d_in[22];
  const float* bec  = (const float*)d_in[23];
  const float* Wc2  = (const float*)d_in[24];
  const float* bc2  = (const float*)d_in[25];
  const float* Wc3  = (const float*)d_in[26];
  const float* bc3  = (const float*)d_in[27];
  (void)n_in; (void)out_size;

  const int N = in_sizes[0] / 128;
  const int E = in_sizes[1] / 2;
  const int* src = ei;
  const int* dst = ei + E;

  // ---- workspace carve-out (fp32 words) -------------------------------------
  auto al4 = [](size_t w) { return (w + 3) & ~(size_t)3; };
  float* ws = (float*)d_ws;
  size_t o = 0;
  int* cnt      = (int*)(ws + o); o += al4((size_t)N);
  int* indptr   = (int*)(ws + o); o += al4((size_t)N + 1);
  int* cursor   = (int*)(ws + o); o += al4((size_t)N);
  int* csr_src  = (int*)(ws + o); o += al4((size_t)E);
  int* bsum     = (int*)(ws + o); o += 1024;
  unsigned short* idbf = (unsigned short*)(ws + o); o += al4((size_t)N * 32);  // [N,64] bf16
  float* stats  = ws + o; o += 1024;
  float* attw   = ws + o; o += 1024;
  float* asad   = ws + o; o += al4((size_t)N * 8);
  float* alpha  = ws + o; o += al4((size_t)E * 4);
  unsigned short* wt = (unsigned short*)(ws + o); o += 64512 + 64;  // packed weights
  float* bufA   = ws + o; o += (size_t)N * 128;   // xbf+mean1bf / h1bf+h2bf / z1
  float* hB     = ws + o; o += (size_t)N * 128;   // h1 / h3+z2
  float* h2     = ws + o; o += (size_t)N * 128;
  unsigned short* xh = (unsigned short*)(ws + o); // [N, G*128] bf16; later yl3+mean3

  long avail = (long)(ws_size / 4) - (long)o;
  int G = 4;
  while (G > 1 && (long)N * 64 * G > avail) G >>= 1;

  // bufA aliases (bf16)
  unsigned short* xbf     = (unsigned short*)bufA;                    // [N,128] bf16
  unsigned short* mean1bf = (unsigned short*)(bufA + (size_t)N * 64); // [N,128] bf16
  unsigned short* h1bf    = (unsigned short*)bufA;                    // after SAGE1
  unsigned short* h2bf    = (unsigned short*)(bufA + (size_t)N * 64); // after SAGE1
  // xh aliases after GAT
  unsigned short* yl3     = xh;                                       // [N,64] bf16
  unsigned short* mean3bf = xh + (size_t)N * 64;                      // [N,64] bf16

  // packed-weight offsets (ushort units)
  unsigned short* WtSk = wt;                 // 64 x128
  unsigned short* WtL1 = WtSk + 8192;        // 128x128
  unsigned short* WtR1 = WtL1 + 16384;       // 128x128
  unsigned short* WtG  = WtR1 + 16384;       // 512x128
  unsigned short* WtL3 = WtG  + 65536;       // 64 x128
  unsigned short* WtR3 = WtL3 + 8192;        // 64 x128
  unsigned short* WtC1 = WtR3 + 8192;        // 64 x64
  unsigned short* WtC2 = WtC1 + 4096;        // 32 x64

  float* st1 = stats, *st2 = stats + 256, *st3 = stats + 512, *st4 = stats + 768;
  float* h3 = hB;
  float* z1 = bufA;
  float* z2 = hB + (size_t)N * 64;

  dim3 blk(256);
  int gE     = (E + 255) / 256;
  int gN64   = (N + 63) / 64;
  int gSC    = (N + 1023) / 1024;                   // scan blocks (chunk 1024)
  int gW     = (int)(((long)N * 64 + 255) / 256);   // one wave per node
  int gA     = (int)(((long)N * 8 + 255) / 256);    // 8 lanes per node
  int gC     = (int)(((long)N * 32 + 255) / 256);   // cast: 4 elems/thread
  int gBN128 = (int)(((long)N * 128 + 255) / 256);
  int gBN64  = (int)(((long)N * 64 + 255) / 256);

  hipMemsetAsync(cnt, 0, (size_t)N * 4, stream);
  hipMemsetAsync(stats, 0, 1024 * 4, stream);

  // ---- CSR build (multi-block scan) + weight packing + x cast ----
  k_hist<<<gE, blk, 0, stream>>>(dst, cnt, E);
  k_scan1<<<gSC, blk, 0, stream>>>(cnt, bsum, N);
  k_scan2<<<1, 1024, 0, stream>>>(bsum, gSC);
  k_scan3<<<gSC, blk, 0, stream>>>(cnt, bsum, indptr, cursor, N);
  k_fill<<<gE, blk, 0, stream>>>(src, dst, cursor, csr_src, E);
  k_cast<<<gC, blk, 0, stream>>>(x, xbf, (long)N * 32);
  k_pack<<<32,  blk, 0, stream>>>(Wsk, WtSk, 128, 64, 64);
  k_pack<<<64,  blk, 0, stream>>>(Wl1, WtL1, 128, 128, 128);
  k_pack<<<64,  blk, 0, stream>>>(Wr1, WtR1, 128, 128, 128);
  k_pack<<<256, blk, 0, stream>>>(Wg,  WtG,  128, 512, 512);
  k_pack<<<32,  blk, 0, stream>>>(Wl3, WtL3, 128, 64, 64);
  k_pack<<<32,  blk, 0, stream>>>(Wr3, WtR3, 128, 64, 64);
  k_pack<<<16,  blk, 0, stream>>>(Wc1, WtC1, 64, 64, 64);
  k_pack<<<8,   blk, 0, stream>>>(Wc2, WtC2, 64, 32, 32);

  // ---- SAGE1 ----
  k_gmean_bf<128><<<gW, blk, 0, stream>>>(xbf, indptr, csr_src, mean1bf, N);
  k_mgemm<2><<<dim3(gN64, 1), blk, 0, stream>>>(
      xbf, 1, WtSk, nullptr, 0, nullptr, bsk, nullptr, idbf, 1, N, 128, 64, 0);
  k_mgemm<4><<<dim3(gN64, 1), blk, 0, stream>>>(
      mean1bf, 1, WtL1, xbf, 1, WtR1, b1, nullptr, hB, 0, N, 128, 128, 0);
  k_stats<<<256, blk, 0, stream>>>(hB, st1, N, 128);
  k_bn<<<gBN128, blk, 0, stream>>>(hB, st1, g1, be1, nullptr, h1bf, N, 128);

  // ---- GAT ----
  k_foldatt<<<4, blk, 0, stream>>>(Wg, atts, attd, attw);
  k_attdots<<<2048, blk, 0, stream>>>(h1bf, attw, asad, N);
  k_alpha<<<gA, blk, 0, stream>>>(indptr, csr_src, asad, alpha, N);
  for (int h0 = 0; h0 < 4; h0 += G) {
    k_mgemm<4><<<dim3(gN64, G), blk, 0, stream>>>(
        h1bf, 1, WtG + (size_t)h0 * 128 * 128, nullptr, 0, nullptr,
        nullptr, nullptr, xh, 1, N, 128, G * 128, 0);
    k_gatw<<<gW, blk, 0, stream>>>(xh, indptr, csr_src, alpha, h2, N, G, h0);
  }
  k_stats<<<256, blk, 0, stream>>>(h2, st2, N, 128);
  k_bn<<<gBN128, blk, 0, stream>>>(h2, st2, g2, be2, nullptr, h2bf, N, 128);

  // ---- SAGE3 (mean commutes with @Wl3: project first, gather 64-wide) ----
  k_mgemm<2><<<dim3(gN64, 1), blk, 0, stream>>>(
      h2bf, 1, WtL3, nullptr, 0, nullptr, nullptr, nullptr, yl3, 1, N, 128, 64, 0);
  k_gmean_bf<64><<<gW, blk, 0, stream>>>(yl3, indptr, csr_src, mean3bf, N);
  k_mgemm<2><<<dim3(gN64, 1), blk, 0, stream>>>(
      h2bf, 1, WtR3, nullptr, 0, nullptr, b3, mean3bf, h3, 0, N, 128, 64, 0);
  k_stats<<<256, blk, 0, stream>>>(h3, st3, N, 64);
  k_bn<<<gBN64, blk, 0, stream>>>(h3, st3, g3, be3, idbf, nullptr, N, 64);  // +identity

  // ---- classifier ----
  k_mgemm<2><<<dim3(gN64, 1), blk, 0, stream>>>(
      h3, 0, WtC1, nullptr, 0, nullptr, bc1, nullptr, z1, 0, N, 64, 64, 0);
  k_stats<<<256, blk, 0, stream>>>(z1, st4, N, 64);
  k_bn<<<gBN64, blk, 0, stream>>>(z1, st4, gc, bec, nullptr, nullptr, N, 64);
  k_mgemm<1><<<dim3(gN64, 1), blk, 0, stream>>>(
      z1, 0, WtC2, nullptr, 0, nullptr, bc2, nullptr, z2, 0, N, 64, 32, 1);
  k_final<<<(N + 255) / 256, blk, 0, stream>>>(z2, Wc3, bc3, (float*)d_out, N);
}

// Round 10
// 935.050 us; speedup vs baseline: 4.9437x; 1.1276x over previous
//
#include <hip/hip_runtime.h>
#include <hip/hip_bf16.h>
#include <cmath>

// ---------------------------------------------------------------------------
// MuleHunterGNN: SAGE -> GAT -> SAGE -> skip -> MLP classifier
// CSR-gather; GAT aggregation in h1-space (alpha-weighted gather + one K=512
// MFMA GEMM). Round 10: replay-deterministic numerics -- BN stats via
// fixed-order two-phase reduction (no float atomics), mean3 Cadd kept fp32
// (bf16-ulp flips from CSR permutation were amplified ~28x by BN gain).
// ---------------------------------------------------------------------------

typedef short s16x8 __attribute__((ext_vector_type(8)));
typedef float f32x4 __attribute__((ext_vector_type(4)));

__device__ __forceinline__ float bf2f(unsigned short u) {
  return __uint_as_float((unsigned)u << 16);
}
__device__ __forceinline__ unsigned short f2bf(float f) {
  __hip_bfloat16 h = __float2bfloat16(f);
  return *reinterpret_cast<unsigned short*>(&h);
}

// ---- CSR build -----------------------------------------------------------
__global__ void k_hist(const int* __restrict__ dst, int* __restrict__ cnt, int E) {
  int e = blockIdx.x * blockDim.x + threadIdx.x;
  if (e < E) atomicAdd(&cnt[dst[e]], 1);
}

__global__ __launch_bounds__(256) void k_scan1(const int* __restrict__ cnt,
                                               int* __restrict__ bsum, int N) {
  int base = blockIdx.x << 10;
  int t = threadIdx.x;
  int s = 0;
  #pragma unroll
  for (int j = 0; j < 4; ++j) {
    int i = base + t * 4 + j;
    if (i < N) s += cnt[i];
  }
  __shared__ int red[256];
  red[t] = s;
  __syncthreads();
  for (int off = 128; off; off >>= 1) {
    if (t < off) red[t] += red[t + off];
    __syncthreads();
  }
  if (t == 0) bsum[blockIdx.x] = red[0];
}

__global__ __launch_bounds__(1024) void k_scan2(int* __restrict__ bsum, int nb) {
  __shared__ int sh[1024];
  int t = threadIdx.x;
  int v = (t < nb) ? bsum[t] : 0;
  sh[t] = v;
  __syncthreads();
  for (int off = 1; off < 1024; off <<= 1) {
    int u = (t >= off) ? sh[t - off] : 0;
    __syncthreads();
    sh[t] += u;
    __syncthreads();
  }
  if (t < nb) bsum[t] = sh[t] - v;  // exclusive prefix
}

__global__ __launch_bounds__(256) void k_scan3(const int* __restrict__ cnt,
                                               const int* __restrict__ bsum,
                                               int* __restrict__ indptr,
                                               int* __restrict__ cursor, int N) {
  int base = blockIdx.x << 10;
  int t = threadIdx.x;
  int lane = t & 63, w = t >> 6;
  int i0 = base + t * 4;
  int v[4], s = 0;
  #pragma unroll
  for (int j = 0; j < 4; ++j) {
    int i = i0 + j;
    v[j] = (i < N) ? cnt[i] : 0;
    s += v[j];
  }
  int incl = s;
  #pragma unroll
  for (int off = 1; off < 64; off <<= 1) {
    int u = __shfl_up(incl, off);
    if (lane >= off) incl += u;
  }
  __shared__ int wsum[4];
  if (lane == 63) wsum[w] = incl;
  __syncthreads();
  int add = 0;
  for (int j = 0; j < w; ++j) add += wsum[j];
  int run = incl - s + add + bsum[blockIdx.x];
  #pragma unroll
  for (int j = 0; j < 4; ++j) {
    int i = i0 + j;
    if (i < N) {
      cursor[i] = run;
      run += v[j];
      indptr[i + 1] = run;
    }
  }
  if (blockIdx.x == 0 && t == 0) indptr[0] = 0;
}

__global__ void k_fill(const int* __restrict__ src, const int* __restrict__ dst,
                       int* __restrict__ cursor, int* __restrict__ csr_src, int E) {
  int e = blockIdx.x * blockDim.x + threadIdx.x;
  if (e >= E) return;
  int pos = atomicAdd(&cursor[dst[e]], 1);
  csr_src[pos] = src[e];
}

// ---- fp32 -> bf16 cast ----------------------------------------------------
__global__ void k_cast(const float* __restrict__ in, unsigned short* __restrict__ out,
                       long n4) {
  long t = (long)blockIdx.x * blockDim.x + threadIdx.x;
  if (t >= n4) return;
  float4 v = *reinterpret_cast<const float4*>(in + t * 4);
  ushort4 u;
  u.x = f2bf(v.x); u.y = f2bf(v.y); u.z = f2bf(v.z); u.w = f2bf(v.w);
  *reinterpret_cast<ushort4*>(out + t * 4) = u;
}

// ---- all weight packs in one launch (129024 ushorts total) -----------------
__global__ void k_packall(const float* __restrict__ Wsk, const float* __restrict__ Wl1,
                          const float* __restrict__ Wr1, const float* __restrict__ Wg,
                          const float* __restrict__ Wl3, const float* __restrict__ Wr3,
                          const float* __restrict__ Wc1, const float* __restrict__ Wc2,
                          unsigned short* __restrict__ wt) {
  int t = blockIdx.x * blockDim.x + threadIdx.x;
  if (t >= 129024) return;
  float v;
  if (t < 8192) {                 // WtSk [64c][128k]
    int c = t >> 7, k = t & 127;
    v = Wsk[k * 64 + c];
  } else if (t < 24576) {         // WtL1 [128c][128k]
    int r = t - 8192; int c = r >> 7, k = r & 127;
    v = Wl1[k * 128 + c];
  } else if (t < 40960) {         // WtR1 [128c][128k]
    int r = t - 24576; int c = r >> 7, k = r & 127;
    v = Wr1[k * 128 + c];
  } else if (t < 106496) {        // WtG2 [128c][512k], kg=h*128+k <- Wg[k][h*128+c]
    int r = t - 40960; int c = r >> 9; int q = r & 511; int h = q >> 7, k = q & 127;
    v = Wg[k * 512 + h * 128 + c];
  } else if (t < 114688) {        // WtL3 [64c][128k]
    int r = t - 106496; int c = r >> 7, k = r & 127;
    v = Wl3[k * 64 + c];
  } else if (t < 122880) {        // WtR3 [64c][128k]
    int r = t - 114688; int c = r >> 7, k = r & 127;
    v = Wr3[k * 64 + c];
  } else if (t < 126976) {        // WtC1 [64c][64k]
    int r = t - 122880; int c = r >> 6, k = r & 63;
    v = Wc1[k * 64 + c];
  } else {                        // WtC2 [32c][64k]
    int r = t - 126976; int c = r >> 6, k = r & 63;
    v = Wc2[k * 32 + c];
  }
  wt[t] = f2bf(v);
}

// ---- gather mean of bf16 rows (W=128/64), bf16 or fp32 out -----------------
template <int W, int OBF>
__global__ __launch_bounds__(256) void k_gmean(const unsigned short* __restrict__ X,
                                               const int* __restrict__ indptr,
                                               const int* __restrict__ csr,
                                               void* __restrict__ out, int N) {
  long wid = ((long)blockIdx.x * blockDim.x + threadIdx.x) >> 6;
  if (wid >= N) return;
  int lane = threadIdx.x & 63;
  int b = indptr[wid], en = indptr[wid + 1];
  if (W == 128) {
    float ax = 0.f, ay = 0.f;
    for (int i = b; i < en; ++i) {
      int s = csr[i];
      ushort2 u = *reinterpret_cast<const ushort2*>(X + ((size_t)s << 7) + (lane << 1));
      ax += bf2f(u.x); ay += bf2f(u.y);
    }
    float inv = 1.0f / (float)max(en - b, 1);
    ax *= inv; ay *= inv;
    if (OBF) {
      ushort2 o; o.x = f2bf(ax); o.y = f2bf(ay);
      *reinterpret_cast<ushort2*>((unsigned short*)out + (wid << 7) + (lane << 1)) = o;
    } else {
      *reinterpret_cast<float2*>((float*)out + (wid << 7) + (lane << 1)) =
          make_float2(ax, ay);
    }
  } else {
    float a = 0.f;
    for (int i = b; i < en; ++i) {
      int s = csr[i];
      a += bf2f(X[((size_t)s << 6) + lane]);
    }
    float inv = 1.0f / (float)max(en - b, 1);
    a *= inv;
    if (OBF) ((unsigned short*)out)[(wid << 6) + lane] = f2bf(a);
    else     ((float*)out)[(wid << 6) + lane] = a;
  }
}

// ---- GAT alpha: per-dst segment softmax, 8 lanes per dst ------------------
__global__ __launch_bounds__(256) void k_alpha(const int* __restrict__ indptr,
                                               const int* __restrict__ csr,
                                               const float* __restrict__ asad,
                                               float* __restrict__ alpha, int N) {
  long g = ((long)blockIdx.x * blockDim.x + threadIdx.x) >> 3;
  if (g >= N) return;
  int l8 = threadIdx.x & 7;
  int b = indptr[g], en = indptr[g + 1];
  float4 adv = *reinterpret_cast<const float4*>(asad + g * 8 + 4);
  float m[4] = {-INFINITY, -INFINITY, -INFINITY, -INFINITY};
  for (int i = b + l8; i < en; i += 8) {
    int s = csr[i];
    float4 a = *reinterpret_cast<const float4*>(asad + (size_t)s * 8);
    float e0 = a.x + adv.x, e1 = a.y + adv.y, e2 = a.z + adv.z, e3 = a.w + adv.w;
    e0 = e0 >= 0.f ? e0 : 0.2f * e0; e1 = e1 >= 0.f ? e1 : 0.2f * e1;
    e2 = e2 >= 0.f ? e2 : 0.2f * e2; e3 = e3 >= 0.f ? e3 : 0.2f * e3;
    m[0] = fmaxf(m[0], e0); m[1] = fmaxf(m[1], e1);
    m[2] = fmaxf(m[2], e2); m[3] = fmaxf(m[3], e3);
  }
  #pragma unroll
  for (int off = 1; off < 8; off <<= 1) {
    #pragma unroll
    for (int h = 0; h < 4; ++h) m[h] = fmaxf(m[h], __shfl_xor(m[h], off));
  }
  float den[4] = {0.f, 0.f, 0.f, 0.f};
  for (int i = b + l8; i < en; i += 8) {
    int s = csr[i];
    float4 a = *reinterpret_cast<const float4*>(asad + (size_t)s * 8);
    float e0 = a.x + adv.x, e1 = a.y + adv.y, e2 = a.z + adv.z, e3 = a.w + adv.w;
    e0 = e0 >= 0.f ? e0 : 0.2f * e0; e1 = e1 >= 0.f ? e1 : 0.2f * e1;
    e2 = e2 >= 0.f ? e2 : 0.2f * e2; e3 = e3 >= 0.f ? e3 : 0.2f * e3;
    float4 w;
    w.x = __expf(e0 - m[0]); w.y = __expf(e1 - m[1]);
    w.z = __expf(e2 - m[2]); w.w = __expf(e3 - m[3]);
    den[0] += w.x; den[1] += w.y; den[2] += w.z; den[3] += w.w;
    *reinterpret_cast<float4*>(alpha + (size_t)i * 4) = w;
  }
  #pragma unroll
  for (int off = 1; off < 8; off <<= 1) {
    #pragma unroll
    for (int h = 0; h < 4; ++h) den[h] += __shfl_xor(den[h], off);
  }
  float s0 = 0.25f / fmaxf(den[0], 1e-16f);
  float s1 = 0.25f / fmaxf(den[1], 1e-16f);
  float s2 = 0.25f / fmaxf(den[2], 1e-16f);
  float s3 = 0.25f / fmaxf(den[3], 1e-16f);
  for (int i = b + l8; i < en; i += 8) {
    float4 w = *reinterpret_cast<const float4*>(alpha + (size_t)i * 4);
    w.x *= s0; w.y *= s1; w.z *= s2; w.w *= s3;
    *reinterpret_cast<float4*>(alpha + (size_t)i * 4) = w;
  }
}

// ---- GAT gather in h1-space: agg[d, h*128+:] = sum_e alpha[e][h]*h1[src_e] --
__global__ __launch_bounds__(256) void k_gath1(
    const unsigned short* __restrict__ h1, const int* __restrict__ indptr,
    const int* __restrict__ csr, const float* __restrict__ alpha,
    unsigned short* __restrict__ agg, int N) {
  long wid = ((long)blockIdx.x * blockDim.x + threadIdx.x) >> 6;
  if (wid >= N) return;
  int lane = threadIdx.x & 63;
  int b = indptr[wid], en = indptr[wid + 1];
  float a0x = 0.f, a0y = 0.f, a1x = 0.f, a1y = 0.f;
  float a2x = 0.f, a2y = 0.f, a3x = 0.f, a3y = 0.f;
  for (int i = b; i < en; ++i) {
    int s = csr[i];
    float4 a = *reinterpret_cast<const float4*>(alpha + (size_t)i * 4);
    ushort2 u = *reinterpret_cast<const ushort2*>(h1 + ((size_t)s << 7) + (lane << 1));
    float vx = bf2f(u.x), vy = bf2f(u.y);
    a0x = fmaf(a.x, vx, a0x); a0y = fmaf(a.x, vy, a0y);
    a1x = fmaf(a.y, vx, a1x); a1y = fmaf(a.y, vy, a1y);
    a2x = fmaf(a.z, vx, a2x); a2y = fmaf(a.z, vy, a2y);
    a3x = fmaf(a.w, vx, a3x); a3y = fmaf(a.w, vy, a3y);
  }
  unsigned short* po = agg + ((size_t)wid << 9) + (lane << 1);
  ushort2 o;
  o.x = f2bf(a0x); o.y = f2bf(a0y); *reinterpret_cast<ushort2*>(po)       = o;
  o.x = f2bf(a1x); o.y = f2bf(a1y); *reinterpret_cast<ushort2*>(po + 128) = o;
  o.x = f2bf(a2x); o.y = f2bf(a2y); *reinterpret_cast<ushort2*>(po + 256) = o;
  o.x = f2bf(a3x); o.y = f2bf(a3y); *reinterpret_cast<ushort2*>(po + 384) = o;
}

// ---- MFMA GEMM: C = A1@W1 [+ A2@W2] + bias [+ Cadd(fp32)]; runtime K -------
template <int CF>
__global__ __launch_bounds__(256) void k_mgemm(
    const void* __restrict__ A1, int a1bf, int ldA1, int K1,
    const unsigned short* __restrict__ Wt1,
    const void* __restrict__ A2, int a2bf, int ldA2, int K2,
    const unsigned short* __restrict__ Wt2,
    const float* __restrict__ bias, const float* __restrict__ Cadd,
    void* __restrict__ Cout, int obf16,
    int Nrows, int ldC, int relu) {
  constexpr int BN = CF * 32;
  __shared__ alignas(16) unsigned short sA[64][136];
  __shared__ alignas(16) unsigned short sBt[128][136];
  const int tid = threadIdx.x;
  const int lane = tid & 63;
  const int w = tid >> 6;
  const int wr = (w >> 1) * 32;
  const int wc = (w & 1) * (CF * 16);
  const int lr = lane & 15;
  const int lk = (lane >> 4) << 3;
  const int row0 = blockIdx.x * 64;
  const int colb = blockIdx.y * BN;

  f32x4 acc[2][CF];
  #pragma unroll
  for (int i = 0; i < 2; ++i)
    #pragma unroll
    for (int j = 0; j < CF; ++j) acc[i][j] = (f32x4){0.f, 0.f, 0.f, 0.f};

  for (int pass = 0; pass < 2; ++pass) {
    const void* A = pass ? A2 : A1;
    if (!A) break;
    const int abf = pass ? a2bf : a1bf;
    const int ldA = pass ? ldA2 : ldA1;
    const int K = pass ? K2 : K1;
    const unsigned short* Wt = pass ? Wt2 : Wt1;
    for (int kb = 0; kb < K; kb += 128) {
      const int kw = min(128, K - kb);
      for (int i = tid * 4; i < 64 * kw; i += 1024) {
        int r = i / kw, k = i - r * kw;
        int gr = row0 + r;
        ushort4 u = make_ushort4(0, 0, 0, 0);
        if (gr < Nrows) {
          if (abf) {
            u = *reinterpret_cast<const ushort4*>(
                (const unsigned short*)A + (size_t)gr * ldA + kb + k);
          } else {
            float4 v = *reinterpret_cast<const float4*>(
                (const float*)A + (size_t)gr * ldA + kb + k);
            u.x = f2bf(v.x); u.y = f2bf(v.y); u.z = f2bf(v.z); u.w = f2bf(v.w);
          }
        }
        *reinterpret_cast<ushort4*>(&sA[r][k]) = u;
      }
      for (int i = tid * 4; i < BN * kw; i += 1024) {
        int c = i / kw, k = i - c * kw;
        ushort4 u = *reinterpret_cast<const ushort4*>(
            Wt + (size_t)(colb + c) * K + kb + k);
        *reinterpret_cast<ushort4*>(&sBt[c][k]) = u;
      }
      __syncthreads();
      for (int k0 = lk; k0 < kw; k0 += 32) {
        s16x8 a0 = *reinterpret_cast<const s16x8*>(&sA[wr + lr][k0]);
        s16x8 a1 = *reinterpret_cast<const s16x8*>(&sA[wr + lr + 16][k0]);
        #pragma unroll
        for (int j = 0; j < CF; ++j) {
          s16x8 bj = *reinterpret_cast<const s16x8*>(&sBt[wc + lr + 16 * j][k0]);
          acc[0][j] = __builtin_amdgcn_mfma_f32_16x16x32_bf16(a0, bj, acc[0][j], 0, 0, 0);
          acc[1][j] = __builtin_amdgcn_mfma_f32_16x16x32_bf16(a1, bj, acc[1][j], 0, 0, 0);
        }
      }
      __syncthreads();
    }
  }

  // epilogue: D col = lane&15, row = 4*(lane>>4)+reg  [m89/m91]
  const int rbase = (lane >> 4) << 2;
  #pragma unroll
  for (int i = 0; i < 2; ++i) {
    int grow = row0 + wr + 16 * i + rbase;
    #pragma unroll
    for (int j = 0; j < CF; ++j) {
      int col = colb + wc + 16 * j + lr;
      float bv = bias ? bias[col] : 0.f;
      #pragma unroll
      for (int r = 0; r < 4; ++r) {
        if (grow + r >= Nrows) continue;
        float v = acc[i][j][r] + bv;
        if (Cadd) v += Cadd[(size_t)(grow + r) * ldC + col];
        if (relu) v = fmaxf(v, 0.f);
        if (obf16)
          ((unsigned short*)Cout)[(size_t)(grow + r) * ldC + col] = f2bf(v);
        else
          ((float*)Cout)[(size_t)(grow + r) * ldC + col] = v;
      }
    }
  }
}

// ---- per-column sum/sumsq partials: grid MUST be 256 blocks (fixed slots) --
template <int BF>
__global__ void k_stats(const void* __restrict__ Xv, float* __restrict__ part,
                        int Nrows, int K) {
  int c = threadIdx.x & (K - 1);
  int rl = threadIdx.x / K;
  int rpb = 256 / K;
  float s = 0.f, s2 = 0.f;
  for (long r = (long)blockIdx.x * rpb + rl; r < Nrows; r += (long)gridDim.x * rpb) {
    float v = BF ? bf2f(((const unsigned short*)Xv)[r * K + c])
                 : ((const float*)Xv)[r * K + c];
    s += v;
    s2 = fmaf(v, v, s2);
  }
  __shared__ float b1s[256], b2s[256];
  b1s[threadIdx.x] = s; b2s[threadIdx.x] = s2;
  __syncthreads();
  if (rl == 0) {
    for (int t = 1; t < rpb; ++t) { s += b1s[t * K + c]; s2 += b2s[t * K + c]; }
    part[(size_t)blockIdx.x * 128 + c] = s;
    part[32768 + (size_t)blockIdx.x * 128 + c] = s2;
  }
}

// ---- fixed-order reduction of partials -> stats (deterministic) ------------
__global__ void k_statred(const float* __restrict__ part, float* __restrict__ st,
                          int K) {
  int c = threadIdx.x;
  if (c >= K) return;
  float s = 0.f, s2 = 0.f;
  for (int b = 0; b < 256; ++b) {
    s += part[(size_t)b * 128 + c];
    s2 += part[32768 + (size_t)b * 128 + c];
  }
  st[c] = s;
  st[128 + c] = s2;
}

// ---- BN+ReLU, bf16 in-place ------------------------------------------------
__global__ void k_bnb(unsigned short* __restrict__ X, const float* __restrict__ stats,
                      const float* __restrict__ g, const float* __restrict__ b,
                      int Nrows, int K) {
  long i = (long)blockIdx.x * blockDim.x + threadIdx.x;
  if (i >= (long)Nrows * K) return;
  int c = (int)(i & (K - 1));
  float invN = 1.0f / (float)Nrows;
  float m = stats[c] * invN;
  float v = stats[128 + c] * invN - m * m;
  float y = g[c] * (bf2f(X[i]) - m) * rsqrtf(v + 1e-5f) + b[c];
  X[i] = f2bf(fmaxf(y, 0.f));
}

// ---- BN+ReLU fp32 in -> bf16 out (+ optional bf16 residual after relu) -----
__global__ void k_bnf(const float* __restrict__ X, const float* __restrict__ stats,
                      const float* __restrict__ g, const float* __restrict__ b,
                      const unsigned short* __restrict__ addAfter,
                      unsigned short* __restrict__ outb, int Nrows, int K) {
  long i = (long)blockIdx.x * blockDim.x + threadIdx.x;
  if (i >= (long)Nrows * K) return;
  int c = (int)(i & (K - 1));
  float invN = 1.0f / (float)Nrows;
  float m = stats[c] * invN;
  float v = stats[128 + c] * invN - m * m;
  float y = g[c] * (X[i] - m) * rsqrtf(v + 1e-5f) + b[c];
  y = fmaxf(y, 0.f);
  if (addAfter) y += bf2f(addAfter[i]);
  outb[i] = f2bf(y);
}

// ---- fold attention vectors -------------------------------------------------
__global__ void k_foldatt(const float* __restrict__ Wg, const float* __restrict__ atts,
                          const float* __restrict__ attd, float* __restrict__ attw) {
  int t = blockIdx.x * blockDim.x + threadIdx.x;
  if (t >= 1024) return;
  int k = t >> 3, j = t & 7, h = j & 3;
  const float* av = (j < 4 ? atts : attd) + h * 128;
  const float* wg = Wg + (size_t)k * 512 + h * 128;
  float s = 0.f;
  for (int c = 0; c < 128; ++c) s = fmaf(wg[c], av[c], s);
  attw[t] = s;
}

// ---- a_s/a_d per node from bf16 h1, one wave each, grid-stride --------------
__global__ void k_attdots(const unsigned short* __restrict__ h1bf,
                          const float* __restrict__ attw,
                          float* __restrict__ asad, int Nrows) {
  int lane = threadIdx.x & 63;
  float c0[8], c1[8];
  #pragma unroll
  for (int j = 0; j < 8; ++j) {
    c0[j] = attw[(2 * lane) * 8 + j];
    c1[j] = attw[(2 * lane + 1) * 8 + j];
  }
  long wid = ((long)blockIdx.x * blockDim.x + threadIdx.x) >> 6;
  long nw = ((long)gridDim.x * blockDim.x) >> 6;
  for (long n = wid; n < Nrows; n += nw) {
    ushort2 u = *reinterpret_cast<const ushort2*>(h1bf + (n << 7) + (lane << 1));
    float vx = bf2f(u.x), vy = bf2f(u.y);
    float a[8];
    #pragma unroll
    for (int j = 0; j < 8; ++j) a[j] = vx * c0[j] + vy * c1[j];
    #pragma unroll
    for (int off = 1; off < 64; off <<= 1) {
      #pragma unroll
      for (int j = 0; j < 8; ++j) a[j] += __shfl_xor(a[j], off);
    }
    if (lane == 0) {
      *reinterpret_cast<float4*>(asad + n * 8)     = make_float4(a[0], a[1], a[2], a[3]);
      *reinterpret_cast<float4*>(asad + n * 8 + 4) = make_float4(a[4], a[5], a[6], a[7]);
    }
  }
}

// ---- final: logits = z2 @ Wc3 + bc3; log_softmax ----------------------------
__global__ void k_final(const float* __restrict__ z2, const float* __restrict__ W,
                        const float* __restrict__ b, float* __restrict__ out, int Nrows) {
  int n = blockIdx.x * blockDim.x + threadIdx.x;
  if (n >= Nrows) return;
  float l0 = b[0], l1 = b[1];
  const float* z = z2 + (size_t)n * 32;
  #pragma unroll
  for (int k = 0; k < 32; ++k) {
    float v = z[k];
    l0 = fmaf(v, W[2 * k], l0);
    l1 = fmaf(v, W[2 * k + 1], l1);
  }
  float m = fmaxf(l0, l1);
  float lse = m + logf(expf(l0 - m) + expf(l1 - m));
  out[2 * n] = l0 - lse;
  out[2 * n + 1] = l1 - lse;
}

// ---------------------------------------------------------------------------
extern "C" void kernel_launch(void* const* d_in, const int* in_sizes, int n_in,
                              void* d_out, int out_size, void* d_ws, size_t ws_size,
                              hipStream_t stream) {
  const float* x    = (const float*)d_in[0];
  const int*   ei   = (const int*)  d_in[1];
  const float* Wl1  = (const float*)d_in[2];
  const float* Wr1  = (const float*)d_in[3];
  const float* b1   = (const float*)d_in[4];
  const float* g1   = (const float*)d_in[5];
  const float* be1  = (const float*)d_in[6];
  const float* Wg   = (const float*)d_in[7];
  const float* atts = (const float*)d_in[8];
  const float* attd = (const float*)d_in[9];
  // d_in[10] = bg: constant column offset, cancels exactly in the following BN.
  const float* g2   = (const float*)d_in[11];
  const float* be2  = (const float*)d_in[12];
  const float* Wl3  = (const float*)d_in[13];
  const float* Wr3  = (const float*)d_in[14];
  const float* b3   = (const float*)d_in[15];
  const float* g3   = (const float*)d_in[16];
  const float* be3  = (const float*)d_in[17];
  const float* Wsk  = (const float*)d_in[18];
  const float* bsk  = (const float*)d_in[19];
  const float* Wc1  = (const float*)d_in[20];
  const float* bc1  = (const float*)d_in[21];
  const float* gc   = (const float*)d_in[22];
  const float* bec  = (const float*)d_in[23];
  const float* Wc2  = (const float*)d_in[24];
  const float* bc2  = (const float*)d_in[25];
  const float* Wc3  = (const float*)d_in[26];
  const float* bc3  = (const float*)d_in[27];
  (void)n_in; (void)out_size; (void)ws_size;

  const int N = in_sizes[0] / 128;
  const int E = in_sizes[1] / 2;
  const int* src = ei;
  const int* dst = ei + E;

  // ---- workspace carve-out (fp32 words) -------------------------------------
  auto al4 = [](size_t w) { return (w + 3) & ~(size_t)3; };
  float* ws = (float*)d_ws;
  size_t o = 0;
  int* cnt      = (int*)(ws + o); o += al4((size_t)N);
  int* indptr   = (int*)(ws + o); o += al4((size_t)N + 1);
  int* cursor   = (int*)(ws + o); o += al4((size_t)N);
  int* csr_src  = (int*)(ws + o); o += al4((size_t)E);
  int* bsum     = (int*)(ws + o); o += 1024;
  unsigned short* idbf = (unsigned short*)(ws + o); o += al4((size_t)N * 32);  // [N,64] bf16
  float* stats  = ws + o; o += 1024;
  float* spart  = ws + o; o += 65536;               // 256 blocks x 128 cols x {s,s2}
  float* attw   = ws + o; o += 1024;
  float* asad   = ws + o; o += al4((size_t)N * 8);
  float* alpha  = ws + o; o += al4((size_t)E * 4);
  unsigned short* wt = (unsigned short*)(ws + o); o += 64512 + 64;  // packed weights
  float* bufA   = ws + o; o += (size_t)N * 128;   // xbf|mean1bf -> h2bf|h3bf -> z1
  float* hb1    = ws + o; o += (size_t)N * 64;    // h1bf [N,128] bf16
  float* hB     = ws + o; o += (size_t)N * 128;   // h3 fp32 [N,64] + z2 [N,32]
  unsigned short* agg = (unsigned short*)(ws + o); o += (size_t)N * 256;  // [N,512] bf16

  // region aliases
  unsigned short* xbf     = (unsigned short*)bufA;                    // [N,128] bf16
  unsigned short* mean1bf = (unsigned short*)(bufA + (size_t)N * 64); // [N,128] bf16
  unsigned short* h1bf    = (unsigned short*)hb1;                     // [N,128] bf16
  unsigned short* h2bf    = (unsigned short*)bufA;                    // [N,128] bf16 (over xbf)
  unsigned short* h3bf    = (unsigned short*)(bufA + (size_t)N * 64); // [N,64] bf16
  unsigned short* yl3     = agg;                                      // [N,64] bf16
  float* mean3f           = (float*)agg + (size_t)N * 32;             // [N,64] fp32 (after yl3)
  unsigned short* z1bf    = agg;                                      // [N,64] bf16 (after SAGE3)
  float* h3 = hB;                                                     // [N,64] fp32
  float* z1 = bufA;                                                   // [N,64] fp32 (over h2bf)
  float* z2 = hB + (size_t)N * 64;                                    // [N,32] fp32

  // packed-weight offsets (ushort units)
  unsigned short* WtSk = wt;                 // 64c x128k
  unsigned short* WtL1 = WtSk + 8192;        // 128x128
  unsigned short* WtR1 = WtL1 + 16384;       // 128x128
  unsigned short* WtG2 = WtR1 + 16384;       // 128c x512k (concat heads)
  unsigned short* WtL3 = WtG2 + 65536;       // 64c x128k
  unsigned short* WtR3 = WtL3 + 8192;        // 64c x128k
  unsigned short* WtC1 = WtR3 + 8192;        // 64c x64k
  unsigned short* WtC2 = WtC1 + 4096;        // 32c x64k

  float* st1 = stats, *st2 = stats + 256, *st3 = stats + 512, *st4 = stats + 768;

  dim3 blk(256);
  int gE     = (E + 255) / 256;
  int gN64   = (N + 63) / 64;
  int gSC    = (N + 1023) / 1024;
  int gW     = (int)(((long)N * 64 + 255) / 256);
  int gA     = (int)(((long)N * 8 + 255) / 256);
  int gC     = (int)(((long)N * 32 + 255) / 256);
  int gBN128 = (int)(((long)N * 128 + 255) / 256);
  int gBN64  = (int)(((long)N * 64 + 255) / 256);

  hipMemsetAsync(cnt, 0, (size_t)N * 4, stream);

  // ---- CSR build + packing + cast ----
  k_hist<<<gE, blk, 0, stream>>>(dst, cnt, E);
  k_scan1<<<gSC, blk, 0, stream>>>(cnt, bsum, N);
  k_scan2<<<1, 1024, 0, stream>>>(bsum, gSC);
  k_scan3<<<gSC, blk, 0, stream>>>(cnt, bsum, indptr, cursor, N);
  k_fill<<<gE, blk, 0, stream>>>(src, dst, cursor, csr_src, E);
  k_cast<<<gC, blk, 0, stream>>>(x, xbf, (long)N * 32);
  k_packall<<<504, blk, 0, stream>>>(Wsk, Wl1, Wr1, Wg, Wl3, Wr3, Wc1, Wc2, wt);

  // ---- SAGE1 ----
  k_gmean<128, 1><<<gW, blk, 0, stream>>>(xbf, indptr, csr_src, mean1bf, N);
  k_mgemm<2><<<dim3(gN64, 1), blk, 0, stream>>>(
      xbf, 1, 128, 128, WtSk, nullptr, 0, 0, 0, nullptr,
      bsk, nullptr, idbf, 1, N, 64, 0);
  k_mgemm<4><<<dim3(gN64, 1), blk, 0, stream>>>(
      mean1bf, 1, 128, 128, WtL1, xbf, 1, 128, 128, WtR1,
      b1, nullptr, h1bf, 1, N, 128, 0);
  k_stats<1><<<256, blk, 0, stream>>>(h1bf, spart, N, 128);
  k_statred<<<1, 128, 0, stream>>>(spart, st1, 128);
  k_bnb<<<gBN128, blk, 0, stream>>>(h1bf, st1, g1, be1, N, 128);

  // ---- GAT (aggregate in h1-space, then one K=512 GEMM) ----
  k_foldatt<<<4, blk, 0, stream>>>(Wg, atts, attd, attw);
  k_attdots<<<2048, blk, 0, stream>>>(h1bf, attw, asad, N);
  k_alpha<<<gA, blk, 0, stream>>>(indptr, csr_src, asad, alpha, N);
  k_gath1<<<gW, blk, 0, stream>>>(h1bf, indptr, csr_src, alpha, agg, N);
  k_mgemm<4><<<dim3(gN64, 1), blk, 0, stream>>>(
      agg, 1, 512, 512, WtG2, nullptr, 0, 0, 0, nullptr,
      nullptr, nullptr, h2bf, 1, N, 128, 0);
  k_stats<1><<<256, blk, 0, stream>>>(h2bf, spart, N, 128);
  k_statred<<<1, 128, 0, stream>>>(spart, st2, 128);
  k_bnb<<<gBN128, blk, 0, stream>>>(h2bf, st2, g2, be2, N, 128);

  // ---- SAGE3 (project-first: gather 64-wide; mean3 kept fp32) ----
  k_mgemm<2><<<dim3(gN64, 1), blk, 0, stream>>>(
      h2bf, 1, 128, 128, WtL3, nullptr, 0, 0, 0, nullptr,
      nullptr, nullptr, yl3, 1, N, 64, 0);
  k_gmean<64, 0><<<gW, blk, 0, stream>>>(yl3, indptr, csr_src, mean3f, N);
  k_mgemm<2><<<dim3(gN64, 1), blk, 0, stream>>>(
      h2bf, 1, 128, 128, WtR3, nullptr, 0, 0, 0, nullptr,
      b3, mean3f, h3, 0, N, 64, 0);
  k_stats<0><<<256, blk, 0, stream>>>(h3, spart, N, 64);
  k_statred<<<1, 128, 0, stream>>>(spart, st3, 64);
  k_bnf<<<gBN64, blk, 0, stream>>>(h3, st3, g3, be3, idbf, h3bf, N, 64);  // +identity

  // ---- classifier ----
  k_mgemm<2><<<dim3(gN64, 1), blk, 0, stream>>>(
      h3bf, 1, 64, 64, WtC1, nullptr, 0, 0, 0, nullptr,
      bc1, nullptr, z1, 0, N, 64, 0);
  k_stats<0><<<256, blk, 0, stream>>>(z1, spart, N, 64);
  k_statred<<<1, 128, 0, stream>>>(spart, st4, 64);
  k_bnf<<<gBN64, blk, 0, stream>>>(z1, st4, gc, bec, nullptr, z1bf, N, 64);
  k_mgemm<1><<<dim3(gN64, 1), blk, 0, stream>>>(
      z1bf, 1, 64, 64, WtC2, nullptr, 0, 0, 0, nullptr,
      bc2, nullptr, z2, 0, N, 32, 1);
  k_final<<<(N + 255) / 256, blk, 0, stream>>>(z2, Wc3, bc3, (float*)d_out, N);
}

// Round 11
// 904.146 us; speedup vs baseline: 5.1127x; 1.0342x over previous
//
#include <hip/hip_runtime.h>
#include <hip/hip_bf16.h>
#include <cmath>

// ---------------------------------------------------------------------------
// MuleHunterGNN: SAGE -> GAT -> SAGE -> skip -> MLP classifier
// CSR-gather; GAT aggregation in h1-space (alpha-weighted gather + one K=512
// MFMA GEMM). Round 11: k_mgemm staging uses shift/mask (kw is always a
// power of two) -- the runtime integer division was 31% VALUBusy.
// Replay-deterministic: BN stats fixed-order reduction, mean3 Cadd fp32.
// ---------------------------------------------------------------------------

typedef short s16x8 __attribute__((ext_vector_type(8)));
typedef float f32x4 __attribute__((ext_vector_type(4)));

__device__ __forceinline__ float bf2f(unsigned short u) {
  return __uint_as_float((unsigned)u << 16);
}
__device__ __forceinline__ unsigned short f2bf(float f) {
  __hip_bfloat16 h = __float2bfloat16(f);
  return *reinterpret_cast<unsigned short*>(&h);
}

// ---- CSR build -----------------------------------------------------------
__global__ void k_hist(const int* __restrict__ dst, int* __restrict__ cnt, int E) {
  int e = blockIdx.x * blockDim.x + threadIdx.x;
  if (e < E) atomicAdd(&cnt[dst[e]], 1);
}

__global__ __launch_bounds__(256) void k_scan1(const int* __restrict__ cnt,
                                               int* __restrict__ bsum, int N) {
  int base = blockIdx.x << 10;
  int t = threadIdx.x;
  int s = 0;
  #pragma unroll
  for (int j = 0; j < 4; ++j) {
    int i = base + t * 4 + j;
    if (i < N) s += cnt[i];
  }
  __shared__ int red[256];
  red[t] = s;
  __syncthreads();
  for (int off = 128; off; off >>= 1) {
    if (t < off) red[t] += red[t + off];
    __syncthreads();
  }
  if (t == 0) bsum[blockIdx.x] = red[0];
}

__global__ __launch_bounds__(1024) void k_scan2(int* __restrict__ bsum, int nb) {
  __shared__ int sh[1024];
  int t = threadIdx.x;
  int v = (t < nb) ? bsum[t] : 0;
  sh[t] = v;
  __syncthreads();
  for (int off = 1; off < 1024; off <<= 1) {
    int u = (t >= off) ? sh[t - off] : 0;
    __syncthreads();
    sh[t] += u;
    __syncthreads();
  }
  if (t < nb) bsum[t] = sh[t] - v;  // exclusive prefix
}

__global__ __launch_bounds__(256) void k_scan3(const int* __restrict__ cnt,
                                               const int* __restrict__ bsum,
                                               int* __restrict__ indptr,
                                               int* __restrict__ cursor, int N) {
  int base = blockIdx.x << 10;
  int t = threadIdx.x;
  int lane = t & 63, w = t >> 6;
  int i0 = base + t * 4;
  int v[4], s = 0;
  #pragma unroll
  for (int j = 0; j < 4; ++j) {
    int i = i0 + j;
    v[j] = (i < N) ? cnt[i] : 0;
    s += v[j];
  }
  int incl = s;
  #pragma unroll
  for (int off = 1; off < 64; off <<= 1) {
    int u = __shfl_up(incl, off);
    if (lane >= off) incl += u;
  }
  __shared__ int wsum[4];
  if (lane == 63) wsum[w] = incl;
  __syncthreads();
  int add = 0;
  for (int j = 0; j < w; ++j) add += wsum[j];
  int run = incl - s + add + bsum[blockIdx.x];
  #pragma unroll
  for (int j = 0; j < 4; ++j) {
    int i = i0 + j;
    if (i < N) {
      cursor[i] = run;
      run += v[j];
      indptr[i + 1] = run;
    }
  }
  if (blockIdx.x == 0 && t == 0) indptr[0] = 0;
}

__global__ void k_fill(const int* __restrict__ src, const int* __restrict__ dst,
                       int* __restrict__ cursor, int* __restrict__ csr_src, int E) {
  int e = blockIdx.x * blockDim.x + threadIdx.x;
  if (e >= E) return;
  int pos = atomicAdd(&cursor[dst[e]], 1);
  csr_src[pos] = src[e];
}

// ---- fp32 -> bf16 cast ----------------------------------------------------
__global__ void k_cast(const float* __restrict__ in, unsigned short* __restrict__ out,
                       long n4) {
  long t = (long)blockIdx.x * blockDim.x + threadIdx.x;
  if (t >= n4) return;
  float4 v = *reinterpret_cast<const float4*>(in + t * 4);
  ushort4 u;
  u.x = f2bf(v.x); u.y = f2bf(v.y); u.z = f2bf(v.z); u.w = f2bf(v.w);
  *reinterpret_cast<ushort4*>(out + t * 4) = u;
}

// ---- all weight packs in one launch (129024 ushorts total) -----------------
__global__ void k_packall(const float* __restrict__ Wsk, const float* __restrict__ Wl1,
                          const float* __restrict__ Wr1, const float* __restrict__ Wg,
                          const float* __restrict__ Wl3, const float* __restrict__ Wr3,
                          const float* __restrict__ Wc1, const float* __restrict__ Wc2,
                          unsigned short* __restrict__ wt) {
  int t = blockIdx.x * blockDim.x + threadIdx.x;
  if (t >= 129024) return;
  float v;
  if (t < 8192) {                 // WtSk [64c][128k]
    int c = t >> 7, k = t & 127;
    v = Wsk[k * 64 + c];
  } else if (t < 24576) {         // WtL1 [128c][128k]
    int r = t - 8192; int c = r >> 7, k = r & 127;
    v = Wl1[k * 128 + c];
  } else if (t < 40960) {         // WtR1 [128c][128k]
    int r = t - 24576; int c = r >> 7, k = r & 127;
    v = Wr1[k * 128 + c];
  } else if (t < 106496) {        // WtG2 [128c][512k], kg=h*128+k <- Wg[k][h*128+c]
    int r = t - 40960; int c = r >> 9; int q = r & 511; int h = q >> 7, k = q & 127;
    v = Wg[k * 512 + h * 128 + c];
  } else if (t < 114688) {        // WtL3 [64c][128k]
    int r = t - 106496; int c = r >> 7, k = r & 127;
    v = Wl3[k * 64 + c];
  } else if (t < 122880) {        // WtR3 [64c][128k]
    int r = t - 114688; int c = r >> 7, k = r & 127;
    v = Wr3[k * 64 + c];
  } else if (t < 126976) {        // WtC1 [64c][64k]
    int r = t - 122880; int c = r >> 6, k = r & 63;
    v = Wc1[k * 64 + c];
  } else {                        // WtC2 [32c][64k]
    int r = t - 126976; int c = r >> 6, k = r & 63;
    v = Wc2[k * 32 + c];
  }
  wt[t] = f2bf(v);
}

// ---- gather mean of bf16 rows (W=128/64), bf16 or fp32 out -----------------
template <int W, int OBF>
__global__ __launch_bounds__(256) void k_gmean(const unsigned short* __restrict__ X,
                                               const int* __restrict__ indptr,
                                               const int* __restrict__ csr,
                                               void* __restrict__ out, int N) {
  long wid = ((long)blockIdx.x * blockDim.x + threadIdx.x) >> 6;
  if (wid >= N) return;
  int lane = threadIdx.x & 63;
  int b = indptr[wid], en = indptr[wid + 1];
  if (W == 128) {
    float ax = 0.f, ay = 0.f;
    for (int i = b; i < en; ++i) {
      int s = csr[i];
      ushort2 u = *reinterpret_cast<const ushort2*>(X + ((size_t)s << 7) + (lane << 1));
      ax += bf2f(u.x); ay += bf2f(u.y);
    }
    float inv = 1.0f / (float)max(en - b, 1);
    ax *= inv; ay *= inv;
    if (OBF) {
      ushort2 o; o.x = f2bf(ax); o.y = f2bf(ay);
      *reinterpret_cast<ushort2*>((unsigned short*)out + (wid << 7) + (lane << 1)) = o;
    } else {
      *reinterpret_cast<float2*>((float*)out + (wid << 7) + (lane << 1)) =
          make_float2(ax, ay);
    }
  } else {
    float a = 0.f;
    for (int i = b; i < en; ++i) {
      int s = csr[i];
      a += bf2f(X[((size_t)s << 6) + lane]);
    }
    float inv = 1.0f / (float)max(en - b, 1);
    a *= inv;
    if (OBF) ((unsigned short*)out)[(wid << 6) + lane] = f2bf(a);
    else     ((float*)out)[(wid << 6) + lane] = a;
  }
}

// ---- GAT alpha: per-dst segment softmax, 8 lanes per dst ------------------
__global__ __launch_bounds__(256) void k_alpha(const int* __restrict__ indptr,
                                               const int* __restrict__ csr,
                                               const float* __restrict__ asad,
                                               float* __restrict__ alpha, int N) {
  long g = ((long)blockIdx.x * blockDim.x + threadIdx.x) >> 3;
  if (g >= N) return;
  int l8 = threadIdx.x & 7;
  int b = indptr[g], en = indptr[g + 1];
  float4 adv = *reinterpret_cast<const float4*>(asad + g * 8 + 4);
  float m[4] = {-INFINITY, -INFINITY, -INFINITY, -INFINITY};
  for (int i = b + l8; i < en; i += 8) {
    int s = csr[i];
    float4 a = *reinterpret_cast<const float4*>(asad + (size_t)s * 8);
    float e0 = a.x + adv.x, e1 = a.y + adv.y, e2 = a.z + adv.z, e3 = a.w + adv.w;
    e0 = e0 >= 0.f ? e0 : 0.2f * e0; e1 = e1 >= 0.f ? e1 : 0.2f * e1;
    e2 = e2 >= 0.f ? e2 : 0.2f * e2; e3 = e3 >= 0.f ? e3 : 0.2f * e3;
    m[0] = fmaxf(m[0], e0); m[1] = fmaxf(m[1], e1);
    m[2] = fmaxf(m[2], e2); m[3] = fmaxf(m[3], e3);
  }
  #pragma unroll
  for (int off = 1; off < 8; off <<= 1) {
    #pragma unroll
    for (int h = 0; h < 4; ++h) m[h] = fmaxf(m[h], __shfl_xor(m[h], off));
  }
  float den[4] = {0.f, 0.f, 0.f, 0.f};
  for (int i = b + l8; i < en; i += 8) {
    int s = csr[i];
    float4 a = *reinterpret_cast<const float4*>(asad + (size_t)s * 8);
    float e0 = a.x + adv.x, e1 = a.y + adv.y, e2 = a.z + adv.z, e3 = a.w + adv.w;
    e0 = e0 >= 0.f ? e0 : 0.2f * e0; e1 = e1 >= 0.f ? e1 : 0.2f * e1;
    e2 = e2 >= 0.f ? e2 : 0.2f * e2; e3 = e3 >= 0.f ? e3 : 0.2f * e3;
    float4 w;
    w.x = __expf(e0 - m[0]); w.y = __expf(e1 - m[1]);
    w.z = __expf(e2 - m[2]); w.w = __expf(e3 - m[3]);
    den[0] += w.x; den[1] += w.y; den[2] += w.z; den[3] += w.w;
    *reinterpret_cast<float4*>(alpha + (size_t)i * 4) = w;
  }
  #pragma unroll
  for (int off = 1; off < 8; off <<= 1) {
    #pragma unroll
    for (int h = 0; h < 4; ++h) den[h] += __shfl_xor(den[h], off);
  }
  float s0 = 0.25f / fmaxf(den[0], 1e-16f);
  float s1 = 0.25f / fmaxf(den[1], 1e-16f);
  float s2 = 0.25f / fmaxf(den[2], 1e-16f);
  float s3 = 0.25f / fmaxf(den[3], 1e-16f);
  for (int i = b + l8; i < en; i += 8) {
    float4 w = *reinterpret_cast<const float4*>(alpha + (size_t)i * 4);
    w.x *= s0; w.y *= s1; w.z *= s2; w.w *= s3;
    *reinterpret_cast<float4*>(alpha + (size_t)i * 4) = w;
  }
}

// ---- GAT gather in h1-space: agg[d, h*128+:] = sum_e alpha[e][h]*h1[src_e] --
__global__ __launch_bounds__(256) void k_gath1(
    const unsigned short* __restrict__ h1, const int* __restrict__ indptr,
    const int* __restrict__ csr, const float* __restrict__ alpha,
    unsigned short* __restrict__ agg, int N) {
  long wid = ((long)blockIdx.x * blockDim.x + threadIdx.x) >> 6;
  if (wid >= N) return;
  int lane = threadIdx.x & 63;
  int b = indptr[wid], en = indptr[wid + 1];
  float a0x = 0.f, a0y = 0.f, a1x = 0.f, a1y = 0.f;
  float a2x = 0.f, a2y = 0.f, a3x = 0.f, a3y = 0.f;
  for (int i = b; i < en; ++i) {
    int s = csr[i];
    float4 a = *reinterpret_cast<const float4*>(alpha + (size_t)i * 4);
    ushort2 u = *reinterpret_cast<const ushort2*>(h1 + ((size_t)s << 7) + (lane << 1));
    float vx = bf2f(u.x), vy = bf2f(u.y);
    a0x = fmaf(a.x, vx, a0x); a0y = fmaf(a.x, vy, a0y);
    a1x = fmaf(a.y, vx, a1x); a1y = fmaf(a.y, vy, a1y);
    a2x = fmaf(a.z, vx, a2x); a2y = fmaf(a.z, vy, a2y);
    a3x = fmaf(a.w, vx, a3x); a3y = fmaf(a.w, vy, a3y);
  }
  unsigned short* po = agg + ((size_t)wid << 9) + (lane << 1);
  ushort2 o;
  o.x = f2bf(a0x); o.y = f2bf(a0y); *reinterpret_cast<ushort2*>(po)       = o;
  o.x = f2bf(a1x); o.y = f2bf(a1y); *reinterpret_cast<ushort2*>(po + 128) = o;
  o.x = f2bf(a2x); o.y = f2bf(a2y); *reinterpret_cast<ushort2*>(po + 256) = o;
  o.x = f2bf(a3x); o.y = f2bf(a3y); *reinterpret_cast<ushort2*>(po + 384) = o;
}

// ---- MFMA GEMM: C = A1@W1 [+ A2@W2] + bias [+ Cadd(fp32)] ------------------
// A bf16/fp32 [N,ldA], Wt bf16 [cols][K]; K in {64,128,512} (kw = min(K,128)
// is a power of two -> shift/mask staging, no integer division).
template <int CF>
__global__ __launch_bounds__(256) void k_mgemm(
    const void* __restrict__ A1, int a1bf, int ldA1, int K1,
    const unsigned short* __restrict__ Wt1,
    const void* __restrict__ A2, int a2bf, int ldA2, int K2,
    const unsigned short* __restrict__ Wt2,
    const float* __restrict__ bias, const float* __restrict__ Cadd,
    void* __restrict__ Cout, int obf16,
    int Nrows, int ldC, int relu) {
  constexpr int BN = CF * 32;
  __shared__ alignas(16) unsigned short sA[64][136];
  __shared__ alignas(16) unsigned short sBt[128][136];
  const int tid = threadIdx.x;
  const int lane = tid & 63;
  const int w = tid >> 6;
  const int wr = (w >> 1) * 32;
  const int wc = (w & 1) * (CF * 16);
  const int lr = lane & 15;
  const int lk = (lane >> 4) << 3;
  const int row0 = blockIdx.x * 64;
  const int colb = blockIdx.y * BN;

  f32x4 acc[2][CF];
  #pragma unroll
  for (int i = 0; i < 2; ++i)
    #pragma unroll
    for (int j = 0; j < CF; ++j) acc[i][j] = (f32x4){0.f, 0.f, 0.f, 0.f};

  for (int pass = 0; pass < 2; ++pass) {
    const void* A = pass ? A2 : A1;
    if (!A) break;
    const int abf = pass ? a2bf : a1bf;
    const int ldA = pass ? ldA2 : ldA1;
    const int K = pass ? K2 : K1;
    const unsigned short* Wt = pass ? Wt2 : Wt1;
    const int kw = (K < 128) ? K : 128;          // 64 or 128 (power of two)
    const int ksh = (kw == 128) ? 7 : 6;
    // per-thread fixed column, strided row (1024 elems per sweep)
    const int kc = (tid << 2) & (kw - 1);
    const int r0 = (tid << 2) >> ksh;
    const int rstep = 1024 >> ksh;               // 8 or 16
    for (int kb = 0; kb < K; kb += kw) {
      for (int r = r0; r < 64; r += rstep) {
        int gr = row0 + r;
        ushort4 u = make_ushort4(0, 0, 0, 0);
        if (gr < Nrows) {
          if (abf) {
            u = *reinterpret_cast<const ushort4*>(
                (const unsigned short*)A + (size_t)gr * ldA + kb + kc);
          } else {
            float4 v = *reinterpret_cast<const float4*>(
                (const float*)A + (size_t)gr * ldA + kb + kc);
            u.x = f2bf(v.x); u.y = f2bf(v.y); u.z = f2bf(v.z); u.w = f2bf(v.w);
          }
        }
        *reinterpret_cast<ushort4*>(&sA[r][kc]) = u;
      }
      for (int c = r0; c < BN; c += rstep) {
        ushort4 u = *reinterpret_cast<const ushort4*>(
            Wt + (size_t)(colb + c) * K + kb + kc);
        *reinterpret_cast<ushort4*>(&sBt[c][kc]) = u;
      }
      __syncthreads();
      for (int k0 = lk; k0 < kw; k0 += 32) {
        s16x8 a0 = *reinterpret_cast<const s16x8*>(&sA[wr + lr][k0]);
        s16x8 a1 = *reinterpret_cast<const s16x8*>(&sA[wr + lr + 16][k0]);
        #pragma unroll
        for (int j = 0; j < CF; ++j) {
          s16x8 bj = *reinterpret_cast<const s16x8*>(&sBt[wc + lr + 16 * j][k0]);
          acc[0][j] = __builtin_amdgcn_mfma_f32_16x16x32_bf16(a0, bj, acc[0][j], 0, 0, 0);
          acc[1][j] = __builtin_amdgcn_mfma_f32_16x16x32_bf16(a1, bj, acc[1][j], 0, 0, 0);
        }
      }
      __syncthreads();
    }
  }

  // epilogue: D col = lane&15, row = 4*(lane>>4)+reg  [m89/m91]
  const int rbase = (lane >> 4) << 2;
  #pragma unroll
  for (int i = 0; i < 2; ++i) {
    int grow = row0 + wr + 16 * i + rbase;
    #pragma unroll
    for (int j = 0; j < CF; ++j) {
      int col = colb + wc + 16 * j + lr;
      float bv = bias ? bias[col] : 0.f;
      #pragma unroll
      for (int r = 0; r < 4; ++r) {
        if (grow + r >= Nrows) continue;
        float v = acc[i][j][r] + bv;
        if (Cadd) v += Cadd[(size_t)(grow + r) * ldC + col];
        if (relu) v = fmaxf(v, 0.f);
        if (obf16)
          ((unsigned short*)Cout)[(size_t)(grow + r) * ldC + col] = f2bf(v);
        else
          ((float*)Cout)[(size_t)(grow + r) * ldC + col] = v;
      }
    }
  }
}

// ---- per-column sum/sumsq partials: grid MUST be 256 blocks (fixed slots) --
template <int BF>
__global__ void k_stats(const void* __restrict__ Xv, float* __restrict__ part,
                        int Nrows, int K) {
  int c = threadIdx.x & (K - 1);
  int rl = threadIdx.x / K;
  int rpb = 256 / K;
  float s = 0.f, s2 = 0.f;
  for (long r = (long)blockIdx.x * rpb + rl; r < Nrows; r += (long)gridDim.x * rpb) {
    float v = BF ? bf2f(((const unsigned short*)Xv)[r * K + c])
                 : ((const float*)Xv)[r * K + c];
    s += v;
    s2 = fmaf(v, v, s2);
  }
  __shared__ float b1s[256], b2s[256];
  b1s[threadIdx.x] = s; b2s[threadIdx.x] = s2;
  __syncthreads();
  if (rl == 0) {
    for (int t = 1; t < rpb; ++t) { s += b1s[t * K + c]; s2 += b2s[t * K + c]; }
    part[(size_t)blockIdx.x * 128 + c] = s;
    part[32768 + (size_t)blockIdx.x * 128 + c] = s2;
  }
}

// ---- fixed-order reduction of partials -> stats (deterministic) ------------
__global__ void k_statred(const float* __restrict__ part, float* __restrict__ st,
                          int K) {
  int c = threadIdx.x;
  if (c >= K) return;
  float s = 0.f, s2 = 0.f;
  for (int b = 0; b < 256; ++b) {
    s += part[(size_t)b * 128 + c];
    s2 += part[32768 + (size_t)b * 128 + c];
  }
  st[c] = s;
  st[128 + c] = s2;
}

// ---- BN+ReLU, bf16 in-place ------------------------------------------------
__global__ void k_bnb(unsigned short* __restrict__ X, const float* __restrict__ stats,
                      const float* __restrict__ g, const float* __restrict__ b,
                      int Nrows, int K) {
  long i = (long)blockIdx.x * blockDim.x + threadIdx.x;
  if (i >= (long)Nrows * K) return;
  int c = (int)(i & (K - 1));
  float invN = 1.0f / (float)Nrows;
  float m = stats[c] * invN;
  float v = stats[128 + c] * invN - m * m;
  float y = g[c] * (bf2f(X[i]) - m) * rsqrtf(v + 1e-5f) + b[c];
  X[i] = f2bf(fmaxf(y, 0.f));
}

// ---- BN+ReLU fp32 in -> bf16 out (+ optional bf16 residual after relu) -----
__global__ void k_bnf(const float* __restrict__ X, const float* __restrict__ stats,
                      const float* __restrict__ g, const float* __restrict__ b,
                      const unsigned short* __restrict__ addAfter,
                      unsigned short* __restrict__ outb, int Nrows, int K) {
  long i = (long)blockIdx.x * blockDim.x + threadIdx.x;
  if (i >= (long)Nrows * K) return;
  int c = (int)(i & (K - 1));
  float invN = 1.0f / (float)Nrows;
  float m = stats[c] * invN;
  float v = stats[128 + c] * invN - m * m;
  float y = g[c] * (X[i] - m) * rsqrtf(v + 1e-5f) + b[c];
  y = fmaxf(y, 0.f);
  if (addAfter) y += bf2f(addAfter[i]);
  outb[i] = f2bf(y);
}

// ---- fold attention vectors -------------------------------------------------
__global__ void k_foldatt(const float* __restrict__ Wg, const float* __restrict__ atts,
                          const float* __restrict__ attd, float* __restrict__ attw) {
  int t = blockIdx.x * blockDim.x + threadIdx.x;
  if (t >= 1024) return;
  int k = t >> 3, j = t & 7, h = j & 3;
  const float* av = (j < 4 ? atts : attd) + h * 128;
  const float* wg = Wg + (size_t)k * 512 + h * 128;
  float s = 0.f;
  for (int c = 0; c < 128; ++c) s = fmaf(wg[c], av[c], s);
  attw[t] = s;
}

// ---- a_s/a_d per node from bf16 h1, one wave each, grid-stride --------------
__global__ void k_attdots(const unsigned short* __restrict__ h1bf,
                          const float* __restrict__ attw,
                          float* __restrict__ asad, int Nrows) {
  int lane = threadIdx.x & 63;
  float c0[8], c1[8];
  #pragma unroll
  for (int j = 0; j < 8; ++j) {
    c0[j] = attw[(2 * lane) * 8 + j];
    c1[j] = attw[(2 * lane + 1) * 8 + j];
  }
  long wid = ((long)blockIdx.x * blockDim.x + threadIdx.x) >> 6;
  long nw = ((long)gridDim.x * blockDim.x) >> 6;
  for (long n = wid; n < Nrows; n += nw) {
    ushort2 u = *reinterpret_cast<const ushort2*>(h1bf + (n << 7) + (lane << 1));
    float vx = bf2f(u.x), vy = bf2f(u.y);
    float a[8];
    #pragma unroll
    for (int j = 0; j < 8; ++j) a[j] = vx * c0[j] + vy * c1[j];
    #pragma unroll
    for (int off = 1; off < 64; off <<= 1) {
      #pragma unroll
      for (int j = 0; j < 8; ++j) a[j] += __shfl_xor(a[j], off);
    }
    if (lane == 0) {
      *reinterpret_cast<float4*>(asad + n * 8)     = make_float4(a[0], a[1], a[2], a[3]);
      *reinterpret_cast<float4*>(asad + n * 8 + 4) = make_float4(a[4], a[5], a[6], a[7]);
    }
  }
}

// ---- final: logits = z2 @ Wc3 + bc3; log_softmax ----------------------------
__global__ void k_final(const float* __restrict__ z2, const float* __restrict__ W,
                        const float* __restrict__ b, float* __restrict__ out, int Nrows) {
  int n = blockIdx.x * blockDim.x + threadIdx.x;
  if (n >= Nrows) return;
  float l0 = b[0], l1 = b[1];
  const float* z = z2 + (size_t)n * 32;
  #pragma unroll
  for (int k = 0; k < 32; ++k) {
    float v = z[k];
    l0 = fmaf(v, W[2 * k], l0);
    l1 = fmaf(v, W[2 * k + 1], l1);
  }
  float m = fmaxf(l0, l1);
  float lse = m + logf(expf(l0 - m) + expf(l1 - m));
  out[2 * n] = l0 - lse;
  out[2 * n + 1] = l1 - lse;
}

// ---------------------------------------------------------------------------
extern "C" void kernel_launch(void* const* d_in, const int* in_sizes, int n_in,
                              void* d_out, int out_size, void* d_ws, size_t ws_size,
                              hipStream_t stream) {
  const float* x    = (const float*)d_in[0];
  const int*   ei   = (const int*)  d_in[1];
  const float* Wl1  = (const float*)d_in[2];
  const float* Wr1  = (const float*)d_in[3];
  const float* b1   = (const float*)d_in[4];
  const float* g1   = (const float*)d_in[5];
  const float* be1  = (const float*)d_in[6];
  const float* Wg   = (const float*)d_in[7];
  const float* atts = (const float*)d_in[8];
  const float* attd = (const float*)d_in[9];
  // d_in[10] = bg: constant column offset, cancels exactly in the following BN.
  const float* g2   = (const float*)d_in[11];
  const float* be2  = (const float*)d_in[12];
  const float* Wl3  = (const float*)d_in[13];
  const float* Wr3  = (const float*)d_in[14];
  const float* b3   = (const float*)d_in[15];
  const float* g3   = (const float*)d_in[16];
  const float* be3  = (const float*)d_in[17];
  const float* Wsk  = (const float*)d_in[18];
  const float* bsk  = (const float*)d_in[19];
  const float* Wc1  = (const float*)d_in[20];
  const float* bc1  = (const float*)d_in[21];
  const float* gc   = (const float*)d_in[22];
  const float* bec  = (const float*)d_in[23];
  const float* Wc2  = (const float*)d_in[24];
  const float* bc2  = (const float*)d_in[25];
  const float* Wc3  = (const float*)d_in[26];
  const float* bc3  = (const float*)d_in[27];
  (void)n_in; (void)out_size; (void)ws_size;

  const int N = in_sizes[0] / 128;
  const int E = in_sizes[1] / 2;
  const int* src = ei;
  const int* dst = ei + E;

  // ---- workspace carve-out (fp32 words) -------------------------------------
  auto al4 = [](size_t w) { return (w + 3) & ~(size_t)3; };
  float* ws = (float*)d_ws;
  size_t o = 0;
  int* cnt      = (int*)(ws + o); o += al4((size_t)N);
  int* indptr   = (int*)(ws + o); o += al4((size_t)N + 1);
  int* cursor   = (int*)(ws + o); o += al4((size_t)N);
  int* csr_src  = (int*)(ws + o); o += al4((size_t)E);
  int* bsum     = (int*)(ws + o); o += 1024;
  unsigned short* idbf = (unsigned short*)(ws + o); o += al4((size_t)N * 32);  // [N,64] bf16
  float* stats  = ws + o; o += 1024;
  float* spart  = ws + o; o += 65536;               // 256 blocks x 128 cols x {s,s2}
  float* attw   = ws + o; o += 1024;
  float* asad   = ws + o; o += al4((size_t)N * 8);
  float* alpha  = ws + o; o += al4((size_t)E * 4);
  unsigned short* wt = (unsigned short*)(ws + o); o += 64512 + 64;  // packed weights
  float* bufA   = ws + o; o += (size_t)N * 128;   // xbf|mean1bf -> h2bf|h3bf -> z1
  float* hb1    = ws + o; o += (size_t)N * 64;    // h1bf [N,128] bf16
  float* hB     = ws + o; o += (size_t)N * 128;   // h3 fp32 [N,64] + z2 [N,32]
  unsigned short* agg = (unsigned short*)(ws + o); o += (size_t)N * 256;  // [N,512] bf16

  // region aliases
  unsigned short* xbf     = (unsigned short*)bufA;                    // [N,128] bf16
  unsigned short* mean1bf = (unsigned short*)(bufA + (size_t)N * 64); // [N,128] bf16
  unsigned short* h1bf    = (unsigned short*)hb1;                     // [N,128] bf16
  unsigned short* h2bf    = (unsigned short*)bufA;                    // [N,128] bf16 (over xbf)
  unsigned short* h3bf    = (unsigned short*)(bufA + (size_t)N * 64); // [N,64] bf16
  unsigned short* yl3     = agg;                                      // [N,64] bf16
  float* mean3f           = (float*)agg + (size_t)N * 32;             // [N,64] fp32 (after yl3)
  unsigned short* z1bf    = agg;                                      // [N,64] bf16 (after SAGE3)
  float* h3 = hB;                                                     // [N,64] fp32
  float* z1 = bufA;                                                   // [N,64] fp32 (over h2bf)
  float* z2 = hB + (size_t)N * 64;                                    // [N,32] fp32

  // packed-weight offsets (ushort units)
  unsigned short* WtSk = wt;                 // 64c x128k
  unsigned short* WtL1 = WtSk + 8192;        // 128x128
  unsigned short* WtR1 = WtL1 + 16384;       // 128x128
  unsigned short* WtG2 = WtR1 + 16384;       // 128c x512k (concat heads)
  unsigned short* WtL3 = WtG2 + 65536;       // 64c x128k
  unsigned short* WtR3 = WtL3 + 8192;        // 64c x128k
  unsigned short* WtC1 = WtR3 + 8192;        // 64c x64k
  unsigned short* WtC2 = WtC1 + 4096;        // 32c x64k

  float* st1 = stats, *st2 = stats + 256, *st3 = stats + 512, *st4 = stats + 768;

  dim3 blk(256);
  int gE     = (E + 255) / 256;
  int gN64   = (N + 63) / 64;
  int gSC    = (N + 1023) / 1024;
  int gW     = (int)(((long)N * 64 + 255) / 256);
  int gA     = (int)(((long)N * 8 + 255) / 256);
  int gC     = (int)(((long)N * 32 + 255) / 256);
  int gBN128 = (int)(((long)N * 128 + 255) / 256);
  int gBN64  = (int)(((long)N * 64 + 255) / 256);

  hipMemsetAsync(cnt, 0, (size_t)N * 4, stream);

  // ---- CSR build + packing + cast ----
  k_hist<<<gE, blk, 0, stream>>>(dst, cnt, E);
  k_scan1<<<gSC, blk, 0, stream>>>(cnt, bsum, N);
  k_scan2<<<1, 1024, 0, stream>>>(bsum, gSC);
  k_scan3<<<gSC, blk, 0, stream>>>(cnt, bsum, indptr, cursor, N);
  k_fill<<<gE, blk, 0, stream>>>(src, dst, cursor, csr_src, E);
  k_cast<<<gC, blk, 0, stream>>>(x, xbf, (long)N * 32);
  k_packall<<<504, blk, 0, stream>>>(Wsk, Wl1, Wr1, Wg, Wl3, Wr3, Wc1, Wc2, wt);

  // ---- SAGE1 ----
  k_gmean<128, 1><<<gW, blk, 0, stream>>>(xbf, indptr, csr_src, mean1bf, N);
  k_mgemm<2><<<dim3(gN64, 1), blk, 0, stream>>>(
      xbf, 1, 128, 128, WtSk, nullptr, 0, 0, 0, nullptr,
      bsk, nullptr, idbf, 1, N, 64, 0);
  k_mgemm<4><<<dim3(gN64, 1), blk, 0, stream>>>(
      mean1bf, 1, 128, 128, WtL1, xbf, 1, 128, 128, WtR1,
      b1, nullptr, h1bf, 1, N, 128, 0);
  k_stats<1><<<256, blk, 0, stream>>>(h1bf, spart, N, 128);
  k_statred<<<1, 128, 0, stream>>>(spart, st1, 128);
  k_bnb<<<gBN128, blk, 0, stream>>>(h1bf, st1, g1, be1, N, 128);

  // ---- GAT (aggregate in h1-space, then one K=512 GEMM) ----
  k_foldatt<<<4, blk, 0, stream>>>(Wg, atts, attd, attw);
  k_attdots<<<2048, blk, 0, stream>>>(h1bf, attw, asad, N);
  k_alpha<<<gA, blk, 0, stream>>>(indptr, csr_src, asad, alpha, N);
  k_gath1<<<gW, blk, 0, stream>>>(h1bf, indptr, csr_src, alpha, agg, N);
  k_mgemm<4><<<dim3(gN64, 1), blk, 0, stream>>>(
      agg, 1, 512, 512, WtG2, nullptr, 0, 0, 0, nullptr,
      nullptr, nullptr, h2bf, 1, N, 128, 0);
  k_stats<1><<<256, blk, 0, stream>>>(h2bf, spart, N, 128);
  k_statred<<<1, 128, 0, stream>>>(spart, st2, 128);
  k_bnb<<<gBN128, blk, 0, stream>>>(h2bf, st2, g2, be2, N, 128);

  // ---- SAGE3 (project-first: gather 64-wide; mean3 kept fp32) ----
  k_mgemm<2><<<dim3(gN64, 1), blk, 0, stream>>>(
      h2bf, 1, 128, 128, WtL3, nullptr, 0, 0, 0, nullptr,
      nullptr, nullptr, yl3, 1, N, 64, 0);
  k_gmean<64, 0><<<gW, blk, 0, stream>>>(yl3, indptr, csr_src, mean3f, N);
  k_mgemm<2><<<dim3(gN64, 1), blk, 0, stream>>>(
      h2bf, 1, 128, 128, WtR3, nullptr, 0, 0, 0, nullptr,
      b3, mean3f, h3, 0, N, 64, 0);
  k_stats<0><<<256, blk, 0, stream>>>(h3, spart, N, 64);
  k_statred<<<1, 128, 0, stream>>>(spart, st3, 64);
  k_bnf<<<gBN64, blk, 0, stream>>>(h3, st3, g3, be3, idbf, h3bf, N, 64);  // +identity

  // ---- classifier ----
  k_mgemm<2><<<dim3(gN64, 1), blk, 0, stream>>>(
      h3bf, 1, 64, 64, WtC1, nullptr, 0, 0, 0, nullptr,
      bc1, nullptr, z1, 0, N, 64, 0);
  k_stats<0><<<256, blk, 0, stream>>>(z1, spart, N, 64);
  k_statred<<<1, 128, 0, stream>>>(spart, st4, 64);
  k_bnf<<<gBN64, blk, 0, stream>>>(z1, st4, gc, bec, nullptr, z1bf, N, 64);
  k_mgemm<1><<<dim3(gN64, 1), blk, 0, stream>>>(
      z1bf, 1, 64, 64, WtC2, nullptr, 0, 0, 0, nullptr,
      bc2, nullptr, z2, 0, N, 32, 1);
  k_final<<<(N + 255) / 256, blk, 0, stream>>>(z2, Wc3, bc3, (float*)d_out, N);
}

// Round 12
// 803.038 us; speedup vs baseline: 5.7564x; 1.1259x over previous
//
#include <hip/hip_runtime.h>
#include <hip/hip_bf16.h>
#include <cmath>

// ---------------------------------------------------------------------------
// MuleHunterGNN: SAGE -> GAT -> SAGE -> skip -> MLP classifier
// CSR-gather; GAT aggregation in h1-space (alpha-weighted gather + one K=512
// MFMA GEMM). Round 12: k_mgemm -> 512 threads / 8 waves / 128-row tiles
// (was 64-row, 23% occupancy, latency-bound). Replay-deterministic.
// ---------------------------------------------------------------------------

typedef short s16x8 __attribute__((ext_vector_type(8)));
typedef float f32x4 __attribute__((ext_vector_type(4)));

__device__ __forceinline__ float bf2f(unsigned short u) {
  return __uint_as_float((unsigned)u << 16);
}
__device__ __forceinline__ unsigned short f2bf(float f) {
  __hip_bfloat16 h = __float2bfloat16(f);
  return *reinterpret_cast<unsigned short*>(&h);
}

// ---- CSR build -----------------------------------------------------------
__global__ void k_hist(const int* __restrict__ dst, int* __restrict__ cnt, int E) {
  int e = blockIdx.x * blockDim.x + threadIdx.x;
  if (e < E) atomicAdd(&cnt[dst[e]], 1);
}

__global__ __launch_bounds__(256) void k_scan1(const int* __restrict__ cnt,
                                               int* __restrict__ bsum, int N) {
  int base = blockIdx.x << 10;
  int t = threadIdx.x;
  int s = 0;
  #pragma unroll
  for (int j = 0; j < 4; ++j) {
    int i = base + t * 4 + j;
    if (i < N) s += cnt[i];
  }
  __shared__ int red[256];
  red[t] = s;
  __syncthreads();
  for (int off = 128; off; off >>= 1) {
    if (t < off) red[t] += red[t + off];
    __syncthreads();
  }
  if (t == 0) bsum[blockIdx.x] = red[0];
}

__global__ __launch_bounds__(1024) void k_scan2(int* __restrict__ bsum, int nb) {
  __shared__ int sh[1024];
  int t = threadIdx.x;
  int v = (t < nb) ? bsum[t] : 0;
  sh[t] = v;
  __syncthreads();
  for (int off = 1; off < 1024; off <<= 1) {
    int u = (t >= off) ? sh[t - off] : 0;
    __syncthreads();
    sh[t] += u;
    __syncthreads();
  }
  if (t < nb) bsum[t] = sh[t] - v;  // exclusive prefix
}

__global__ __launch_bounds__(256) void k_scan3(const int* __restrict__ cnt,
                                               const int* __restrict__ bsum,
                                               int* __restrict__ indptr,
                                               int* __restrict__ cursor, int N) {
  int base = blockIdx.x << 10;
  int t = threadIdx.x;
  int lane = t & 63, w = t >> 6;
  int i0 = base + t * 4;
  int v[4], s = 0;
  #pragma unroll
  for (int j = 0; j < 4; ++j) {
    int i = i0 + j;
    v[j] = (i < N) ? cnt[i] : 0;
    s += v[j];
  }
  int incl = s;
  #pragma unroll
  for (int off = 1; off < 64; off <<= 1) {
    int u = __shfl_up(incl, off);
    if (lane >= off) incl += u;
  }
  __shared__ int wsum[4];
  if (lane == 63) wsum[w] = incl;
  __syncthreads();
  int add = 0;
  for (int j = 0; j < w; ++j) add += wsum[j];
  int run = incl - s + add + bsum[blockIdx.x];
  #pragma unroll
  for (int j = 0; j < 4; ++j) {
    int i = i0 + j;
    if (i < N) {
      cursor[i] = run;
      run += v[j];
      indptr[i + 1] = run;
    }
  }
  if (blockIdx.x == 0 && t == 0) indptr[0] = 0;
}

__global__ void k_fill(const int* __restrict__ src, const int* __restrict__ dst,
                       int* __restrict__ cursor, int* __restrict__ csr_src, int E) {
  int e = blockIdx.x * blockDim.x + threadIdx.x;
  if (e >= E) return;
  int pos = atomicAdd(&cursor[dst[e]], 1);
  csr_src[pos] = src[e];
}

// ---- fp32 -> bf16 cast ----------------------------------------------------
__global__ void k_cast(const float* __restrict__ in, unsigned short* __restrict__ out,
                       long n4) {
  long t = (long)blockIdx.x * blockDim.x + threadIdx.x;
  if (t >= n4) return;
  float4 v = *reinterpret_cast<const float4*>(in + t * 4);
  ushort4 u;
  u.x = f2bf(v.x); u.y = f2bf(v.y); u.z = f2bf(v.z); u.w = f2bf(v.w);
  *reinterpret_cast<ushort4*>(out + t * 4) = u;
}

// ---- all weight packs in one launch (129024 ushorts total) -----------------
__global__ void k_packall(const float* __restrict__ Wsk, const float* __restrict__ Wl1,
                          const float* __restrict__ Wr1, const float* __restrict__ Wg,
                          const float* __restrict__ Wl3, const float* __restrict__ Wr3,
                          const float* __restrict__ Wc1, const float* __restrict__ Wc2,
                          unsigned short* __restrict__ wt) {
  int t = blockIdx.x * blockDim.x + threadIdx.x;
  if (t >= 129024) return;
  float v;
  if (t < 8192) {                 // WtSk [64c][128k]
    int c = t >> 7, k = t & 127;
    v = Wsk[k * 64 + c];
  } else if (t < 24576) {         // WtL1 [128c][128k]
    int r = t - 8192; int c = r >> 7, k = r & 127;
    v = Wl1[k * 128 + c];
  } else if (t < 40960) {         // WtR1 [128c][128k]
    int r = t - 24576; int c = r >> 7, k = r & 127;
    v = Wr1[k * 128 + c];
  } else if (t < 106496) {        // WtG2 [128c][512k], kg=h*128+k <- Wg[k][h*128+c]
    int r = t - 40960; int c = r >> 9; int q = r & 511; int h = q >> 7, k = q & 127;
    v = Wg[k * 512 + h * 128 + c];
  } else if (t < 114688) {        // WtL3 [64c][128k]
    int r = t - 106496; int c = r >> 7, k = r & 127;
    v = Wl3[k * 64 + c];
  } else if (t < 122880) {        // WtR3 [64c][128k]
    int r = t - 114688; int c = r >> 7, k = r & 127;
    v = Wr3[k * 64 + c];
  } else if (t < 126976) {        // WtC1 [64c][64k]
    int r = t - 122880; int c = r >> 6, k = r & 63;
    v = Wc1[k * 64 + c];
  } else {                        // WtC2 [32c][64k]
    int r = t - 126976; int c = r >> 6, k = r & 63;
    v = Wc2[k * 32 + c];
  }
  wt[t] = f2bf(v);
}

// ---- gather mean of bf16 rows (W=128/64), bf16 or fp32 out -----------------
template <int W, int OBF>
__global__ __launch_bounds__(256) void k_gmean(const unsigned short* __restrict__ X,
                                               const int* __restrict__ indptr,
                                               const int* __restrict__ csr,
                                               void* __restrict__ out, int N) {
  long wid = ((long)blockIdx.x * blockDim.x + threadIdx.x) >> 6;
  if (wid >= N) return;
  int lane = threadIdx.x & 63;
  int b = indptr[wid], en = indptr[wid + 1];
  if (W == 128) {
    float ax = 0.f, ay = 0.f;
    for (int i = b; i < en; ++i) {
      int s = csr[i];
      ushort2 u = *reinterpret_cast<const ushort2*>(X + ((size_t)s << 7) + (lane << 1));
      ax += bf2f(u.x); ay += bf2f(u.y);
    }
    float inv = 1.0f / (float)max(en - b, 1);
    ax *= inv; ay *= inv;
    if (OBF) {
      ushort2 o; o.x = f2bf(ax); o.y = f2bf(ay);
      *reinterpret_cast<ushort2*>((unsigned short*)out + (wid << 7) + (lane << 1)) = o;
    } else {
      *reinterpret_cast<float2*>((float*)out + (wid << 7) + (lane << 1)) =
          make_float2(ax, ay);
    }
  } else {
    float a = 0.f;
    for (int i = b; i < en; ++i) {
      int s = csr[i];
      a += bf2f(X[((size_t)s << 6) + lane]);
    }
    float inv = 1.0f / (float)max(en - b, 1);
    a *= inv;
    if (OBF) ((unsigned short*)out)[(wid << 6) + lane] = f2bf(a);
    else     ((float*)out)[(wid << 6) + lane] = a;
  }
}

// ---- GAT alpha: per-dst segment softmax, 8 lanes per dst ------------------
__global__ __launch_bounds__(256) void k_alpha(const int* __restrict__ indptr,
                                               const int* __restrict__ csr,
                                               const float* __restrict__ asad,
                                               float* __restrict__ alpha, int N) {
  long g = ((long)blockIdx.x * blockDim.x + threadIdx.x) >> 3;
  if (g >= N) return;
  int l8 = threadIdx.x & 7;
  int b = indptr[g], en = indptr[g + 1];
  float4 adv = *reinterpret_cast<const float4*>(asad + g * 8 + 4);
  float m[4] = {-INFINITY, -INFINITY, -INFINITY, -INFINITY};
  for (int i = b + l8; i < en; i += 8) {
    int s = csr[i];
    float4 a = *reinterpret_cast<const float4*>(asad + (size_t)s * 8);
    float e0 = a.x + adv.x, e1 = a.y + adv.y, e2 = a.z + adv.z, e3 = a.w + adv.w;
    e0 = e0 >= 0.f ? e0 : 0.2f * e0; e1 = e1 >= 0.f ? e1 : 0.2f * e1;
    e2 = e2 >= 0.f ? e2 : 0.2f * e2; e3 = e3 >= 0.f ? e3 : 0.2f * e3;
    m[0] = fmaxf(m[0], e0); m[1] = fmaxf(m[1], e1);
    m[2] = fmaxf(m[2], e2); m[3] = fmaxf(m[3], e3);
  }
  #pragma unroll
  for (int off = 1; off < 8; off <<= 1) {
    #pragma unroll
    for (int h = 0; h < 4; ++h) m[h] = fmaxf(m[h], __shfl_xor(m[h], off));
  }
  float den[4] = {0.f, 0.f, 0.f, 0.f};
  for (int i = b + l8; i < en; i += 8) {
    int s = csr[i];
    float4 a = *reinterpret_cast<const float4*>(asad + (size_t)s * 8);
    float e0 = a.x + adv.x, e1 = a.y + adv.y, e2 = a.z + adv.z, e3 = a.w + adv.w;
    e0 = e0 >= 0.f ? e0 : 0.2f * e0; e1 = e1 >= 0.f ? e1 : 0.2f * e1;
    e2 = e2 >= 0.f ? e2 : 0.2f * e2; e3 = e3 >= 0.f ? e3 : 0.2f * e3;
    float4 w;
    w.x = __expf(e0 - m[0]); w.y = __expf(e1 - m[1]);
    w.z = __expf(e2 - m[2]); w.w = __expf(e3 - m[3]);
    den[0] += w.x; den[1] += w.y; den[2] += w.z; den[3] += w.w;
    *reinterpret_cast<float4*>(alpha + (size_t)i * 4) = w;
  }
  #pragma unroll
  for (int off = 1; off < 8; off <<= 1) {
    #pragma unroll
    for (int h = 0; h < 4; ++h) den[h] += __shfl_xor(den[h], off);
  }
  float s0 = 0.25f / fmaxf(den[0], 1e-16f);
  float s1 = 0.25f / fmaxf(den[1], 1e-16f);
  float s2 = 0.25f / fmaxf(den[2], 1e-16f);
  float s3 = 0.25f / fmaxf(den[3], 1e-16f);
  for (int i = b + l8; i < en; i += 8) {
    float4 w = *reinterpret_cast<const float4*>(alpha + (size_t)i * 4);
    w.x *= s0; w.y *= s1; w.z *= s2; w.w *= s3;
    *reinterpret_cast<float4*>(alpha + (size_t)i * 4) = w;
  }
}

// ---- GAT gather in h1-space: agg[d, h*128+:] = sum_e alpha[e][h]*h1[src_e] --
__global__ __launch_bounds__(256) void k_gath1(
    const unsigned short* __restrict__ h1, const int* __restrict__ indptr,
    const int* __restrict__ csr, const float* __restrict__ alpha,
    unsigned short* __restrict__ agg, int N) {
  long wid = ((long)blockIdx.x * blockDim.x + threadIdx.x) >> 6;
  if (wid >= N) return;
  int lane = threadIdx.x & 63;
  int b = indptr[wid], en = indptr[wid + 1];
  float a0x = 0.f, a0y = 0.f, a1x = 0.f, a1y = 0.f;
  float a2x = 0.f, a2y = 0.f, a3x = 0.f, a3y = 0.f;
  for (int i = b; i < en; ++i) {
    int s = csr[i];
    float4 a = *reinterpret_cast<const float4*>(alpha + (size_t)i * 4);
    ushort2 u = *reinterpret_cast<const ushort2*>(h1 + ((size_t)s << 7) + (lane << 1));
    float vx = bf2f(u.x), vy = bf2f(u.y);
    a0x = fmaf(a.x, vx, a0x); a0y = fmaf(a.x, vy, a0y);
    a1x = fmaf(a.y, vx, a1x); a1y = fmaf(a.y, vy, a1y);
    a2x = fmaf(a.z, vx, a2x); a2y = fmaf(a.z, vy, a2y);
    a3x = fmaf(a.w, vx, a3x); a3y = fmaf(a.w, vy, a3y);
  }
  unsigned short* po = agg + ((size_t)wid << 9) + (lane << 1);
  ushort2 o;
  o.x = f2bf(a0x); o.y = f2bf(a0y); *reinterpret_cast<ushort2*>(po)       = o;
  o.x = f2bf(a1x); o.y = f2bf(a1y); *reinterpret_cast<ushort2*>(po + 128) = o;
  o.x = f2bf(a2x); o.y = f2bf(a2y); *reinterpret_cast<ushort2*>(po + 256) = o;
  o.x = f2bf(a3x); o.y = f2bf(a3y); *reinterpret_cast<ushort2*>(po + 384) = o;
}

// ---- MFMA GEMM: C = A1@W1 [+ A2@W2] + bias [+ Cadd(fp32)] ------------------
// 512 threads = 8 waves (4 row x 2 col), 128-row x BN-col tile.
// A bf16/fp32 [N,ldA], Wt bf16 [cols][K]; kw = min(K,128) is a power of two.
template <int CF>
__global__ __launch_bounds__(512, 2) void k_mgemm(
    const void* __restrict__ A1, int a1bf, int ldA1, int K1,
    const unsigned short* __restrict__ Wt1,
    const void* __restrict__ A2, int a2bf, int ldA2, int K2,
    const unsigned short* __restrict__ Wt2,
    const float* __restrict__ bias, const float* __restrict__ Cadd,
    void* __restrict__ Cout, int obf16,
    int Nrows, int ldC, int relu) {
  constexpr int BN = CF * 32;
  __shared__ alignas(16) unsigned short sA[128][136];
  __shared__ alignas(16) unsigned short sBt[BN][136];
  const int tid = threadIdx.x;
  const int lane = tid & 63;
  const int w = tid >> 6;                 // 0..7
  const int wr = (w >> 1) * 32;           // wave row base (0/32/64/96)
  const int wc = (w & 1) * (CF * 16);     // wave col base
  const int lr = lane & 15;
  const int lk = (lane >> 4) << 3;
  const int row0 = blockIdx.x * 128;
  const int colb = blockIdx.y * BN;

  f32x4 acc[2][CF];
  #pragma unroll
  for (int i = 0; i < 2; ++i)
    #pragma unroll
    for (int j = 0; j < CF; ++j) acc[i][j] = (f32x4){0.f, 0.f, 0.f, 0.f};

  for (int pass = 0; pass < 2; ++pass) {
    const void* A = pass ? A2 : A1;
    if (!A) break;
    const int abf = pass ? a2bf : a1bf;
    const int ldA = pass ? ldA2 : ldA1;
    const int K = pass ? K2 : K1;
    const unsigned short* Wt = pass ? Wt2 : Wt1;
    const int kw = (K < 128) ? K : 128;          // 64 or 128 (power of two)
    const int ksh = (kw == 128) ? 7 : 6;
    const int kc = (tid << 2) & (kw - 1);        // fixed column group
    const int r0 = (tid << 2) >> ksh;
    const int rstep = 2048 >> ksh;               // 16 or 32
    for (int kb = 0; kb < K; kb += kw) {
      for (int r = r0; r < 128; r += rstep) {
        int gr = row0 + r;
        ushort4 u = make_ushort4(0, 0, 0, 0);
        if (gr < Nrows) {
          if (abf) {
            u = *reinterpret_cast<const ushort4*>(
                (const unsigned short*)A + (size_t)gr * ldA + kb + kc);
          } else {
            float4 v = *reinterpret_cast<const float4*>(
                (const float*)A + (size_t)gr * ldA + kb + kc);
            u.x = f2bf(v.x); u.y = f2bf(v.y); u.z = f2bf(v.z); u.w = f2bf(v.w);
          }
        }
        *reinterpret_cast<ushort4*>(&sA[r][kc]) = u;
      }
      for (int c = r0; c < BN; c += rstep) {
        ushort4 u = *reinterpret_cast<const ushort4*>(
            Wt + (size_t)(colb + c) * K + kb + kc);
        *reinterpret_cast<ushort4*>(&sBt[c][kc]) = u;
      }
      __syncthreads();
      for (int k0 = lk; k0 < kw; k0 += 32) {
        s16x8 a0 = *reinterpret_cast<const s16x8*>(&sA[wr + lr][k0]);
        s16x8 a1 = *reinterpret_cast<const s16x8*>(&sA[wr + lr + 16][k0]);
        #pragma unroll
        for (int j = 0; j < CF; ++j) {
          s16x8 bj = *reinterpret_cast<const s16x8*>(&sBt[wc + lr + 16 * j][k0]);
          acc[0][j] = __builtin_amdgcn_mfma_f32_16x16x32_bf16(a0, bj, acc[0][j], 0, 0, 0);
          acc[1][j] = __builtin_amdgcn_mfma_f32_16x16x32_bf16(a1, bj, acc[1][j], 0, 0, 0);
        }
      }
      __syncthreads();
    }
  }

  // epilogue: D col = lane&15, row = 4*(lane>>4)+reg  [m89/m91]
  const int rbase = (lane >> 4) << 2;
  #pragma unroll
  for (int i = 0; i < 2; ++i) {
    int grow = row0 + wr + 16 * i + rbase;
    #pragma unroll
    for (int j = 0; j < CF; ++j) {
      int col = colb + wc + 16 * j + lr;
      float bv = bias ? bias[col] : 0.f;
      #pragma unroll
      for (int r = 0; r < 4; ++r) {
        if (grow + r >= Nrows) continue;
        float v = acc[i][j][r] + bv;
        if (Cadd) v += Cadd[(size_t)(grow + r) * ldC + col];
        if (relu) v = fmaxf(v, 0.f);
        if (obf16)
          ((unsigned short*)Cout)[(size_t)(grow + r) * ldC + col] = f2bf(v);
        else
          ((float*)Cout)[(size_t)(grow + r) * ldC + col] = v;
      }
    }
  }
}

// ---- per-column sum/sumsq partials: grid MUST be 256 blocks (fixed slots) --
template <int BF>
__global__ void k_stats(const void* __restrict__ Xv, float* __restrict__ part,
                        int Nrows, int K) {
  int c = threadIdx.x & (K - 1);
  int rl = threadIdx.x / K;
  int rpb = 256 / K;
  float s = 0.f, s2 = 0.f;
  for (long r = (long)blockIdx.x * rpb + rl; r < Nrows; r += (long)gridDim.x * rpb) {
    float v = BF ? bf2f(((const unsigned short*)Xv)[r * K + c])
                 : ((const float*)Xv)[r * K + c];
    s += v;
    s2 = fmaf(v, v, s2);
  }
  __shared__ float b1s[256], b2s[256];
  b1s[threadIdx.x] = s; b2s[threadIdx.x] = s2;
  __syncthreads();
  if (rl == 0) {
    for (int t = 1; t < rpb; ++t) { s += b1s[t * K + c]; s2 += b2s[t * K + c]; }
    part[(size_t)blockIdx.x * 128 + c] = s;
    part[32768 + (size_t)blockIdx.x * 128 + c] = s2;
  }
}

// ---- fixed-order reduction of partials -> stats (deterministic) ------------
__global__ void k_statred(const float* __restrict__ part, float* __restrict__ st,
                          int K) {
  int c = threadIdx.x;
  if (c >= K) return;
  float s = 0.f, s2 = 0.f;
  for (int b = 0; b < 256; ++b) {
    s += part[(size_t)b * 128 + c];
    s2 += part[32768 + (size_t)b * 128 + c];
  }
  st[c] = s;
  st[128 + c] = s2;
}

// ---- BN+ReLU, bf16 in-place ------------------------------------------------
__global__ void k_bnb(unsigned short* __restrict__ X, const float* __restrict__ stats,
                      const float* __restrict__ g, const float* __restrict__ b,
                      int Nrows, int K) {
  long i = (long)blockIdx.x * blockDim.x + threadIdx.x;
  if (i >= (long)Nrows * K) return;
  int c = (int)(i & (K - 1));
  float invN = 1.0f / (float)Nrows;
  float m = stats[c] * invN;
  float v = stats[128 + c] * invN - m * m;
  float y = g[c] * (bf2f(X[i]) - m) * rsqrtf(v + 1e-5f) + b[c];
  X[i] = f2bf(fmaxf(y, 0.f));
}

// ---- BN+ReLU fp32 in -> bf16 out (+ optional bf16 residual after relu) -----
__global__ void k_bnf(const float* __restrict__ X, const float* __restrict__ stats,
                      const float* __restrict__ g, const float* __restrict__ b,
                      const unsigned short* __restrict__ addAfter,
                      unsigned short* __restrict__ outb, int Nrows, int K) {
  long i = (long)blockIdx.x * blockDim.x + threadIdx.x;
  if (i >= (long)Nrows * K) return;
  int c = (int)(i & (K - 1));
  float invN = 1.0f / (float)Nrows;
  float m = stats[c] * invN;
  float v = stats[128 + c] * invN - m * m;
  float y = g[c] * (X[i] - m) * rsqrtf(v + 1e-5f) + b[c];
  y = fmaxf(y, 0.f);
  if (addAfter) y += bf2f(addAfter[i]);
  outb[i] = f2bf(y);
}

// ---- fold attention vectors -------------------------------------------------
__global__ void k_foldatt(const float* __restrict__ Wg, const float* __restrict__ atts,
                          const float* __restrict__ attd, float* __restrict__ attw) {
  int t = blockIdx.x * blockDim.x + threadIdx.x;
  if (t >= 1024) return;
  int k = t >> 3, j = t & 7, h = j & 3;
  const float* av = (j < 4 ? atts : attd) + h * 128;
  const float* wg = Wg + (size_t)k * 512 + h * 128;
  float s = 0.f;
  for (int c = 0; c < 128; ++c) s = fmaf(wg[c], av[c], s);
  attw[t] = s;
}

// ---- a_s/a_d per node from bf16 h1, one wave each, grid-stride --------------
__global__ void k_attdots(const unsigned short* __restrict__ h1bf,
                          const float* __restrict__ attw,
                          float* __restrict__ asad, int Nrows) {
  int lane = threadIdx.x & 63;
  float c0[8], c1[8];
  #pragma unroll
  for (int j = 0; j < 8; ++j) {
    c0[j] = attw[(2 * lane) * 8 + j];
    c1[j] = attw[(2 * lane + 1) * 8 + j];
  }
  long wid = ((long)blockIdx.x * blockDim.x + threadIdx.x) >> 6;
  long nw = ((long)gridDim.x * blockDim.x) >> 6;
  for (long n = wid; n < Nrows; n += nw) {
    ushort2 u = *reinterpret_cast<const ushort2*>(h1bf + (n << 7) + (lane << 1));
    float vx = bf2f(u.x), vy = bf2f(u.y);
    float a[8];
    #pragma unroll
    for (int j = 0; j < 8; ++j) a[j] = vx * c0[j] + vy * c1[j];
    #pragma unroll
    for (int off = 1; off < 64; off <<= 1) {
      #pragma unroll
      for (int j = 0; j < 8; ++j) a[j] += __shfl_xor(a[j], off);
    }
    if (lane == 0) {
      *reinterpret_cast<float4*>(asad + n * 8)     = make_float4(a[0], a[1], a[2], a[3]);
      *reinterpret_cast<float4*>(asad + n * 8 + 4) = make_float4(a[4], a[5], a[6], a[7]);
    }
  }
}

// ---- final: logits = z2 @ Wc3 + bc3; log_softmax ----------------------------
__global__ void k_final(const float* __restrict__ z2, const float* __restrict__ W,
                        const float* __restrict__ b, float* __restrict__ out, int Nrows) {
  int n = blockIdx.x * blockDim.x + threadIdx.x;
  if (n >= Nrows) return;
  float l0 = b[0], l1 = b[1];
  const float* z = z2 + (size_t)n * 32;
  #pragma unroll
  for (int k = 0; k < 32; ++k) {
    float v = z[k];
    l0 = fmaf(v, W[2 * k], l0);
    l1 = fmaf(v, W[2 * k + 1], l1);
  }
  float m = fmaxf(l0, l1);
  float lse = m + logf(expf(l0 - m) + expf(l1 - m));
  out[2 * n] = l0 - lse;
  out[2 * n + 1] = l1 - lse;
}

// ---------------------------------------------------------------------------
extern "C" void kernel_launch(void* const* d_in, const int* in_sizes, int n_in,
                              void* d_out, int out_size, void* d_ws, size_t ws_size,
                              hipStream_t stream) {
  const float* x    = (const float*)d_in[0];
  const int*   ei   = (const int*)  d_in[1];
  const float* Wl1  = (const float*)d_in[2];
  const float* Wr1  = (const float*)d_in[3];
  const float* b1   = (const float*)d_in[4];
  const float* g1   = (const float*)d_in[5];
  const float* be1  = (const float*)d_in[6];
  const float* Wg   = (const float*)d_in[7];
  const float* atts = (const float*)d_in[8];
  const float* attd = (const float*)d_in[9];
  // d_in[10] = bg: constant column offset, cancels exactly in the following BN.
  const float* g2   = (const float*)d_in[11];
  const float* be2  = (const float*)d_in[12];
  const float* Wl3  = (const float*)d_in[13];
  const float* Wr3  = (const float*)d_in[14];
  const float* b3   = (const float*)d_in[15];
  const float* g3   = (const float*)d_in[16];
  const float* be3  = (const float*)d_in[17];
  const float* Wsk  = (const float*)d_in[18];
  const float* bsk  = (const float*)d_in[19];
  const float* Wc1  = (const float*)d_in[20];
  const float* bc1  = (const float*)d_in[21];
  const float* gc   = (const float*)d_in[22];
  const float* bec  = (const float*)d_in[23];
  const float* Wc2  = (const float*)d_in[24];
  const float* bc2  = (const float*)d_in[25];
  const float* Wc3  = (const float*)d_in[26];
  const float* bc3  = (const float*)d_in[27];
  (void)n_in; (void)out_size; (void)ws_size;

  const int N = in_sizes[0] / 128;
  const int E = in_sizes[1] / 2;
  const int* src = ei;
  const int* dst = ei + E;

  // ---- workspace carve-out (fp32 words) -------------------------------------
  auto al4 = [](size_t w) { return (w + 3) & ~(size_t)3; };
  float* ws = (float*)d_ws;
  size_t o = 0;
  int* cnt      = (int*)(ws + o); o += al4((size_t)N);
  int* indptr   = (int*)(ws + o); o += al4((size_t)N + 1);
  int* cursor   = (int*)(ws + o); o += al4((size_t)N);
  int* csr_src  = (int*)(ws + o); o += al4((size_t)E);
  int* bsum     = (int*)(ws + o); o += 1024;
  unsigned short* idbf = (unsigned short*)(ws + o); o += al4((size_t)N * 32);  // [N,64] bf16
  float* stats  = ws + o; o += 1024;
  float* spart  = ws + o; o += 65536;               // 256 blocks x 128 cols x {s,s2}
  float* attw   = ws + o; o += 1024;
  float* asad   = ws + o; o += al4((size_t)N * 8);
  float* alpha  = ws + o; o += al4((size_t)E * 4);
  unsigned short* wt = (unsigned short*)(ws + o); o += 64512 + 64;  // packed weights
  float* bufA   = ws + o; o += (size_t)N * 128;   // xbf|mean1bf -> h2bf|h3bf -> z1
  float* hb1    = ws + o; o += (size_t)N * 64;    // h1bf [N,128] bf16
  float* hB     = ws + o; o += (size_t)N * 128;   // h3 fp32 [N,64] + z2 [N,32]
  unsigned short* agg = (unsigned short*)(ws + o); o += (size_t)N * 256;  // [N,512] bf16

  // region aliases
  unsigned short* xbf     = (unsigned short*)bufA;                    // [N,128] bf16
  unsigned short* mean1bf = (unsigned short*)(bufA + (size_t)N * 64); // [N,128] bf16
  unsigned short* h1bf    = (unsigned short*)hb1;                     // [N,128] bf16
  unsigned short* h2bf    = (unsigned short*)bufA;                    // [N,128] bf16 (over xbf)
  unsigned short* h3bf    = (unsigned short*)(bufA + (size_t)N * 64); // [N,64] bf16
  unsigned short* yl3     = agg;                                      // [N,64] bf16
  float* mean3f           = (float*)agg + (size_t)N * 32;             // [N,64] fp32 (after yl3)
  unsigned short* z1bf    = agg;                                      // [N,64] bf16 (after SAGE3)
  float* h3 = hB;                                                     // [N,64] fp32
  float* z1 = bufA;                                                   // [N,64] fp32 (over h2bf)
  float* z2 = hB + (size_t)N * 64;                                    // [N,32] fp32

  // packed-weight offsets (ushort units)
  unsigned short* WtSk = wt;                 // 64c x128k
  unsigned short* WtL1 = WtSk + 8192;        // 128x128
  unsigned short* WtR1 = WtL1 + 16384;       // 128x128
  unsigned short* WtG2 = WtR1 + 16384;       // 128c x512k (concat heads)
  unsigned short* WtL3 = WtG2 + 65536;       // 64c x128k
  unsigned short* WtR3 = WtL3 + 8192;        // 64c x128k
  unsigned short* WtC1 = WtR3 + 8192;        // 64c x64k
  unsigned short* WtC2 = WtC1 + 4096;        // 32c x64k

  float* st1 = stats, *st2 = stats + 256, *st3 = stats + 512, *st4 = stats + 768;

  dim3 blk(256);
  dim3 blk512(512);
  int gE     = (E + 255) / 256;
  int gN128  = (N + 127) / 128;
  int gSC    = (N + 1023) / 1024;
  int gW     = (int)(((long)N * 64 + 255) / 256);
  int gA     = (int)(((long)N * 8 + 255) / 256);
  int gC     = (int)(((long)N * 32 + 255) / 256);
  int gBN128 = (int)(((long)N * 128 + 255) / 256);
  int gBN64  = (int)(((long)N * 64 + 255) / 256);

  hipMemsetAsync(cnt, 0, (size_t)N * 4, stream);

  // ---- CSR build + packing + cast ----
  k_hist<<<gE, blk, 0, stream>>>(dst, cnt, E);
  k_scan1<<<gSC, blk, 0, stream>>>(cnt, bsum, N);
  k_scan2<<<1, 1024, 0, stream>>>(bsum, gSC);
  k_scan3<<<gSC, blk, 0, stream>>>(cnt, bsum, indptr, cursor, N);
  k_fill<<<gE, blk, 0, stream>>>(src, dst, cursor, csr_src, E);
  k_cast<<<gC, blk, 0, stream>>>(x, xbf, (long)N * 32);
  k_packall<<<504, blk, 0, stream>>>(Wsk, Wl1, Wr1, Wg, Wl3, Wr3, Wc1, Wc2, wt);

  // ---- SAGE1 ----
  k_gmean<128, 1><<<gW, blk, 0, stream>>>(xbf, indptr, csr_src, mean1bf, N);
  k_mgemm<2><<<dim3(gN128, 1), blk512, 0, stream>>>(
      xbf, 1, 128, 128, WtSk, nullptr, 0, 0, 0, nullptr,
      bsk, nullptr, idbf, 1, N, 64, 0);
  k_mgemm<4><<<dim3(gN128, 1), blk512, 0, stream>>>(
      mean1bf, 1, 128, 128, WtL1, xbf, 1, 128, 128, WtR1,
      b1, nullptr, h1bf, 1, N, 128, 0);
  k_stats<1><<<256, blk, 0, stream>>>(h1bf, spart, N, 128);
  k_statred<<<1, 128, 0, stream>>>(spart, st1, 128);
  k_bnb<<<gBN128, blk, 0, stream>>>(h1bf, st1, g1, be1, N, 128);

  // ---- GAT (aggregate in h1-space, then one K=512 GEMM) ----
  k_foldatt<<<4, blk, 0, stream>>>(Wg, atts, attd, attw);
  k_attdots<<<2048, blk, 0, stream>>>(h1bf, attw, asad, N);
  k_alpha<<<gA, blk, 0, stream>>>(indptr, csr_src, asad, alpha, N);
  k_gath1<<<gW, blk, 0, stream>>>(h1bf, indptr, csr_src, alpha, agg, N);
  k_mgemm<4><<<dim3(gN128, 1), blk512, 0, stream>>>(
      agg, 1, 512, 512, WtG2, nullptr, 0, 0, 0, nullptr,
      nullptr, nullptr, h2bf, 1, N, 128, 0);
  k_stats<1><<<256, blk, 0, stream>>>(h2bf, spart, N, 128);
  k_statred<<<1, 128, 0, stream>>>(spart, st2, 128);
  k_bnb<<<gBN128, blk, 0, stream>>>(h2bf, st2, g2, be2, N, 128);

  // ---- SAGE3 (project-first: gather 64-wide; mean3 kept fp32) ----
  k_mgemm<2><<<dim3(gN128, 1), blk512, 0, stream>>>(
      h2bf, 1, 128, 128, WtL3, nullptr, 0, 0, 0, nullptr,
      nullptr, nullptr, yl3, 1, N, 64, 0);
  k_gmean<64, 0><<<gW, blk, 0, stream>>>(yl3, indptr, csr_src, mean3f, N);
  k_mgemm<2><<<dim3(gN128, 1), blk512, 0, stream>>>(
      h2bf, 1, 128, 128, WtR3, nullptr, 0, 0, 0, nullptr,
      b3, mean3f, h3, 0, N, 64, 0);
  k_stats<0><<<256, blk, 0, stream>>>(h3, spart, N, 64);
  k_statred<<<1, 128, 0, stream>>>(spart, st3, 64);
  k_bnf<<<gBN64, blk, 0, stream>>>(h3, st3, g3, be3, idbf, h3bf, N, 64);  // +identity

  // ---- classifier ----
  k_mgemm<2><<<dim3(gN128, 1), blk512, 0, stream>>>(
      h3bf, 1, 64, 64, WtC1, nullptr, 0, 0, 0, nullptr,
      bc1, nullptr, z1, 0, N, 64, 0);
  k_stats<0><<<256, blk, 0, stream>>>(z1, spart, N, 64);
  k_statred<<<1, 128, 0, stream>>>(spart, st4, 64);
  k_bnf<<<gBN64, blk, 0, stream>>>(z1, st4, gc, bec, nullptr, z1bf, N, 64);
  k_mgemm<1><<<dim3(gN128, 1), blk512, 0, stream>>>(
      z1bf, 1, 64, 64, WtC2, nullptr, 0, 0, 0, nullptr,
      bc2, nullptr, z2, 0, N, 32, 1);
  k_final<<<(N + 255) / 256, blk, 0, stream>>>(z2, Wc3, bc3, (float*)d_out, N);
}